// Round 1
// baseline (907.190 us; speedup 1.0000x reference)
//
#include <hip/hip_runtime.h>
#include <math.h>

#define N_NODES 10000
#define E_EDGES 160000
#define S_DIM 512
#define V_DIM 128
#define H_HEADS 8
#define R_BASIS 32
#define HD_DIM 64
#define NV3 (V_DIM*3)   // 384

static __device__ __forceinline__ float wave_sum(float v) {
  #pragma unroll
  for (int o = 32; o > 0; o >>= 1) v += __shfl_xor(v, o, 64);
  return v;
}
static __device__ __forceinline__ float wave_max(float v) {
  #pragma unroll
  for (int o = 32; o > 0; o >>= 1) v = fmaxf(v, __shfl_xor(v, o, 64));
  return v;
}

// ---------------- f32 tiled GEMM: C = A(MxK) @ B(KxN) + bias ----------------
#define BM 64
#define BN 64
#define BK 16
__global__ __launch_bounds__(256) void gemm_f32_kernel(
    const float* __restrict__ A, const float* __restrict__ B,
    const float* __restrict__ bias, float* __restrict__ C,
    int M, int K, int Nn)
{
  __shared__ float As[BK][BM + 4];
  __shared__ float Bs[BK][BN + 4];
  int tid = threadIdx.x;
  int tx = tid & 15;   // 0..15 -> 4 cols each
  int ty = tid >> 4;   // 0..15 -> 4 rows each
  int row0 = blockIdx.y * BM;
  int col0 = blockIdx.x * BN;

  float acc[4][4] = {};
  for (int k0 = 0; k0 < K; k0 += BK) {
    // A tile: As[k][m] = A[(row0+m)*K + k0+k]
    {
      int k = tid & 15;
      int mb = tid >> 4;
      #pragma unroll
      for (int mm = 0; mm < 4; ++mm) {
        int m = mb + mm * 16;
        int gr = row0 + m;
        As[k][m] = (gr < M) ? A[(size_t)gr * K + k0 + k] : 0.f;
      }
    }
    // B tile: Bs[k][nn] = B[(k0+k)*Nn + col0+nn]
    {
      int nn = tid & 63;
      int kb = tid >> 6;
      #pragma unroll
      for (int kk = 0; kk < 4; ++kk) {
        int k = kb + kk * 4;
        Bs[k][nn] = B[(size_t)(k0 + k) * Nn + col0 + nn];
      }
    }
    __syncthreads();
    #pragma unroll
    for (int k = 0; k < BK; ++k) {
      float4 a4 = *reinterpret_cast<const float4*>(&As[k][ty * 4]);
      float4 b4 = *reinterpret_cast<const float4*>(&Bs[k][tx * 4]);
      float a[4] = {a4.x, a4.y, a4.z, a4.w};
      float b[4] = {b4.x, b4.y, b4.z, b4.w};
      #pragma unroll
      for (int i = 0; i < 4; ++i)
        #pragma unroll
        for (int j = 0; j < 4; ++j)
          acc[i][j] = fmaf(a[i], b[j], acc[i][j]);
    }
    __syncthreads();
  }
  #pragma unroll
  for (int i = 0; i < 4; ++i) {
    int gr = row0 + ty * 4 + i;
    if (gr < M) {
      #pragma unroll
      for (int j = 0; j < 4; ++j) {
        int gc = col0 + tx * 4 + j;
        C[(size_t)gr * Nn + gc] = acc[i][j] + (bias ? bias[gc] : 0.f);
      }
    }
  }
}

// -------- vector-channel GEMM: out[n,w,i] = sum_v A[n,v,i]*W[v,w] (+bias[w]) (+res[n,w,i])
__global__ __launch_bounds__(128) void vec_gemm_kernel(
    const float* __restrict__ A, const float* __restrict__ W,
    const float* __restrict__ bias, const float* __restrict__ res,
    float* __restrict__ out)
{
  __shared__ float As[NV3];
  int n = blockIdx.x;
  int w = threadIdx.x;
  for (int j = w; j < NV3; j += 128) As[j] = A[(size_t)n * NV3 + j];
  __syncthreads();
  float a0 = 0.f, a1 = 0.f, a2 = 0.f;
  #pragma unroll 4
  for (int v = 0; v < V_DIM; ++v) {
    float wv = W[v * V_DIM + w];
    a0 = fmaf(As[v * 3 + 0], wv, a0);
    a1 = fmaf(As[v * 3 + 1], wv, a1);
    a2 = fmaf(As[v * 3 + 2], wv, a2);
  }
  size_t base = (size_t)n * NV3 + (size_t)w * 3;
  float b = bias ? bias[w] : 0.f;
  out[base + 0] = a0 + b + (res ? res[base + 0] : 0.f);
  out[base + 1] = a1 + b + (res ? res[base + 1] : 0.f);
  out[base + 2] = a2 + b + (res ? res[base + 2] : 0.f);
}

// -------- per-edge logits: one wave per edge --------
__global__ __launch_bounds__(256) void edge_logits_kernel(
    const float* __restrict__ q_s, const float* __restrict__ k_s,
    const float* __restrict__ q_v, const float* __restrict__ k_v,
    const float* __restrict__ edge_vec, const int* __restrict__ ei,
    const float* __restrict__ W_edge, const float* __restrict__ b_edge,
    float* __restrict__ logits)
{
  const float PI_F = 3.14159265358979323846f;
  int e = blockIdx.x * 4 + (threadIdx.x >> 6);
  int lane = threadIdx.x & 63;
  if (e >= E_EDGES) return;
  int row = ei[e];
  int col = ei[E_EDGES + e];

  // scalar attention per head: dot over HD=64 (lane = d)
  float hs[H_HEADS];
  #pragma unroll
  for (int h = 0; h < H_HEADS; ++h) {
    float p = q_s[(size_t)row * S_DIM + h * HD_DIM + lane] *
              k_s[(size_t)col * S_DIM + h * HD_DIM + lane];
    hs[h] = wave_sum(p);
  }
  // vector attention: dot over 384 = 6*64
  float pv = 0.f;
  #pragma unroll
  for (int j = 0; j < 6; ++j) {
    int idx = lane + j * 64;
    pv += q_v[(size_t)row * NV3 + idx] * k_v[(size_t)col * NV3 + idx];
  }
  pv = wave_sum(pv) * 0.57735026918962576f;  // 1/sqrt(3)

  // bessel basis (lane r < 32) -> edge MLP
  float ex = edge_vec[(size_t)e * 3 + 0];
  float ey = edge_vec[(size_t)e * 3 + 1];
  float ez = edge_vec[(size_t)e * 3 + 2];
  float d = sqrtf(ex * ex + ey * ey + ez * ez);
  float basis = 0.f;
  if (lane < R_BASIS) {
    float freq = (lane + 1) * (PI_F / 10.0f);
    float cut = (d < 10.0f) ? 0.5f * (cosf(PI_F * d * 0.1f) + 1.0f) : 0.f;
    basis = sinf(freq * d) / fmaxf(d, 1e-8f) * cut;
  }
  float ea[H_HEADS];
  #pragma unroll
  for (int h = 0; h < H_HEADS; ++h) {
    float p = (lane < R_BASIS) ? basis * W_edge[lane * H_HEADS + h] : 0.f;
    ea[h] = wave_sum(p) + b_edge[h];
  }

  if (lane == 0) {
    #pragma unroll
    for (int h = 0; h < H_HEADS; ++h)
      logits[(size_t)e * H_HEADS + h] = (hs[h] + pv + ea[h]) * 0.125f;
  }
}

// -------- CSR build --------
__global__ void count_kernel(const int* __restrict__ ei, int* __restrict__ counts) {
  int e = blockIdx.x * 256 + threadIdx.x;
  if (e < E_EDGES) atomicAdd(&counts[ei[e]], 1);
}

__global__ __launch_bounds__(256) void scan_kernel(const int* __restrict__ counts,
                                                   int* __restrict__ offs) {
  __shared__ int tmp[256];
  __shared__ int carry_s;
  int tid = threadIdx.x;
  if (tid == 0) carry_s = 0;
  __syncthreads();
  for (int base = 0; base < N_NODES; base += 256) {
    int i = base + tid;
    int v = (i < N_NODES) ? counts[i] : 0;
    tmp[tid] = v;
    __syncthreads();
    for (int o = 1; o < 256; o <<= 1) {
      int t = (tid >= o) ? tmp[tid - o] : 0;
      __syncthreads();
      tmp[tid] += t;
      __syncthreads();
    }
    int incl = tmp[tid];
    int c = carry_s;
    if (i < N_NODES) offs[i] = c + incl - v;
    __syncthreads();
    if (tid == 255) carry_s = c + tmp[255];
    __syncthreads();
  }
  if (tid == 0) offs[N_NODES] = carry_s;
}

__global__ void scatter_kernel(const int* __restrict__ ei, const int* __restrict__ offs,
                               int* __restrict__ cursor, int* __restrict__ eord) {
  int e = blockIdx.x * 256 + threadIdx.x;
  if (e < E_EDGES) {
    int r = ei[e];
    int p = offs[r] + atomicAdd(&cursor[r], 1);
    eord[p] = e;
  }
}

// -------- per-node softmax + aggregation (block per node, no atomics) --------
#define MAXDEG 512
__global__ __launch_bounds__(256) void agg_kernel(
    const float* __restrict__ logits, const float* __restrict__ v_s,
    const float* __restrict__ v_v, const int* __restrict__ ei,
    const int* __restrict__ offs, const int* __restrict__ eord,
    float* __restrict__ out_s, float* __restrict__ out_v)
{
  __shared__ float attn_lds[MAXDEG][H_HEADS];
  __shared__ float av_lds[MAXDEG];
  __shared__ int col_lds[MAXDEG];
  __shared__ float m_sh[H_HEADS], inv_sh[H_HEADS];

  int n = blockIdx.x;
  int beg = offs[n];
  int deg = offs[n + 1] - beg;
  int tid = threadIdx.x;
  bool fits = (deg <= MAXDEG);

  if (tid < 64) {
    int lane = tid;
    float lm[H_HEADS];
    #pragma unroll
    for (int h = 0; h < H_HEADS; ++h) lm[h] = -INFINITY;
    for (int i = lane; i < deg; i += 64) {
      int e = eord[beg + i];
      if (fits) col_lds[i] = ei[E_EDGES + e];
      #pragma unroll
      for (int h = 0; h < H_HEADS; ++h)
        lm[h] = fmaxf(lm[h], logits[(size_t)e * H_HEADS + h]);
    }
    #pragma unroll
    for (int h = 0; h < H_HEADS; ++h) lm[h] = wave_max(lm[h]);

    float ls[H_HEADS];
    #pragma unroll
    for (int h = 0; h < H_HEADS; ++h) ls[h] = 0.f;
    for (int i = lane; i < deg; i += 64) {
      int e = eord[beg + i];
      #pragma unroll
      for (int h = 0; h < H_HEADS; ++h) {
        float w = expf(logits[(size_t)e * H_HEADS + h] - lm[h]);
        ls[h] += w;
        if (fits) attn_lds[i][h] = w;
      }
    }
    #pragma unroll
    for (int h = 0; h < H_HEADS; ++h) ls[h] = wave_sum(ls[h]);

    float inv[H_HEADS];
    #pragma unroll
    for (int h = 0; h < H_HEADS; ++h) inv[h] = 1.f / (ls[h] + 1e-9f);
    if (lane == 0) {
      #pragma unroll
      for (int h = 0; h < H_HEADS; ++h) { m_sh[h] = lm[h]; inv_sh[h] = inv[h]; }
    }
    if (fits) {
      for (int i = lane; i < deg; i += 64) {
        float a = 0.f;
        #pragma unroll
        for (int h = 0; h < H_HEADS; ++h) a += attn_lds[i][h] * inv[h];
        av_lds[i] = 0.125f * a;
      }
    }
  }
  __syncthreads();

  float acc0 = 0.f, acc1 = 0.f, accv0 = 0.f, accv1 = 0.f;
  int h0 = tid >> 6, h1 = h0 + 4;
  for (int i = 0; i < deg; ++i) {
    int colv;
    float w0, w1, av;
    if (fits) {
      colv = col_lds[i];
      w0 = attn_lds[i][h0] * inv_sh[h0];
      w1 = attn_lds[i][h1] * inv_sh[h1];
      av = av_lds[i];
    } else {
      int e = eord[beg + i];
      colv = ei[E_EDGES + e];
      w0 = expf(logits[(size_t)e * H_HEADS + h0] - m_sh[h0]) * inv_sh[h0];
      w1 = expf(logits[(size_t)e * H_HEADS + h1] - m_sh[h1]) * inv_sh[h1];
      float a = 0.f;
      #pragma unroll
      for (int h = 0; h < H_HEADS; ++h)
        a += expf(logits[(size_t)e * H_HEADS + h] - m_sh[h]) * inv_sh[h];
      av = 0.125f * a;
    }
    const float* vs = v_s + (size_t)colv * S_DIM;
    const float* vv = v_v + (size_t)colv * NV3;
    acc0 += w0 * vs[tid];
    acc1 += w1 * vs[256 + tid];
    accv0 += av * vv[tid];
    if (tid < 128) accv1 += av * vv[256 + tid];
  }
  out_s[(size_t)n * S_DIM + tid] = acc0;
  out_s[(size_t)n * S_DIM + 256 + tid] = acc1;
  out_v[(size_t)n * NV3 + tid] = accv0;
  if (tid < 128) out_v[(size_t)n * NV3 + 256 + tid] = accv1;
}

// -------- residual + LayerNorm (wave per row) --------
__global__ __launch_bounds__(256) void ln_kernel(
    const float* __restrict__ x0, const float* __restrict__ dx,
    const float* __restrict__ g, const float* __restrict__ b,
    float* __restrict__ out)
{
  int r = blockIdx.x * 4 + (threadIdx.x >> 6);
  int lane = threadIdx.x & 63;
  if (r >= N_NODES) return;
  float x[8];
  float s = 0.f;
  #pragma unroll
  for (int j = 0; j < 8; ++j) {
    int d = lane + j * 64;
    x[j] = x0[(size_t)r * S_DIM + d] + dx[(size_t)r * S_DIM + d];
    s += x[j];
  }
  s = wave_sum(s);
  float mu = s * (1.f / 512.f);
  float vs = 0.f;
  #pragma unroll
  for (int j = 0; j < 8; ++j) { float t = x[j] - mu; vs += t * t; }
  vs = wave_sum(vs);
  float inv = rsqrtf(vs * (1.f / 512.f) + 1e-5f);
  #pragma unroll
  for (int j = 0; j < 8; ++j) {
    int d = lane + j * 64;
    out[(size_t)r * S_DIM + d] = (x[j] - mu) * inv * g[d] + b[d];
  }
}

extern "C" void kernel_launch(void* const* d_in, const int* in_sizes, int n_in,
                              void* d_out, int out_size, void* d_ws, size_t ws_size,
                              hipStream_t stream)
{
  (void)in_sizes; (void)n_in; (void)out_size; (void)ws_size;
  const float* scalars  = (const float*)d_in[0];
  const float* vectors  = (const float*)d_in[1];
  const float* edge_vec = (const float*)d_in[2];
  const float* Wq_s = (const float*)d_in[3];
  const float* bq_s = (const float*)d_in[4];
  const float* Wk_s = (const float*)d_in[5];
  const float* bk_s = (const float*)d_in[6];
  const float* Wv_s = (const float*)d_in[7];
  const float* bv_s = (const float*)d_in[8];
  const float* Wq_v = (const float*)d_in[9];
  const float* Wk_v = (const float*)d_in[10];
  const float* Wv_v = (const float*)d_in[11];
  const float* Wout_s = (const float*)d_in[12];
  const float* bout_s = (const float*)d_in[13];
  const float* Wout_v = (const float*)d_in[14];
  const float* bout_v = (const float*)d_in[15];
  const float* W_edge = (const float*)d_in[16];
  const float* b_edge = (const float*)d_in[17];
  const float* ln_g = (const float*)d_in[18];
  const float* ln_b = (const float*)d_in[19];
  const int* ei = (const int*)d_in[20];

  float* out = (float*)d_out;
  const size_t NS = (size_t)N_NODES * S_DIM;     // 5,120,000
  const size_t NVs = (size_t)N_NODES * NV3;      // 3,840,000
  const size_t EH = (size_t)E_EDGES * H_HEADS;   // 1,280,000

  float* ws = (float*)d_ws;
  float* bufA0 = ws;             // q_s  -> out_s_pre
  float* bufA1 = bufA0 + NS;     // k_s  -> out_s_post
  float* bufA2 = bufA1 + NS;     // v_s
  float* bufB0 = bufA2 + NS;     // q_v  -> out_v_pre
  float* bufB1 = bufB0 + NVs;    // k_v
  float* bufB2 = bufB1 + NVs;    // v_v
  float* logitsBuf = bufB2 + NVs;
  int* counts = (int*)(logitsBuf + EH);
  int* offs   = counts + N_NODES;
  int* cursor = offs + N_NODES + 1;
  int* eord   = cursor + N_NODES;

  hipMemsetAsync(counts, 0, N_NODES * sizeof(int), stream);
  hipMemsetAsync(cursor, 0, N_NODES * sizeof(int), stream);

  dim3 gemmGrid(S_DIM / BN, (N_NODES + BM - 1) / BM);
  gemm_f32_kernel<<<gemmGrid, 256, 0, stream>>>(scalars, Wq_s, bq_s, bufA0, N_NODES, S_DIM, S_DIM);
  gemm_f32_kernel<<<gemmGrid, 256, 0, stream>>>(scalars, Wk_s, bk_s, bufA1, N_NODES, S_DIM, S_DIM);
  gemm_f32_kernel<<<gemmGrid, 256, 0, stream>>>(scalars, Wv_s, bv_s, bufA2, N_NODES, S_DIM, S_DIM);
  vec_gemm_kernel<<<N_NODES, 128, 0, stream>>>(vectors, Wq_v, nullptr, nullptr, bufB0);
  vec_gemm_kernel<<<N_NODES, 128, 0, stream>>>(vectors, Wk_v, nullptr, nullptr, bufB1);
  vec_gemm_kernel<<<N_NODES, 128, 0, stream>>>(vectors, Wv_v, nullptr, nullptr, bufB2);

  edge_logits_kernel<<<E_EDGES / 4, 256, 0, stream>>>(bufA0, bufA1, bufB0, bufB1,
                                                      edge_vec, ei, W_edge, b_edge, logitsBuf);

  count_kernel<<<(E_EDGES + 255) / 256, 256, 0, stream>>>(ei, counts);
  scan_kernel<<<1, 256, 0, stream>>>(counts, offs);
  scatter_kernel<<<(E_EDGES + 255) / 256, 256, 0, stream>>>(ei, offs, cursor, eord);

  agg_kernel<<<N_NODES, 256, 0, stream>>>(logitsBuf, bufA2, bufB2, ei, offs, eord,
                                          bufA0, bufB0);

  gemm_f32_kernel<<<gemmGrid, 256, 0, stream>>>(bufA0, Wout_s, bout_s, bufA1, N_NODES, S_DIM, S_DIM);
  vec_gemm_kernel<<<N_NODES, 128, 0, stream>>>(bufB0, Wout_v, bout_v, vectors, out + NS);
  ln_kernel<<<2500, 256, 0, stream>>>(scalars, bufA1, ln_g, ln_b, out);
}

// Round 2
// 679.954 us; speedup vs baseline: 1.3342x; 1.3342x over previous
//
#include <hip/hip_runtime.h>
#include <math.h>

#define N_NODES 10000
#define E_EDGES 160000
#define S_DIM 512
#define V_DIM 128
#define H_HEADS 8
#define R_BASIS 32
#define HD_DIM 64
#define NV3 (V_DIM*3)   // 384

typedef __bf16 bf16_t;
typedef bf16_t bf16x8 __attribute__((ext_vector_type(8)));
typedef float f32x4 __attribute__((ext_vector_type(4)));

static __device__ __forceinline__ float bf2f(unsigned int u) {
  return __uint_as_float(u << 16);
}
static __device__ __forceinline__ unsigned short f2bf(float f) {
  unsigned int u = __float_as_uint(f);
  u += 0x7fffu + ((u >> 16) & 1u);
  return (unsigned short)(u >> 16);
}
static __device__ __forceinline__ float wave_sum(float v) {
  #pragma unroll
  for (int o = 32; o > 0; o >>= 1) v += __shfl_xor(v, o, 64);
  return v;
}
static __device__ __forceinline__ float wave_max(float v) {
  #pragma unroll
  for (int o = 32; o > 0; o >>= 1) v = fmaxf(v, __shfl_xor(v, o, 64));
  return v;
}
static __device__ __forceinline__ float dot8(int4 a, int4 b) {
  float s = 0.f;
  unsigned int aw[4] = {(unsigned)a.x, (unsigned)a.y, (unsigned)a.z, (unsigned)a.w};
  unsigned int bw[4] = {(unsigned)b.x, (unsigned)b.y, (unsigned)b.z, (unsigned)b.w};
  #pragma unroll
  for (int i = 0; i < 4; ++i) {
    s = fmaf(bf2f(aw[i] & 0xffffu), bf2f(bw[i] & 0xffffu), s);
    s = fmaf(bf2f(aw[i] >> 16),     bf2f(bw[i] >> 16),     s);
  }
  return s;
}

// ---------------- f32 -> bf16 flat convert (float4 -> ushort4) ----------------
__global__ __launch_bounds__(256) void f32_to_bf16_kernel(
    const float* __restrict__ in, unsigned short* __restrict__ out, int n4)
{
  int i = blockIdx.x * 256 + threadIdx.x;
  if (i < n4) {
    float4 v = reinterpret_cast<const float4*>(in)[i];
    ushort4 o;
    o.x = f2bf(v.x); o.y = f2bf(v.y); o.z = f2bf(v.z); o.w = f2bf(v.w);
    reinterpret_cast<ushort4*>(out)[i] = o;
  }
}

// ---------------- W (f32 [K][N]) -> W^T (bf16 [N][K]), K=N=512 ----------------
__global__ __launch_bounds__(256) void transpose_bf16_kernel(
    const float* __restrict__ W, unsigned short* __restrict__ Wt)
{
  __shared__ float t[32][33];
  int n0 = blockIdx.x * 32, k0 = blockIdx.y * 32;
  int x = threadIdx.x, y = threadIdx.y;   // 32 x 8
  #pragma unroll
  for (int j = 0; j < 32; j += 8)
    t[y + j][x] = W[(size_t)(k0 + y + j) * S_DIM + n0 + x];
  __syncthreads();
  #pragma unroll
  for (int j = 0; j < 32; j += 8)
    Wt[(size_t)(n0 + y + j) * S_DIM + k0 + x] = f2bf(t[x][y + j]);
}

// ---------------- bf16 MFMA GEMM: C = A[M][K] @ Bt[N][K]^T + bias ----------------
// 128x128 tile, BK=32, 4 waves (2x2), each wave 64x64 = 4x4 frags of 16x16x32.
__global__ __launch_bounds__(256) void gemm_bf16_kernel(
    const unsigned short* __restrict__ A, const unsigned short* __restrict__ Bt,
    const float* __restrict__ bias, float* __restrict__ Cf,
    unsigned short* __restrict__ Cb, int M, int K, int Nn)
{
  __shared__ unsigned short At[128 * 32];
  __shared__ unsigned short Bs[128 * 32];
  int tid = threadIdx.x;
  int wid = tid >> 6, lane = tid & 63;
  int wr = wid >> 1, wc = wid & 1;
  int row0 = blockIdx.y * 128, col0 = blockIdx.x * 128;

  const f32x4 zero = {0.f, 0.f, 0.f, 0.f};
  f32x4 acc[4][4];
  #pragma unroll
  for (int m = 0; m < 4; ++m)
    #pragma unroll
    for (int n = 0; n < 4; ++n) acc[m][n] = zero;

  int lr = lane & 15;
  int lk = (lane >> 4) * 8;

  for (int k0 = 0; k0 < K; k0 += 32) {
    int4 areg[2], breg[2];
    #pragma unroll
    for (int p = 0; p < 2; ++p) {
      int idx = tid + 256 * p;          // 0..511, 16B chunks of the 8KB tile
      int r = idx >> 2;                 // 0..127
      int kc = (idx & 3) * 8;           // 0,8,16,24
      int gr = row0 + r; if (gr >= M) gr = M - 1;
      areg[p] = *reinterpret_cast<const int4*>(A  + (size_t)gr * K + k0 + kc);
      breg[p] = *reinterpret_cast<const int4*>(Bt + (size_t)(col0 + r) * K + k0 + kc);
    }
    __syncthreads();
    #pragma unroll
    for (int p = 0; p < 2; ++p) {
      int idx = tid + 256 * p;
      *reinterpret_cast<int4*>(At + idx * 8) = areg[p];
      *reinterpret_cast<int4*>(Bs + idx * 8) = breg[p];
    }
    __syncthreads();

    bf16x8 af[4], bfr[4];
    #pragma unroll
    for (int m = 0; m < 4; ++m)
      af[m] = *reinterpret_cast<const bf16x8*>(At + (wr * 64 + m * 16 + lr) * 32 + lk);
    #pragma unroll
    for (int n = 0; n < 4; ++n)
      bfr[n] = *reinterpret_cast<const bf16x8*>(Bs + (wc * 64 + n * 16 + lr) * 32 + lk);
    #pragma unroll
    for (int m = 0; m < 4; ++m)
      #pragma unroll
      for (int n = 0; n < 4; ++n)
        acc[m][n] = __builtin_amdgcn_mfma_f32_16x16x32_bf16(af[m], bfr[n], acc[m][n], 0, 0, 0);
  }

  int lq = lane >> 4;
  #pragma unroll
  for (int m = 0; m < 4; ++m) {
    #pragma unroll
    for (int j = 0; j < 4; ++j) {
      int row = row0 + wr * 64 + m * 16 + lq * 4 + j;
      if (row < M) {
        #pragma unroll
        for (int n = 0; n < 4; ++n) {
          int col = col0 + wc * 64 + n * 16 + lr;
          float v = acc[m][n][j] + (bias ? bias[col] : 0.f);
          if (Cf) Cf[(size_t)row * Nn + col] = v;
          else    Cb[(size_t)row * Nn + col] = f2bf(v);
        }
      }
    }
  }
}

// -------- vector-channel GEMMs --------
__global__ __launch_bounds__(128) void vec_gemm_qkv_kernel(
    const float* __restrict__ A, const float* __restrict__ W,
    unsigned short* __restrict__ outb)
{
  __shared__ float As[NV3];
  int n = blockIdx.x, w = threadIdx.x;
  for (int j = w; j < NV3; j += 128) As[j] = A[(size_t)n * NV3 + j];
  __syncthreads();
  float a0 = 0.f, a1 = 0.f, a2 = 0.f;
  #pragma unroll 4
  for (int v = 0; v < V_DIM; ++v) {
    float wv = W[v * V_DIM + w];
    a0 = fmaf(As[v * 3 + 0], wv, a0);
    a1 = fmaf(As[v * 3 + 1], wv, a1);
    a2 = fmaf(As[v * 3 + 2], wv, a2);
  }
  size_t base = (size_t)n * NV3 + (size_t)w * 3;
  outb[base + 0] = f2bf(a0);
  outb[base + 1] = f2bf(a1);
  outb[base + 2] = f2bf(a2);
}

__global__ __launch_bounds__(128) void vec_gemm_final_kernel(
    const unsigned short* __restrict__ A, const float* __restrict__ W,
    const float* __restrict__ bias, const float* __restrict__ res,
    float* __restrict__ out)
{
  __shared__ float As[NV3];
  int n = blockIdx.x, w = threadIdx.x;
  for (int j = w; j < NV3; j += 128) As[j] = bf2f(A[(size_t)n * NV3 + j]);
  __syncthreads();
  float a0 = 0.f, a1 = 0.f, a2 = 0.f;
  #pragma unroll 4
  for (int v = 0; v < V_DIM; ++v) {
    float wv = W[v * V_DIM + w];
    a0 = fmaf(As[v * 3 + 0], wv, a0);
    a1 = fmaf(As[v * 3 + 1], wv, a1);
    a2 = fmaf(As[v * 3 + 2], wv, a2);
  }
  size_t base = (size_t)n * NV3 + (size_t)w * 3;
  float b = bias[w];
  out[base + 0] = a0 + b + res[base + 0];
  out[base + 1] = a1 + b + res[base + 1];
  out[base + 2] = a2 + b + res[base + 2];
}

// -------- CSR build --------
__global__ void count_kernel(const int* __restrict__ ei, int* __restrict__ counts) {
  int e = blockIdx.x * 256 + threadIdx.x;
  if (e < E_EDGES) atomicAdd(&counts[ei[e]], 1);
}

__global__ __launch_bounds__(256) void scan_kernel(const int* __restrict__ counts,
                                                   int* __restrict__ offs) {
  __shared__ int tmp[256];
  __shared__ int carry_s;
  int tid = threadIdx.x;
  if (tid == 0) carry_s = 0;
  __syncthreads();
  for (int base = 0; base < N_NODES; base += 256) {
    int i = base + tid;
    int v = (i < N_NODES) ? counts[i] : 0;
    tmp[tid] = v;
    __syncthreads();
    for (int o = 1; o < 256; o <<= 1) {
      int t = (tid >= o) ? tmp[tid - o] : 0;
      __syncthreads();
      tmp[tid] += t;
      __syncthreads();
    }
    int incl = tmp[tid];
    int c = carry_s;
    if (i < N_NODES) offs[i] = c + incl - v;
    __syncthreads();
    if (tid == 255) carry_s = c + tmp[255];
    __syncthreads();
  }
  if (tid == 0) offs[N_NODES] = carry_s;
}

__global__ void scatter_kernel(const int* __restrict__ ei, const int* __restrict__ offs,
                               int* __restrict__ cursor, int* __restrict__ eord) {
  int e = blockIdx.x * 256 + threadIdx.x;
  if (e < E_EDGES) {
    int r = ei[e];
    int p = offs[r] + atomicAdd(&cursor[r], 1);
    eord[p] = e;
  }
}

// -------- per-edge logits in CSR order; outputs at sorted position --------
__global__ __launch_bounds__(256) void edge_logits_kernel(
    const unsigned short* __restrict__ q_s, const unsigned short* __restrict__ k_s,
    const unsigned short* __restrict__ q_v, const unsigned short* __restrict__ k_v,
    const float* __restrict__ edge_vec, const int* __restrict__ ei,
    const int* __restrict__ eord,
    const float* __restrict__ W_edge, const float* __restrict__ b_edge,
    float* __restrict__ logits, int* __restrict__ cols)
{
  const float PI_F = 3.14159265358979323846f;
  int pos = blockIdx.x * 4 + (threadIdx.x >> 6);
  int lane = threadIdx.x & 63;
  if (pos >= E_EDGES) return;
  int e = eord[pos];
  int row = ei[e];
  int col = ei[E_EDGES + e];

  // scalar attention: lane l covers dims l*8..l*8+8 -> head = l>>3
  int4 qa = *reinterpret_cast<const int4*>(q_s + (size_t)row * S_DIM + lane * 8);
  int4 ka = *reinterpret_cast<const int4*>(k_s + (size_t)col * S_DIM + lane * 8);
  float p = dot8(qa, ka);
  p += __shfl_xor(p, 1, 64);
  p += __shfl_xor(p, 2, 64);
  p += __shfl_xor(p, 4, 64);
  float qk = __shfl(p, (lane * 8) & 63, 64);  // lane<8: dot for head=lane

  // vector attention: 384 dims = 48 lanes x 8
  float pv = 0.f;
  if (lane < 48) {
    int4 qv = *reinterpret_cast<const int4*>(q_v + (size_t)row * NV3 + lane * 8);
    int4 kv = *reinterpret_cast<const int4*>(k_v + (size_t)col * NV3 + lane * 8);
    pv = dot8(qv, kv);
  }
  pv = wave_sum(pv) * 0.57735026918962576f;

  // bessel basis + edge MLP
  float ex = edge_vec[(size_t)e * 3 + 0];
  float ey = edge_vec[(size_t)e * 3 + 1];
  float ez = edge_vec[(size_t)e * 3 + 2];
  float d = sqrtf(ex * ex + ey * ey + ez * ez);
  float basis = 0.f;
  if (lane < R_BASIS) {
    float freq = (lane + 1) * (PI_F / 10.0f);
    float cut = (d < 10.0f) ? 0.5f * (cosf(PI_F * d * 0.1f) + 1.0f) : 0.f;
    basis = sinf(freq * d) / fmaxf(d, 1e-8f) * cut;
  }
  float eah = 0.f;
  #pragma unroll
  for (int h = 0; h < H_HEADS; ++h) {
    float t = (lane < R_BASIS) ? basis * W_edge[lane * H_HEADS + h] : 0.f;
    float s = wave_sum(t);
    if (lane == h) eah = s + b_edge[h];
  }

  if (lane < 8) logits[(size_t)pos * H_HEADS + lane] = (qk + pv + eah) * 0.125f;
  if (lane == 8) cols[pos] = col;
}

// -------- per-node softmax + aggregation --------
#define MAXDEG 512
__global__ __launch_bounds__(256) void agg_kernel(
    const float* __restrict__ logits, const int* __restrict__ cols,
    const unsigned short* __restrict__ v_s, const unsigned short* __restrict__ v_v,
    const int* __restrict__ offs,
    unsigned short* __restrict__ out_s, unsigned short* __restrict__ out_v)
{
  __shared__ float attn_lds[MAXDEG][H_HEADS];
  __shared__ float av_lds[MAXDEG];
  __shared__ int col_lds[MAXDEG];
  __shared__ float m_sh[H_HEADS], inv_sh[H_HEADS];

  int n = blockIdx.x;
  int beg = offs[n];
  int deg = offs[n + 1] - beg;
  int tid = threadIdx.x;
  bool fits = (deg <= MAXDEG);

  if (tid < 64) {
    int lane = tid;
    float lm[H_HEADS];
    #pragma unroll
    for (int h = 0; h < H_HEADS; ++h) lm[h] = -INFINITY;
    for (int i = lane; i < deg; i += 64) {
      const float4* lp = reinterpret_cast<const float4*>(logits + (size_t)(beg + i) * 8);
      float4 a = lp[0], b = lp[1];
      if (fits) col_lds[i] = cols[beg + i];
      lm[0] = fmaxf(lm[0], a.x); lm[1] = fmaxf(lm[1], a.y);
      lm[2] = fmaxf(lm[2], a.z); lm[3] = fmaxf(lm[3], a.w);
      lm[4] = fmaxf(lm[4], b.x); lm[5] = fmaxf(lm[5], b.y);
      lm[6] = fmaxf(lm[6], b.z); lm[7] = fmaxf(lm[7], b.w);
    }
    #pragma unroll
    for (int h = 0; h < H_HEADS; ++h) lm[h] = wave_max(lm[h]);

    float ls[H_HEADS];
    #pragma unroll
    for (int h = 0; h < H_HEADS; ++h) ls[h] = 0.f;
    for (int i = lane; i < deg; i += 64) {
      const float4* lp = reinterpret_cast<const float4*>(logits + (size_t)(beg + i) * 8);
      float4 a = lp[0], b = lp[1];
      float w[8];
      w[0] = expf(a.x - lm[0]); w[1] = expf(a.y - lm[1]);
      w[2] = expf(a.z - lm[2]); w[3] = expf(a.w - lm[3]);
      w[4] = expf(b.x - lm[4]); w[5] = expf(b.y - lm[5]);
      w[6] = expf(b.z - lm[6]); w[7] = expf(b.w - lm[7]);
      #pragma unroll
      for (int h = 0; h < H_HEADS; ++h) {
        ls[h] += w[h];
        if (fits) attn_lds[i][h] = w[h];
      }
    }
    #pragma unroll
    for (int h = 0; h < H_HEADS; ++h) ls[h] = wave_sum(ls[h]);

    float inv[H_HEADS];
    #pragma unroll
    for (int h = 0; h < H_HEADS; ++h) inv[h] = 1.f / (ls[h] + 1e-9f);
    if (lane == 0) {
      #pragma unroll
      for (int h = 0; h < H_HEADS; ++h) { m_sh[h] = lm[h]; inv_sh[h] = inv[h]; }
    }
    if (fits) {
      for (int i = lane; i < deg; i += 64) {
        float a = 0.f;
        #pragma unroll
        for (int h = 0; h < H_HEADS; ++h) a += attn_lds[i][h] * inv[h];
        av_lds[i] = 0.125f * a;
      }
    }
  }
  __syncthreads();

  // accumulation: thread tid owns scalar dims 2*tid, 2*tid+1 (head = tid>>5)
  // and vector dims 2*tid, 2*tid+1 for tid<192.
  int h = tid >> 5;
  float mh = m_sh[h], ih = inv_sh[h];
  float a0 = 0.f, a1 = 0.f, b0 = 0.f, b1 = 0.f;
  for (int i = 0; i < deg; ++i) {
    int colv;
    float w, av;
    if (fits) {
      colv = col_lds[i];
      w = attn_lds[i][h] * ih;
      av = av_lds[i];
    } else {
      colv = cols[beg + i];
      const float* lp = logits + (size_t)(beg + i) * 8;
      w = expf(lp[h] - mh) * ih;
      float a = 0.f;
      #pragma unroll
      for (int hh = 0; hh < H_HEADS; ++hh)
        a += expf(lp[hh] - m_sh[hh]) * inv_sh[hh];
      av = 0.125f * a;
    }
    ushort2 vs = *reinterpret_cast<const ushort2*>(v_s + (size_t)colv * S_DIM + 2 * tid);
    a0 = fmaf(w, bf2f(vs.x), a0);
    a1 = fmaf(w, bf2f(vs.y), a1);
    if (tid < 192) {
      ushort2 vv = *reinterpret_cast<const ushort2*>(v_v + (size_t)colv * NV3 + 2 * tid);
      b0 = fmaf(av, bf2f(vv.x), b0);
      b1 = fmaf(av, bf2f(vv.y), b1);
    }
  }
  ushort2 os; os.x = f2bf(a0); os.y = f2bf(a1);
  *reinterpret_cast<ushort2*>(out_s + (size_t)n * S_DIM + 2 * tid) = os;
  if (tid < 192) {
    ushort2 ov; ov.x = f2bf(b0); ov.y = f2bf(b1);
    *reinterpret_cast<ushort2*>(out_v + (size_t)n * NV3 + 2 * tid) = ov;
  }
}

// -------- residual + LayerNorm (wave per row) --------
__global__ __launch_bounds__(256) void ln_kernel(
    const float* __restrict__ x0, const float* __restrict__ dx,
    const float* __restrict__ g, const float* __restrict__ b,
    float* __restrict__ out)
{
  int r = blockIdx.x * 4 + (threadIdx.x >> 6);
  int lane = threadIdx.x & 63;
  if (r >= N_NODES) return;
  float x[8];
  float s = 0.f;
  #pragma unroll
  for (int j = 0; j < 8; ++j) {
    int d = lane + j * 64;
    x[j] = x0[(size_t)r * S_DIM + d] + dx[(size_t)r * S_DIM + d];
    s += x[j];
  }
  s = wave_sum(s);
  float mu = s * (1.f / 512.f);
  float vs = 0.f;
  #pragma unroll
  for (int j = 0; j < 8; ++j) { float t = x[j] - mu; vs += t * t; }
  vs = wave_sum(vs);
  float inv = rsqrtf(vs * (1.f / 512.f) + 1e-5f);
  #pragma unroll
  for (int j = 0; j < 8; ++j) {
    int d = lane + j * 64;
    out[(size_t)r * S_DIM + d] = (x[j] - mu) * inv * g[d] + b[d];
  }
}

extern "C" void kernel_launch(void* const* d_in, const int* in_sizes, int n_in,
                              void* d_out, int out_size, void* d_ws, size_t ws_size,
                              hipStream_t stream)
{
  (void)in_sizes; (void)n_in; (void)out_size; (void)ws_size;
  const float* scalars  = (const float*)d_in[0];
  const float* vectors  = (const float*)d_in[1];
  const float* edge_vec = (const float*)d_in[2];
  const float* Wq_s = (const float*)d_in[3];
  const float* bq_s = (const float*)d_in[4];
  const float* Wk_s = (const float*)d_in[5];
  const float* bk_s = (const float*)d_in[6];
  const float* Wv_s = (const float*)d_in[7];
  const float* bv_s = (const float*)d_in[8];
  const float* Wq_v = (const float*)d_in[9];
  const float* Wk_v = (const float*)d_in[10];
  const float* Wv_v = (const float*)d_in[11];
  const float* Wout_s = (const float*)d_in[12];
  const float* bout_s = (const float*)d_in[13];
  const float* Wout_v = (const float*)d_in[14];
  const float* bout_v = (const float*)d_in[15];
  const float* W_edge = (const float*)d_in[16];
  const float* b_edge = (const float*)d_in[17];
  const float* ln_g = (const float*)d_in[18];
  const float* ln_b = (const float*)d_in[19];
  const int* ei = (const int*)d_in[20];

  float* out = (float*)d_out;
  const size_t NS  = (size_t)N_NODES * S_DIM;   // 5,120,000
  const size_t NVs = (size_t)N_NODES * NV3;     // 3,840,000
  const size_t EH  = (size_t)E_EDGES * H_HEADS; // 1,280,000
  const size_t WSZ = (size_t)S_DIM * S_DIM;     // 262,144

  char* base = (char*)d_ws;
  auto carve = [&](size_t bytes) -> char* {
    char* p = base;
    base += (bytes + 255) & ~(size_t)255;
    return p;
  };
  unsigned short* Abf      = (unsigned short*)carve(NS * 2);
  unsigned short* q_s      = (unsigned short*)carve(NS * 2);
  unsigned short* k_s      = (unsigned short*)carve(NS * 2);
  unsigned short* v_s      = (unsigned short*)carve(NS * 2);
  unsigned short* q_v      = (unsigned short*)carve(NVs * 2);
  unsigned short* k_v      = (unsigned short*)carve(NVs * 2);
  unsigned short* v_v      = (unsigned short*)carve(NVs * 2);
  unsigned short* outs_pre = (unsigned short*)carve(NS * 2);
  unsigned short* outv_pre = (unsigned short*)carve(NVs * 2);
  float* dx       = (float*)carve(NS * 4);
  float* logitsS  = (float*)carve(EH * 4);
  int*   colsS    = (int*)carve(E_EDGES * 4);
  unsigned short* WqT = (unsigned short*)carve(WSZ * 2);
  unsigned short* WkT = (unsigned short*)carve(WSZ * 2);
  unsigned short* WvT = (unsigned short*)carve(WSZ * 2);
  unsigned short* WoT = (unsigned short*)carve(WSZ * 2);
  int* counts = (int*)carve(N_NODES * 4);
  int* offs   = (int*)carve((N_NODES + 1) * 4);
  int* cursor = (int*)carve(N_NODES * 4);
  int* eord   = (int*)carve(E_EDGES * 4);

  hipMemsetAsync(counts, 0, N_NODES * sizeof(int), stream);
  hipMemsetAsync(cursor, 0, N_NODES * sizeof(int), stream);

  // bf16 conversions
  f32_to_bf16_kernel<<<(int)(NS / 4 + 255) / 256, 256, 0, stream>>>(scalars, Abf, (int)(NS / 4));
  dim3 tGrid(16, 16), tBlk(32, 8);
  transpose_bf16_kernel<<<tGrid, tBlk, 0, stream>>>(Wq_s, WqT);
  transpose_bf16_kernel<<<tGrid, tBlk, 0, stream>>>(Wk_s, WkT);
  transpose_bf16_kernel<<<tGrid, tBlk, 0, stream>>>(Wv_s, WvT);
  transpose_bf16_kernel<<<tGrid, tBlk, 0, stream>>>(Wout_s, WoT);

  // scalar projections (MFMA)
  dim3 gemmGrid(S_DIM / 128, (N_NODES + 127) / 128);
  gemm_bf16_kernel<<<gemmGrid, 256, 0, stream>>>(Abf, WqT, bq_s, nullptr, q_s, N_NODES, S_DIM, S_DIM);
  gemm_bf16_kernel<<<gemmGrid, 256, 0, stream>>>(Abf, WkT, bk_s, nullptr, k_s, N_NODES, S_DIM, S_DIM);
  gemm_bf16_kernel<<<gemmGrid, 256, 0, stream>>>(Abf, WvT, bv_s, nullptr, v_s, N_NODES, S_DIM, S_DIM);

  // vector projections
  vec_gemm_qkv_kernel<<<N_NODES, 128, 0, stream>>>(vectors, Wq_v, q_v);
  vec_gemm_qkv_kernel<<<N_NODES, 128, 0, stream>>>(vectors, Wk_v, k_v);
  vec_gemm_qkv_kernel<<<N_NODES, 128, 0, stream>>>(vectors, Wv_v, v_v);

  // CSR
  count_kernel<<<(E_EDGES + 255) / 256, 256, 0, stream>>>(ei, counts);
  scan_kernel<<<1, 256, 0, stream>>>(counts, offs);
  scatter_kernel<<<(E_EDGES + 255) / 256, 256, 0, stream>>>(ei, offs, cursor, eord);

  // edge logits in CSR order
  edge_logits_kernel<<<E_EDGES / 4, 256, 0, stream>>>(q_s, k_s, q_v, k_v, edge_vec,
                                                      ei, eord, W_edge, b_edge,
                                                      logitsS, colsS);

  // softmax + aggregate
  agg_kernel<<<N_NODES, 256, 0, stream>>>(logitsS, colsS, v_s, v_v, offs,
                                          outs_pre, outv_pre);

  // output projections + epilogues
  gemm_bf16_kernel<<<gemmGrid, 256, 0, stream>>>(outs_pre, WoT, bout_s, dx, nullptr, N_NODES, S_DIM, S_DIM);
  vec_gemm_final_kernel<<<N_NODES, 128, 0, stream>>>(outv_pre, Wout_v, bout_v, vectors, out + NS);
  ln_kernel<<<2500, 256, 0, stream>>>(scalars, dx, ln_g, ln_b, out);
}

// Round 3
// 518.601 us; speedup vs baseline: 1.7493x; 1.3111x over previous
//
#include <hip/hip_runtime.h>
#include <math.h>

#define N_NODES 10000
#define E_EDGES 160000
#define S_DIM 512
#define V_DIM 128
#define H_HEADS 8
#define R_BASIS 32
#define HD_DIM 64
#define NV3 (V_DIM*3)   // 384

typedef _Float16 f16;
typedef f16 f16x2 __attribute__((ext_vector_type(2)));
typedef f16 f16x8 __attribute__((ext_vector_type(8)));
typedef float f32x4 __attribute__((ext_vector_type(4)));

static __device__ __forceinline__ float h2f(unsigned short u) {
  f16 h; __builtin_memcpy(&h, &u, 2); return (float)h;
}
static __device__ __forceinline__ unsigned short f2h(float f) {
  f16 h = (f16)f; unsigned short u; __builtin_memcpy(&u, &h, 2); return u;
}
static __device__ __forceinline__ float wave_sum(float v) {
  #pragma unroll
  for (int o = 32; o > 0; o >>= 1) v += __shfl_xor(v, o, 64);
  return v;
}
static __device__ __forceinline__ float wave_max(float v) {
  #pragma unroll
  for (int o = 32; o > 0; o >>= 1) v = fmaxf(v, __shfl_xor(v, o, 64));
  return v;
}
// dot of two int4s interpreted as 8 f16 each, f32 accumulate via v_dot2_f32_f16
static __device__ __forceinline__ float dot_i4(int4 a, int4 b, float s) {
  union U { int4 v; f16x2 h[4]; } ua, ub;
  ua.v = a; ub.v = b;
  #pragma unroll
  for (int j = 0; j < 4; ++j)
    s = __builtin_amdgcn_fdot2(ua.h[j], ub.h[j], s, false);
  return s;
}

// ---------------- f32 -> f16 flat convert ----------------
__global__ __launch_bounds__(256) void f32_to_f16_kernel(
    const float* __restrict__ in, unsigned short* __restrict__ out, int n4)
{
  int i = blockIdx.x * 256 + threadIdx.x;
  if (i < n4) {
    float4 v = reinterpret_cast<const float4*>(in)[i];
    ushort4 o;
    o.x = f2h(v.x); o.y = f2h(v.y); o.z = f2h(v.z); o.w = f2h(v.w);
    reinterpret_cast<ushort4*>(out)[i] = o;
  }
}

// ---------------- W (f32 [K][N]) -> W^T (f16 [N][K]), square D ----------------
__global__ __launch_bounds__(256) void transpose_f16_kernel(
    const float* __restrict__ W, unsigned short* __restrict__ Wt, int D)
{
  __shared__ float t[32][33];
  int n0 = blockIdx.x * 32, k0 = blockIdx.y * 32;
  int x = threadIdx.x, y = threadIdx.y;   // 32 x 8
  #pragma unroll
  for (int j = 0; j < 32; j += 8)
    t[y + j][x] = W[(size_t)(k0 + y + j) * D + n0 + x];
  __syncthreads();
  #pragma unroll
  for (int j = 0; j < 32; j += 8)
    Wt[(size_t)(n0 + y + j) * D + k0 + x] = f2h(t[x][y + j]);
}

// ---------------- vectors [n][128][3] f32 -> VT [(n*3+i)][128] f16 ----------------
__global__ __launch_bounds__(128) void vec_transpose_kernel(
    const float* __restrict__ vecs, unsigned short* __restrict__ VT)
{
  __shared__ float l[NV3];
  int n = blockIdx.x, t = threadIdx.x;
  #pragma unroll
  for (int j = 0; j < 3; ++j) l[t + j * 128] = vecs[(size_t)n * NV3 + t + j * 128];
  __syncthreads();
  #pragma unroll
  for (int i = 0; i < 3; ++i)
    VT[((size_t)n * 3 + i) * V_DIM + t] = f2h(l[t * 3 + i]);
}

// ---------------- f16 MFMA GEMM: C = A[M][K] @ Bt[N][K]^T + bias ----------------
// 128x128 tile, BK=32, 4 waves (2x2). LDS rows padded to 40 halves (80B).
#define ROWP 40
__global__ __launch_bounds__(256) void gemm_f16_kernel(
    const unsigned short* __restrict__ A, const unsigned short* __restrict__ Bt,
    const float* __restrict__ bias, float* __restrict__ Cf,
    unsigned short* __restrict__ Ch, int M, int K, int Nn)
{
  __shared__ unsigned short At[128 * ROWP];
  __shared__ unsigned short Bs[128 * ROWP];
  int tid = threadIdx.x;
  int wid = tid >> 6, lane = tid & 63;
  int wr = wid >> 1, wc = wid & 1;
  int row0 = blockIdx.y * 128, col0 = blockIdx.x * 128;

  const f32x4 zero = {0.f, 0.f, 0.f, 0.f};
  f32x4 acc[4][4];
  #pragma unroll
  for (int m = 0; m < 4; ++m)
    #pragma unroll
    for (int n = 0; n < 4; ++n) acc[m][n] = zero;

  int lr = lane & 15;
  int lk = (lane >> 4) * 8;

  for (int k0 = 0; k0 < K; k0 += 32) {
    int4 areg[2], breg[2];
    #pragma unroll
    for (int p = 0; p < 2; ++p) {
      int idx = tid + 256 * p;          // 0..511 16B chunks
      int r = idx >> 2;                 // 0..127
      int kc = (idx & 3) * 8;           // halves: 0,8,16,24
      int gr = row0 + r; if (gr >= M) gr = M - 1;
      areg[p] = *reinterpret_cast<const int4*>(A  + (size_t)gr * K + k0 + kc);
      breg[p] = *reinterpret_cast<const int4*>(Bt + (size_t)(col0 + r) * K + k0 + kc);
    }
    __syncthreads();
    #pragma unroll
    for (int p = 0; p < 2; ++p) {
      int idx = tid + 256 * p;
      int r = idx >> 2, kc = (idx & 3) * 8;
      *reinterpret_cast<int4*>(At + r * ROWP + kc) = areg[p];
      *reinterpret_cast<int4*>(Bs + r * ROWP + kc) = breg[p];
    }
    __syncthreads();

    f16x8 af[4], bfr[4];
    #pragma unroll
    for (int m = 0; m < 4; ++m)
      af[m] = *reinterpret_cast<const f16x8*>(At + (wr * 64 + m * 16 + lr) * ROWP + lk);
    #pragma unroll
    for (int n = 0; n < 4; ++n)
      bfr[n] = *reinterpret_cast<const f16x8*>(Bs + (wc * 64 + n * 16 + lr) * ROWP + lk);
    #pragma unroll
    for (int m = 0; m < 4; ++m)
      #pragma unroll
      for (int n = 0; n < 4; ++n)
        acc[m][n] = __builtin_amdgcn_mfma_f32_16x16x32_f16(af[m], bfr[n], acc[m][n], 0, 0, 0);
  }

  int lq = lane >> 4;
  #pragma unroll
  for (int m = 0; m < 4; ++m) {
    #pragma unroll
    for (int j = 0; j < 4; ++j) {
      int row = row0 + wr * 64 + m * 16 + lq * 4 + j;
      if (row < M) {
        #pragma unroll
        for (int n = 0; n < 4; ++n) {
          int col = col0 + wc * 64 + n * 16 + lr;
          float v = acc[m][n][j] + (bias ? bias[col] : 0.f);
          if (Cf) Cf[(size_t)row * Nn + col] = v;
          else    Ch[(size_t)row * Nn + col] = f2h(v);
        }
      }
    }
  }
}

// -------- CSR build --------
__global__ void count_kernel(const int* __restrict__ ei, int* __restrict__ counts) {
  int e = blockIdx.x * 256 + threadIdx.x;
  if (e < E_EDGES) atomicAdd(&counts[ei[e]], 1);
}

__global__ __launch_bounds__(256) void scan_kernel(const int* __restrict__ counts,
                                                   int* __restrict__ offs) {
  __shared__ int tmp[256];
  __shared__ int carry_s;
  int tid = threadIdx.x;
  if (tid == 0) carry_s = 0;
  __syncthreads();
  for (int base = 0; base < N_NODES; base += 256) {
    int i = base + tid;
    int v = (i < N_NODES) ? counts[i] : 0;
    tmp[tid] = v;
    __syncthreads();
    for (int o = 1; o < 256; o <<= 1) {
      int t = (tid >= o) ? tmp[tid - o] : 0;
      __syncthreads();
      tmp[tid] += t;
      __syncthreads();
    }
    int incl = tmp[tid];
    int c = carry_s;
    if (i < N_NODES) offs[i] = c + incl - v;
    __syncthreads();
    if (tid == 255) carry_s = c + tmp[255];
    __syncthreads();
  }
  if (tid == 0) offs[N_NODES] = carry_s;
}

__global__ void scatter_kernel(const int* __restrict__ ei, const int* __restrict__ offs,
                               int* __restrict__ cursor, int* __restrict__ eord) {
  int e = blockIdx.x * 256 + threadIdx.x;
  if (e < E_EDGES) {
    int r = ei[e];
    int p = offs[r] + atomicAdd(&cursor[r], 1);
    eord[p] = e;
  }
}

// -------- per-edge logits: 8 lanes per edge, lane = head, no big shuffles --------
__global__ __launch_bounds__(256) void edge_logits_kernel(
    const unsigned short* __restrict__ q_s, const unsigned short* __restrict__ k_s,
    const unsigned short* __restrict__ q_v, const unsigned short* __restrict__ k_v,
    const float* __restrict__ edge_vec, const int* __restrict__ ei,
    const int* __restrict__ eord,
    const float* __restrict__ W_edge, const float* __restrict__ b_edge,
    float* __restrict__ logits, int* __restrict__ cols)
{
  int lane = threadIdx.x & 63;
  int wv = threadIdx.x >> 6;
  int g = lane >> 3, h = lane & 7;
  int pos = blockIdx.x * 32 + wv * 8 + g;
  int e = eord[pos];
  int row = ei[e], col = ei[E_EDGES + e];

  // scalar attention: this lane computes head h's full 64-dim dot
  const unsigned short* qp = q_s + (size_t)row * S_DIM + h * HD_DIM;
  const unsigned short* kp = k_s + (size_t)col * S_DIM + h * HD_DIM;
  float qk = 0.f;
  #pragma unroll
  for (int r = 0; r < 8; ++r) {
    int4 a = *reinterpret_cast<const int4*>(qp + r * 8);
    int4 b = *reinterpret_cast<const int4*>(kp + r * 8);
    qk = dot_i4(a, b, qk);
  }
  // vector attention: 48 dims per lane, reduce over 8 lanes
  const unsigned short* qv = q_v + (size_t)row * NV3 + h * 48;
  const unsigned short* kv = k_v + (size_t)col * NV3 + h * 48;
  float pv = 0.f;
  #pragma unroll
  for (int r = 0; r < 6; ++r) {
    int4 a = *reinterpret_cast<const int4*>(qv + r * 8);
    int4 b = *reinterpret_cast<const int4*>(kv + r * 8);
    pv = dot_i4(a, b, pv);
  }
  pv += __shfl_xor(pv, 1, 64);
  pv += __shfl_xor(pv, 2, 64);
  pv += __shfl_xor(pv, 4, 64);
  pv *= 0.57735026918962576f;  // 1/sqrt(3)

  // bessel basis via sin recurrence; each lane accumulates its head's MLP column
  float ex = edge_vec[(size_t)e * 3 + 0];
  float ey = edge_vec[(size_t)e * 3 + 1];
  float ez = edge_vec[(size_t)e * 3 + 2];
  float d = sqrtf(ex * ex + ey * ey + ez * ez);
  float th = d * 0.31415926535897932f;      // pi*d/10
  float s1 = __sinf(th), c1 = __cosf(th);
  float cut = (d < 10.f) ? 0.5f * (c1 + 1.f) : 0.f;
  float scale = cut / fmaxf(d, 1e-8f);
  float sr = s1, cr = c1, acc = 0.f;
  #pragma unroll
  for (int r = 0; r < R_BASIS; ++r) {
    acc = fmaf(sr, W_edge[r * H_HEADS + h], acc);
    float sn = fmaf(sr, c1, cr * s1);
    cr = fmaf(cr, c1, -sr * s1);
    sr = sn;
  }
  float eah = acc * scale + b_edge[h];

  logits[(size_t)pos * H_HEADS + h] = (qk + pv + eah) * 0.125f;
  if (h == 0) cols[pos] = col;
}

// -------- per-node softmax + aggregation (4-wave edge-parallel) --------
#define MAXDEG 512
__global__ __launch_bounds__(256) void agg_kernel(
    const float* __restrict__ logits, const int* __restrict__ cols,
    const unsigned short* __restrict__ v_s, const unsigned short* __restrict__ v_v,
    const int* __restrict__ offs,
    unsigned short* __restrict__ out_s, unsigned short* __restrict__ out_v)
{
  __shared__ float attn_lds[MAXDEG * H_HEADS];   // reused as cross-wave reduce buffer
  __shared__ float av_lds[MAXDEG];
  __shared__ int col_lds[MAXDEG];
  __shared__ float m_sh[H_HEADS], inv_sh[H_HEADS];

  int n = blockIdx.x;
  int beg = offs[n];
  int deg = offs[n + 1] - beg;
  int tid = threadIdx.x;
  bool fits = (deg <= MAXDEG);

  if (tid < 64) {
    int lane = tid;
    float lm[H_HEADS];
    #pragma unroll
    for (int h = 0; h < H_HEADS; ++h) lm[h] = -INFINITY;
    for (int i = lane; i < deg; i += 64) {
      const float4* lp = reinterpret_cast<const float4*>(logits + (size_t)(beg + i) * 8);
      float4 a = lp[0], b = lp[1];
      if (fits) col_lds[i] = cols[beg + i];
      lm[0] = fmaxf(lm[0], a.x); lm[1] = fmaxf(lm[1], a.y);
      lm[2] = fmaxf(lm[2], a.z); lm[3] = fmaxf(lm[3], a.w);
      lm[4] = fmaxf(lm[4], b.x); lm[5] = fmaxf(lm[5], b.y);
      lm[6] = fmaxf(lm[6], b.z); lm[7] = fmaxf(lm[7], b.w);
    }
    #pragma unroll
    for (int h = 0; h < H_HEADS; ++h) lm[h] = wave_max(lm[h]);

    float ls[H_HEADS];
    #pragma unroll
    for (int h = 0; h < H_HEADS; ++h) ls[h] = 0.f;
    for (int i = lane; i < deg; i += 64) {
      const float4* lp = reinterpret_cast<const float4*>(logits + (size_t)(beg + i) * 8);
      float4 a = lp[0], b = lp[1];
      float w[8];
      w[0] = expf(a.x - lm[0]); w[1] = expf(a.y - lm[1]);
      w[2] = expf(a.z - lm[2]); w[3] = expf(a.w - lm[3]);
      w[4] = expf(b.x - lm[4]); w[5] = expf(b.y - lm[5]);
      w[6] = expf(b.z - lm[6]); w[7] = expf(b.w - lm[7]);
      #pragma unroll
      for (int h = 0; h < H_HEADS; ++h) {
        ls[h] += w[h];
        if (fits) attn_lds[i * 8 + h] = w[h];
      }
    }
    #pragma unroll
    for (int h = 0; h < H_HEADS; ++h) ls[h] = wave_sum(ls[h]);

    float inv[H_HEADS];
    #pragma unroll
    for (int h = 0; h < H_HEADS; ++h) inv[h] = 1.f / (ls[h] + 1e-9f);
    if (lane == 0) {
      #pragma unroll
      for (int h = 0; h < H_HEADS; ++h) { m_sh[h] = lm[h]; inv_sh[h] = inv[h]; }
    }
    if (fits) {
      for (int i = lane; i < deg; i += 64) {
        float a = 0.f;
        #pragma unroll
        for (int h = 0; h < H_HEADS; ++h) a += attn_lds[i * 8 + h] * inv[h];
        av_lds[i] = 0.125f * a;
      }
    }
  }
  __syncthreads();

  // phase 2: wave wv takes edges i = wv, wv+4, ... ; lane owns 8 scalar dims
  // (head = lane>>3) and, for lane<48, 8 vector dims.
  int lane = tid & 63, wv = tid >> 6;
  int h = lane >> 3;
  float ih = inv_sh[h], mh = m_sh[h];
  float accs[8] = {0,0,0,0,0,0,0,0};
  float accv[8] = {0,0,0,0,0,0,0,0};
  for (int i = wv; i < deg; i += 4) {
    int colv;
    float wgt, av;
    if (fits) {
      colv = col_lds[i];
      wgt = attn_lds[i * 8 + h] * ih;
      av = av_lds[i];
    } else {
      colv = cols[beg + i];
      const float* lp = logits + (size_t)(beg + i) * 8;
      wgt = expf(lp[h] - mh) * ih;
      float a = 0.f;
      #pragma unroll
      for (int hh = 0; hh < H_HEADS; ++hh)
        a += expf(lp[hh] - m_sh[hh]) * inv_sh[hh];
      av = 0.125f * a;
    }
    int4 vs = *reinterpret_cast<const int4*>(v_s + (size_t)colv * S_DIM + lane * 8);
    union U { int4 v; unsigned short u[8]; } uv; uv.v = vs;
    #pragma unroll
    for (int j = 0; j < 8; ++j) accs[j] = fmaf(wgt, h2f(uv.u[j]), accs[j]);
    if (lane < 48) {
      int4 vvl = *reinterpret_cast<const int4*>(v_v + (size_t)colv * NV3 + lane * 8);
      union U2 { int4 v; unsigned short u[8]; } uv2; uv2.v = vvl;
      #pragma unroll
      for (int j = 0; j < 8; ++j) accv[j] = fmaf(av, h2f(uv2.u[j]), accv[j]);
    }
  }
  __syncthreads();   // attn_lds reads done; alias as reduce buffer

  float* red_s = attn_lds;            // [4][512]
  float* red_v = attn_lds + 2048;     // [4][384]
  #pragma unroll
  for (int j = 0; j < 8; j += 4)
    *reinterpret_cast<float4*>(&red_s[wv * 512 + lane * 8 + j]) =
      make_float4(accs[j], accs[j+1], accs[j+2], accs[j+3]);
  if (lane < 48) {
    #pragma unroll
    for (int j = 0; j < 8; j += 4)
      *reinterpret_cast<float4*>(&red_v[wv * 384 + lane * 8 + j]) =
        make_float4(accv[j], accv[j+1], accv[j+2], accv[j+3]);
  }
  __syncthreads();

  {
    int d0 = 2 * tid;  // scalar dims
    float s0 = red_s[d0] + red_s[512 + d0] + red_s[1024 + d0] + red_s[1536 + d0];
    float s1 = red_s[d0+1] + red_s[512 + d0+1] + red_s[1024 + d0+1] + red_s[1536 + d0+1];
    ushort2 o; o.x = f2h(s0); o.y = f2h(s1);
    *reinterpret_cast<ushort2*>(out_s + (size_t)n * S_DIM + d0) = o;
  }
  if (tid < 192) {
    int d0 = 2 * tid;
    float s0 = red_v[d0] + red_v[384 + d0] + red_v[768 + d0] + red_v[1152 + d0];
    float s1 = red_v[d0+1] + red_v[384 + d0+1] + red_v[768 + d0+1] + red_v[1152 + d0+1];
    ushort2 o; o.x = f2h(s0); o.y = f2h(s1);
    *reinterpret_cast<ushort2*>(out_v + (size_t)n * NV3 + d0) = o;
  }
}

// -------- vec output epilogue: tmp [(n*3+i)][128] f32 -> out [n][w][i] + bias + residual --------
__global__ __launch_bounds__(128) void vec_epilogue_kernel(
    const float* __restrict__ tmp, const float* __restrict__ bout_v,
    const float* __restrict__ vectors, float* __restrict__ out)
{
  __shared__ float l[NV3];
  int n = blockIdx.x, t = threadIdx.x;
  #pragma unroll
  for (int i = 0; i < 3; ++i)
    l[i * 128 + t] = tmp[((size_t)n * 3 + i) * V_DIM + t];
  __syncthreads();
  #pragma unroll
  for (int c = 0; c < 3; ++c) {
    int j = t + c * 128;      // j = w*3 + i
    int w = j / 3, i = j - 3 * w;
    out[(size_t)n * NV3 + j] = l[i * 128 + w] + bout_v[w] + vectors[(size_t)n * NV3 + j];
  }
}

// -------- residual + LayerNorm (wave per row) --------
__global__ __launch_bounds__(256) void ln_kernel(
    const float* __restrict__ x0, const float* __restrict__ dx,
    const float* __restrict__ g, const float* __restrict__ b,
    float* __restrict__ out)
{
  int r = blockIdx.x * 4 + (threadIdx.x >> 6);
  int lane = threadIdx.x & 63;
  if (r >= N_NODES) return;
  float x[8];
  float s = 0.f;
  #pragma unroll
  for (int j = 0; j < 8; ++j) {
    int d = lane + j * 64;
    x[j] = x0[(size_t)r * S_DIM + d] + dx[(size_t)r * S_DIM + d];
    s += x[j];
  }
  s = wave_sum(s);
  float mu = s * (1.f / 512.f);
  float vs = 0.f;
  #pragma unroll
  for (int j = 0; j < 8; ++j) { float t = x[j] - mu; vs += t * t; }
  vs = wave_sum(vs);
  float inv = rsqrtf(vs * (1.f / 512.f) + 1e-5f);
  #pragma unroll
  for (int j = 0; j < 8; ++j) {
    int d = lane + j * 64;
    out[(size_t)r * S_DIM + d] = (x[j] - mu) * inv * g[d] + b[d];
  }
}

extern "C" void kernel_launch(void* const* d_in, const int* in_sizes, int n_in,
                              void* d_out, int out_size, void* d_ws, size_t ws_size,
                              hipStream_t stream)
{
  (void)in_sizes; (void)n_in; (void)out_size; (void)ws_size;
  const float* scalars  = (const float*)d_in[0];
  const float* vectors  = (const float*)d_in[1];
  const float* edge_vec = (const float*)d_in[2];
  const float* Wq_s = (const float*)d_in[3];
  const float* bq_s = (const float*)d_in[4];
  const float* Wk_s = (const float*)d_in[5];
  const float* bk_s = (const float*)d_in[6];
  const float* Wv_s = (const float*)d_in[7];
  const float* bv_s = (const float*)d_in[8];
  const float* Wq_v = (const float*)d_in[9];
  const float* Wk_v = (const float*)d_in[10];
  const float* Wv_v = (const float*)d_in[11];
  const float* Wout_s = (const float*)d_in[12];
  const float* bout_s = (const float*)d_in[13];
  const float* Wout_v = (const float*)d_in[14];
  const float* bout_v = (const float*)d_in[15];
  const float* W_edge = (const float*)d_in[16];
  const float* b_edge = (const float*)d_in[17];
  const float* ln_g = (const float*)d_in[18];
  const float* ln_b = (const float*)d_in[19];
  const int* ei = (const int*)d_in[20];

  float* out = (float*)d_out;
  const size_t NS  = (size_t)N_NODES * S_DIM;   // 5,120,000
  const size_t NVs = (size_t)N_NODES * NV3;     // 3,840,000
  const size_t EH  = (size_t)E_EDGES * H_HEADS; // 1,280,000
  const size_t WSZ = (size_t)S_DIM * S_DIM;
  const size_t WVZ = (size_t)V_DIM * V_DIM;

  char* base = (char*)d_ws;
  auto carve = [&](size_t bytes) -> char* {
    char* p = base;
    base += (bytes + 255) & ~(size_t)255;
    return p;
  };
  // Af16+VT0 are dead after the projection GEMMs; tmpv (15.4MB f32) aliases them.
  unsigned short* Af16 = (unsigned short*)carve(NS * 2);    // 10.24MB
  unsigned short* VT0  = (unsigned short*)carve(NVs * 2);   // 7.68MB
  float* tmpv = (float*)Af16;                               // alias, needs 15.36MB
  unsigned short* q_s  = (unsigned short*)carve(NS * 2);
  unsigned short* k_s  = (unsigned short*)carve(NS * 2);
  unsigned short* v_s  = (unsigned short*)carve(NS * 2);
  unsigned short* q_v  = (unsigned short*)carve(NVs * 2);
  unsigned short* k_v  = (unsigned short*)carve(NVs * 2);
  unsigned short* v_v  = (unsigned short*)carve(NVs * 2);
  unsigned short* outs_pre = (unsigned short*)carve(NS * 2);
  unsigned short* outv_pre = (unsigned short*)carve(NVs * 2);
  float* dx      = (float*)carve(NS * 4);
  float* logitsS = (float*)carve(EH * 4);
  int*   colsS   = (int*)carve(E_EDGES * 4);
  unsigned short* WqT = (unsigned short*)carve(WSZ * 2);
  unsigned short* WkT = (unsigned short*)carve(WSZ * 2);
  unsigned short* WvT = (unsigned short*)carve(WSZ * 2);
  unsigned short* WoT = (unsigned short*)carve(WSZ * 2);
  unsigned short* WqvT = (unsigned short*)carve(WVZ * 2);
  unsigned short* WkvT = (unsigned short*)carve(WVZ * 2);
  unsigned short* WvvT = (unsigned short*)carve(WVZ * 2);
  unsigned short* WovT = (unsigned short*)carve(WVZ * 2);
  int* counts = (int*)carve(N_NODES * 4);
  int* offs   = (int*)carve((N_NODES + 1) * 4);
  int* cursor = (int*)carve(N_NODES * 4);
  int* eord   = (int*)carve(E_EDGES * 4);

  hipMemsetAsync(counts, 0, N_NODES * sizeof(int), stream);
  hipMemsetAsync(cursor, 0, N_NODES * sizeof(int), stream);

  // f16 conversions / transposes
  f32_to_f16_kernel<<<(int)(NS / 4 + 255) / 256, 256, 0, stream>>>(scalars, Af16, (int)(NS / 4));
  dim3 tBlk(32, 8);
  transpose_f16_kernel<<<dim3(16, 16), tBlk, 0, stream>>>(Wq_s, WqT, S_DIM);
  transpose_f16_kernel<<<dim3(16, 16), tBlk, 0, stream>>>(Wk_s, WkT, S_DIM);
  transpose_f16_kernel<<<dim3(16, 16), tBlk, 0, stream>>>(Wv_s, WvT, S_DIM);
  transpose_f16_kernel<<<dim3(16, 16), tBlk, 0, stream>>>(Wout_s, WoT, S_DIM);
  transpose_f16_kernel<<<dim3(4, 4), tBlk, 0, stream>>>(Wq_v, WqvT, V_DIM);
  transpose_f16_kernel<<<dim3(4, 4), tBlk, 0, stream>>>(Wk_v, WkvT, V_DIM);
  transpose_f16_kernel<<<dim3(4, 4), tBlk, 0, stream>>>(Wv_v, WvvT, V_DIM);
  transpose_f16_kernel<<<dim3(4, 4), tBlk, 0, stream>>>(Wout_v, WovT, V_DIM);
  vec_transpose_kernel<<<N_NODES, 128, 0, stream>>>(vectors, VT0);

  // scalar projections (MFMA, M=10000 K=512 N=512)
  dim3 gemmGridS(S_DIM / 128, (N_NODES + 127) / 128);
  gemm_f16_kernel<<<gemmGridS, 256, 0, stream>>>(Af16, WqT, bq_s, nullptr, q_s, N_NODES, S_DIM, S_DIM);
  gemm_f16_kernel<<<gemmGridS, 256, 0, stream>>>(Af16, WkT, bk_s, nullptr, k_s, N_NODES, S_DIM, S_DIM);
  gemm_f16_kernel<<<gemmGridS, 256, 0, stream>>>(Af16, WvT, bv_s, nullptr, v_s, N_NODES, S_DIM, S_DIM);

  // vector projections (MFMA, M=30000 K=128 N=128)
  int MV = N_NODES * 3;
  dim3 gemmGridV(1, (MV + 127) / 128);
  gemm_f16_kernel<<<gemmGridV, 256, 0, stream>>>(VT0, WqvT, nullptr, nullptr, q_v, MV, V_DIM, V_DIM);
  gemm_f16_kernel<<<gemmGridV, 256, 0, stream>>>(VT0, WkvT, nullptr, nullptr, k_v, MV, V_DIM, V_DIM);
  gemm_f16_kernel<<<gemmGridV, 256, 0, stream>>>(VT0, WvvT, nullptr, nullptr, v_v, MV, V_DIM, V_DIM);

  // CSR
  count_kernel<<<(E_EDGES + 255) / 256, 256, 0, stream>>>(ei, counts);
  scan_kernel<<<1, 256, 0, stream>>>(counts, offs);
  scatter_kernel<<<(E_EDGES + 255) / 256, 256, 0, stream>>>(ei, offs, cursor, eord);

  // edge logits (8 lanes/edge, CSR order)
  edge_logits_kernel<<<E_EDGES / 32, 256, 0, stream>>>(q_s, k_s, q_v, k_v, edge_vec,
                                                       ei, eord, W_edge, b_edge,
                                                       logitsS, colsS);

  // softmax + aggregate
  agg_kernel<<<N_NODES, 256, 0, stream>>>(logitsS, colsS, v_s, v_v, offs,
                                          outs_pre, outv_pre);

  // output projections + epilogues
  gemm_f16_kernel<<<gemmGridS, 256, 0, stream>>>(outs_pre, WoT, bout_s, dx, nullptr, N_NODES, S_DIM, S_DIM);
  gemm_f16_kernel<<<gemmGridV, 256, 0, stream>>>(outv_pre, WovT, nullptr, tmpv, nullptr, MV, V_DIM, V_DIM);
  vec_epilogue_kernel<<<N_NODES, 128, 0, stream>>>(tmpv, bout_v, vectors, out + NS);
  ln_kernel<<<2500, 256, 0, stream>>>(scalars, dx, ln_g, ln_b, out);
}

// Round 4
// 409.416 us; speedup vs baseline: 2.2158x; 1.2667x over previous
//
#include <hip/hip_runtime.h>
#include <math.h>

#define N_NODES 10000
#define E_EDGES 160000
#define S_DIM 512
#define QKV3 (3*S_DIM)   // 1536
#define V_DIM 128
#define VQKV3 (3*V_DIM)  // 384
#define H_HEADS 8
#define R_BASIS 32
#define HD_DIM 64
#define NV3 (V_DIM*3)    // 384

typedef _Float16 f16;
typedef f16 f16x2 __attribute__((ext_vector_type(2)));
typedef f16 f16x8 __attribute__((ext_vector_type(8)));
typedef float f32x4 __attribute__((ext_vector_type(4)));

static __device__ __forceinline__ float h2f(unsigned short u) {
  f16 h; __builtin_memcpy(&h, &u, 2); return (float)h;
}
static __device__ __forceinline__ unsigned short f2h(float f) {
  f16 h = (f16)f; unsigned short u; __builtin_memcpy(&u, &h, 2); return u;
}
static __device__ __forceinline__ float wave_sum(float v) {
  #pragma unroll
  for (int o = 32; o > 0; o >>= 1) v += __shfl_xor(v, o, 64);
  return v;
}
static __device__ __forceinline__ float wave_max(float v) {
  #pragma unroll
  for (int o = 32; o > 0; o >>= 1) v = fmaxf(v, __shfl_xor(v, o, 64));
  return v;
}
static __device__ __forceinline__ float dot_i4(int4 a, int4 b, float s) {
  union U { int4 v; f16x2 h[4]; } ua, ub;
  ua.v = a; ub.v = b;
  #pragma unroll
  for (int j = 0; j < 4; ++j)
    s = __builtin_amdgcn_fdot2(ua.h[j], ub.h[j], s, false);
  return s;
}

// ---------------- f32 -> f16 flat convert ----------------
__global__ __launch_bounds__(256) void f32_to_f16_kernel(
    const float* __restrict__ in, unsigned short* __restrict__ out, int n4)
{
  int i = blockIdx.x * 256 + threadIdx.x;
  if (i < n4) {
    float4 v = reinterpret_cast<const float4*>(in)[i];
    ushort4 o;
    o.x = f2h(v.x); o.y = f2h(v.y); o.z = f2h(v.z); o.w = f2h(v.w);
    reinterpret_cast<ushort4*>(out)[i] = o;
  }
}

// ------- 4 weight transposes in one launch: z=0..2 -> cat dst, z=3 -> Do -------
__global__ __launch_bounds__(256) void transpose4_kernel(
    const float* __restrict__ W0, const float* __restrict__ W1,
    const float* __restrict__ W2, const float* __restrict__ W3,
    unsigned short* __restrict__ Dcat, unsigned short* __restrict__ Do, int D)
{
  __shared__ float t[32][33];
  int z = blockIdx.z;
  const float* W = (z == 0) ? W0 : (z == 1) ? W1 : (z == 2) ? W2 : W3;
  unsigned short* dst = (z < 3) ? Dcat + (size_t)z * D * D : Do;
  int n0 = blockIdx.x * 32, k0 = blockIdx.y * 32;
  int x = threadIdx.x, y = threadIdx.y;   // 32 x 8
  #pragma unroll
  for (int j = 0; j < 32; j += 8)
    t[y + j][x] = W[(size_t)(k0 + y + j) * D + n0 + x];
  __syncthreads();
  #pragma unroll
  for (int j = 0; j < 32; j += 8)
    dst[(size_t)(n0 + y + j) * D + k0 + x] = f2h(t[x][y + j]);
}

// -------- bias concat [1536] --------
__global__ void bias_cat_kernel(const float* __restrict__ bq, const float* __restrict__ bk,
                                const float* __restrict__ bv, float* __restrict__ o)
{
  int c = blockIdx.x * 256 + threadIdx.x;
  if (c < QKV3)
    o[c] = (c < 512) ? bq[c] : (c < 1024) ? bk[c - 512] : bv[c - 1024];
}

// ---------------- vectors [n][128][3] f32 -> VT [(n*3+i)][128] f16 ----------------
__global__ __launch_bounds__(128) void vec_transpose_kernel(
    const float* __restrict__ vecs, unsigned short* __restrict__ VT)
{
  __shared__ float l[NV3];
  int n = blockIdx.x, t = threadIdx.x;
  #pragma unroll
  for (int j = 0; j < 3; ++j) l[t + j * 128] = vecs[(size_t)n * NV3 + t + j * 128];
  __syncthreads();
  #pragma unroll
  for (int i = 0; i < 3; ++i)
    VT[((size_t)n * 3 + i) * V_DIM + t] = f2h(l[t * 3 + i]);
}

// ---------------- f16 MFMA GEMM: C = A[M][K] @ Bt[N][K]^T + bias ----------------
#define ROWP 40
__global__ __launch_bounds__(256) void gemm_f16_kernel(
    const unsigned short* __restrict__ A, const unsigned short* __restrict__ Bt,
    const float* __restrict__ bias, float* __restrict__ Cf,
    unsigned short* __restrict__ Ch, int M, int K, int Nn)
{
  __shared__ unsigned short At[128 * ROWP];
  __shared__ unsigned short Bs[128 * ROWP];
  int tid = threadIdx.x;
  int wid = tid >> 6, lane = tid & 63;
  int wr = wid >> 1, wc = wid & 1;
  int row0 = blockIdx.y * 128, col0 = blockIdx.x * 128;

  const f32x4 zero = {0.f, 0.f, 0.f, 0.f};
  f32x4 acc[4][4];
  #pragma unroll
  for (int m = 0; m < 4; ++m)
    #pragma unroll
    for (int n = 0; n < 4; ++n) acc[m][n] = zero;

  int lr = lane & 15;
  int lk = (lane >> 4) * 8;

  for (int k0 = 0; k0 < K; k0 += 32) {
    int4 areg[2], breg[2];
    #pragma unroll
    for (int p = 0; p < 2; ++p) {
      int idx = tid + 256 * p;
      int r = idx >> 2;
      int kc = (idx & 3) * 8;
      int gr = row0 + r; if (gr >= M) gr = M - 1;
      areg[p] = *reinterpret_cast<const int4*>(A  + (size_t)gr * K + k0 + kc);
      breg[p] = *reinterpret_cast<const int4*>(Bt + (size_t)(col0 + r) * K + k0 + kc);
    }
    __syncthreads();
    #pragma unroll
    for (int p = 0; p < 2; ++p) {
      int idx = tid + 256 * p;
      int r = idx >> 2, kc = (idx & 3) * 8;
      *reinterpret_cast<int4*>(At + r * ROWP + kc) = areg[p];
      *reinterpret_cast<int4*>(Bs + r * ROWP + kc) = breg[p];
    }
    __syncthreads();

    f16x8 af[4], bfr[4];
    #pragma unroll
    for (int m = 0; m < 4; ++m)
      af[m] = *reinterpret_cast<const f16x8*>(At + (wr * 64 + m * 16 + lr) * ROWP + lk);
    #pragma unroll
    for (int n = 0; n < 4; ++n)
      bfr[n] = *reinterpret_cast<const f16x8*>(Bs + (wc * 64 + n * 16 + lr) * ROWP + lk);
    #pragma unroll
    for (int m = 0; m < 4; ++m)
      #pragma unroll
      for (int n = 0; n < 4; ++n)
        acc[m][n] = __builtin_amdgcn_mfma_f32_16x16x32_f16(af[m], bfr[n], acc[m][n], 0, 0, 0);
  }

  int lq = lane >> 4;
  #pragma unroll
  for (int m = 0; m < 4; ++m) {
    #pragma unroll
    for (int j = 0; j < 4; ++j) {
      int row = row0 + wr * 64 + m * 16 + lq * 4 + j;
      if (row < M) {
        #pragma unroll
        for (int n = 0; n < 4; ++n) {
          int col = col0 + wc * 64 + n * 16 + lr;
          float v = acc[m][n][j] + (bias ? bias[col] : 0.f);
          if (Cf) Cf[(size_t)row * Nn + col] = v;
          else    Ch[(size_t)row * Nn + col] = f2h(v);
        }
      }
    }
  }
}

// -------- CSR build --------
__global__ void count_kernel(const int* __restrict__ ei, int* __restrict__ counts) {
  int e = blockIdx.x * 256 + threadIdx.x;
  if (e < E_EDGES) atomicAdd(&counts[ei[e]], 1);
}

__global__ __launch_bounds__(1024) void scan_kernel(const int* __restrict__ counts,
                                                    int* __restrict__ offs) {
  __shared__ int wsum[16];
  __shared__ int carry_s;
  int tid = threadIdx.x;
  int lane = tid & 63, w = tid >> 6;
  if (tid == 0) carry_s = 0;
  __syncthreads();
  for (int base = 0; base < N_NODES; base += 1024) {
    int i = base + tid;
    int v = (i < N_NODES) ? counts[i] : 0;
    int x = v;
    #pragma unroll
    for (int o = 1; o < 64; o <<= 1) {
      int t = __shfl_up(x, o, 64);
      if (lane >= o) x += t;
    }
    if (lane == 63) wsum[w] = x;
    __syncthreads();
    if (w == 0 && lane < 16) {
      int t = wsum[lane];
      #pragma unroll
      for (int o = 1; o < 16; o <<= 1) {
        int u = __shfl_up(t, o, 64);
        if (lane >= o) t += u;
      }
      wsum[lane] = t;
    }
    __syncthreads();
    int incl = x + ((w > 0) ? wsum[w - 1] : 0);
    int c = carry_s;
    __syncthreads();
    if (i < N_NODES) offs[i] = c + incl - v;
    if (tid == 1023) carry_s = c + incl;
    __syncthreads();
  }
  if (tid == 0) offs[N_NODES] = carry_s;
}

__global__ void scatter_kernel(const int* __restrict__ ei, const int* __restrict__ offs,
                               int* __restrict__ cursor, int* __restrict__ eord) {
  int e = blockIdx.x * 256 + threadIdx.x;
  if (e < E_EDGES) {
    int r = ei[e];
    int p = offs[r] + atomicAdd(&cursor[r], 1);
    eord[p] = e;
  }
}

// -------- bessel basis + edge MLP -> edge_att[pos][8] (8 lanes/edge) --------
__global__ __launch_bounds__(256) void bessel_kernel(
    const float* __restrict__ edge_vec, const int* __restrict__ eord,
    const float* __restrict__ W_edge, const float* __restrict__ b_edge,
    float* __restrict__ edge_att)
{
  __shared__ float Wl[R_BASIS * H_HEADS];
  int tid = threadIdx.x;
  Wl[tid] = W_edge[tid];
  __syncthreads();
  int lane = tid & 63, wv = tid >> 6;
  int g = lane >> 3, h = lane & 7;
  int pos = blockIdx.x * 32 + wv * 8 + g;
  int e = eord[pos];
  float ex = edge_vec[(size_t)e * 3 + 0];
  float ey = edge_vec[(size_t)e * 3 + 1];
  float ez = edge_vec[(size_t)e * 3 + 2];
  float d = sqrtf(ex * ex + ey * ey + ez * ez);
  float th = d * 0.31415926535897932f;  // pi*d/10
  float s1 = __sinf(th), c1 = __cosf(th);
  float s2 = 2.f * s1 * c1,        c2 = fmaf(c1, c1, -s1 * s1);
  float s3 = fmaf(s2, c1, c2 * s1), c3 = fmaf(c2, c1, -s2 * s1);
  float s4 = 2.f * s2 * c2,        c4 = fmaf(c2, c2, -s2 * s2);
  float sr[4] = {s1, s2, s3, s4};
  float cr[4] = {c1, c2, c3, c4};
  float acc = 0.f;
  #pragma unroll
  for (int t = 0; t < 8; ++t) {
    #pragma unroll
    for (int j = 0; j < 4; ++j) {
      acc = fmaf(sr[j], Wl[(t * 4 + j) * H_HEADS + h], acc);
      float sn = fmaf(sr[j], c4, cr[j] * s4);
      cr[j] = fmaf(cr[j], c4, -sr[j] * s4);
      sr[j] = sn;
    }
  }
  float cut = (d < 10.f) ? 0.5f * (c1 + 1.f) : 0.f;
  float scale = cut / fmaxf(d, 1e-8f);
  edge_att[(size_t)pos * H_HEADS + h] = fmaf(acc, scale, b_edge[h]);
}

// -------- per-edge logits: 8 lanes/edge, batched register gathers --------
__global__ __launch_bounds__(256, 4) void edge_logits_kernel(
    const unsigned short* __restrict__ qkv_s, const unsigned short* __restrict__ qkv_v,
    const int* __restrict__ ei, const int* __restrict__ eord,
    const float* __restrict__ edge_att,
    float* __restrict__ logits, int* __restrict__ cols)
{
  int lane = threadIdx.x & 63;
  int wv = threadIdx.x >> 6;
  int g = lane >> 3, h = lane & 7;
  int pos = blockIdx.x * 32 + wv * 8 + g;
  int e = eord[pos];
  int row = ei[e], col = ei[E_EDGES + e];

  const unsigned short* qp = qkv_s + (size_t)row * QKV3 + h * HD_DIM;
  const unsigned short* kp = qkv_s + (size_t)col * QKV3 + 512 + h * HD_DIM;
  int4 qa[8], ka[8];
  #pragma unroll
  for (int r = 0; r < 8; ++r) qa[r] = *reinterpret_cast<const int4*>(qp + r * 8);
  #pragma unroll
  for (int r = 0; r < 8; ++r) ka[r] = *reinterpret_cast<const int4*>(kp + r * 8);

  int4 qv[6], kv[6];
  #pragma unroll
  for (int r = 0; r < 6; ++r) {
    int f = h * 48 + r * 8;
    int i = f >> 7, w = f & 127;
    qv[r] = *reinterpret_cast<const int4*>(qkv_v + ((size_t)row * 3 + i) * VQKV3 + w);
    kv[r] = *reinterpret_cast<const int4*>(qkv_v + ((size_t)col * 3 + i) * VQKV3 + 128 + w);
  }

  float qk = 0.f;
  #pragma unroll
  for (int r = 0; r < 8; ++r) qk = dot_i4(qa[r], ka[r], qk);

  float pv = 0.f;
  #pragma unroll
  for (int r = 0; r < 6; ++r) pv = dot_i4(qv[r], kv[r], pv);
  pv += __shfl_xor(pv, 1, 64);
  pv += __shfl_xor(pv, 2, 64);
  pv += __shfl_xor(pv, 4, 64);
  pv *= 0.57735026918962576f;  // 1/sqrt(3)

  float eah = edge_att[(size_t)pos * H_HEADS + h];
  logits[(size_t)pos * H_HEADS + h] = (qk + pv + eah) * 0.125f;
  if (h == 0) cols[pos] = col;
}

// -------- per-node softmax + aggregation (4-wave edge-parallel) --------
#define MAXDEG 512
__global__ __launch_bounds__(256) void agg_kernel(
    const float* __restrict__ logits, const int* __restrict__ cols,
    const unsigned short* __restrict__ qkv_s, const unsigned short* __restrict__ qkv_v,
    const int* __restrict__ offs,
    unsigned short* __restrict__ out_s, unsigned short* __restrict__ out_v)
{
  __shared__ float attn_lds[MAXDEG * H_HEADS];
  __shared__ float av_lds[MAXDEG];
  __shared__ int col_lds[MAXDEG];
  __shared__ float m_sh[H_HEADS], inv_sh[H_HEADS];

  int n = blockIdx.x;
  int beg = offs[n];
  int deg = offs[n + 1] - beg;
  int tid = threadIdx.x;
  bool fits = (deg <= MAXDEG);

  if (tid < 64) {
    int lane = tid;
    float lm[H_HEADS];
    #pragma unroll
    for (int h = 0; h < H_HEADS; ++h) lm[h] = -INFINITY;
    for (int i = lane; i < deg; i += 64) {
      const float4* lp = reinterpret_cast<const float4*>(logits + (size_t)(beg + i) * 8);
      float4 a = lp[0], b = lp[1];
      if (fits) col_lds[i] = cols[beg + i];
      lm[0] = fmaxf(lm[0], a.x); lm[1] = fmaxf(lm[1], a.y);
      lm[2] = fmaxf(lm[2], a.z); lm[3] = fmaxf(lm[3], a.w);
      lm[4] = fmaxf(lm[4], b.x); lm[5] = fmaxf(lm[5], b.y);
      lm[6] = fmaxf(lm[6], b.z); lm[7] = fmaxf(lm[7], b.w);
    }
    #pragma unroll
    for (int h = 0; h < H_HEADS; ++h) lm[h] = wave_max(lm[h]);

    float ls[H_HEADS];
    #pragma unroll
    for (int h = 0; h < H_HEADS; ++h) ls[h] = 0.f;
    for (int i = lane; i < deg; i += 64) {
      const float4* lp = reinterpret_cast<const float4*>(logits + (size_t)(beg + i) * 8);
      float4 a = lp[0], b = lp[1];
      float w[8];
      w[0] = expf(a.x - lm[0]); w[1] = expf(a.y - lm[1]);
      w[2] = expf(a.z - lm[2]); w[3] = expf(a.w - lm[3]);
      w[4] = expf(b.x - lm[4]); w[5] = expf(b.y - lm[5]);
      w[6] = expf(b.z - lm[6]); w[7] = expf(b.w - lm[7]);
      #pragma unroll
      for (int h = 0; h < H_HEADS; ++h) {
        ls[h] += w[h];
        if (fits) attn_lds[i * 8 + h] = w[h];
      }
    }
    #pragma unroll
    for (int h = 0; h < H_HEADS; ++h) ls[h] = wave_sum(ls[h]);

    float inv[H_HEADS];
    #pragma unroll
    for (int h = 0; h < H_HEADS; ++h) inv[h] = 1.f / (ls[h] + 1e-9f);
    if (lane == 0) {
      #pragma unroll
      for (int h = 0; h < H_HEADS; ++h) { m_sh[h] = lm[h]; inv_sh[h] = inv[h]; }
    }
    if (fits) {
      for (int i = lane; i < deg; i += 64) {
        float a = 0.f;
        #pragma unroll
        for (int h = 0; h < H_HEADS; ++h) a += attn_lds[i * 8 + h] * inv[h];
        av_lds[i] = 0.125f * a;
      }
    }
  }
  __syncthreads();

  int lane = tid & 63, wv = tid >> 6;
  int h = lane >> 3;
  int fv = lane * 8;
  int vi = fv >> 7, vw = fv & 127;
  float ih = inv_sh[h], mh = m_sh[h];
  float accs[8] = {0,0,0,0,0,0,0,0};
  float accv[8] = {0,0,0,0,0,0,0,0};

  auto body = [&](int i) {
    int colv;
    float wgt, av;
    if (fits) {
      colv = col_lds[i];
      wgt = attn_lds[i * 8 + h] * ih;
      av = av_lds[i];
    } else {
      colv = cols[beg + i];
      const float* lp = logits + (size_t)(beg + i) * 8;
      wgt = expf(lp[h] - mh) * ih;
      float a = 0.f;
      #pragma unroll
      for (int hh = 0; hh < H_HEADS; ++hh)
        a += expf(lp[hh] - m_sh[hh]) * inv_sh[hh];
      av = 0.125f * a;
    }
    int4 vs = *reinterpret_cast<const int4*>(qkv_s + (size_t)colv * QKV3 + 1024 + lane * 8);
    union U { int4 v; unsigned short u[8]; } uv; uv.v = vs;
    #pragma unroll
    for (int j = 0; j < 8; ++j) accs[j] = fmaf(wgt, h2f(uv.u[j]), accs[j]);
    if (lane < 48) {
      int4 vvl = *reinterpret_cast<const int4*>(qkv_v + ((size_t)colv * 3 + vi) * VQKV3 + 256 + vw);
      union U2 { int4 v; unsigned short u[8]; } uv2; uv2.v = vvl;
      #pragma unroll
      for (int j = 0; j < 8; ++j) accv[j] = fmaf(av, h2f(uv2.u[j]), accv[j]);
    }
  };

  int i = wv;
  for (; i + 4 < deg; i += 8) { body(i); body(i + 4); }
  if (i < deg) body(i);
  __syncthreads();

  float* red_s = attn_lds;            // [4][512]
  float* red_v = attn_lds + 2048;     // [4][384]
  #pragma unroll
  for (int j = 0; j < 8; j += 4)
    *reinterpret_cast<float4*>(&red_s[wv * 512 + lane * 8 + j]) =
      make_float4(accs[j], accs[j+1], accs[j+2], accs[j+3]);
  if (lane < 48) {
    #pragma unroll
    for (int j = 0; j < 8; j += 4)
      *reinterpret_cast<float4*>(&red_v[wv * 384 + lane * 8 + j]) =
        make_float4(accv[j], accv[j+1], accv[j+2], accv[j+3]);
  }
  __syncthreads();

  {
    int d0 = 2 * tid;
    float s0 = red_s[d0] + red_s[512 + d0] + red_s[1024 + d0] + red_s[1536 + d0];
    float s1 = red_s[d0+1] + red_s[512 + d0+1] + red_s[1024 + d0+1] + red_s[1536 + d0+1];
    ushort2 o; o.x = f2h(s0); o.y = f2h(s1);
    *reinterpret_cast<ushort2*>(out_s + (size_t)n * S_DIM + d0) = o;
  }
  if (tid < 192) {
    int d0 = 2 * tid;
    float s0 = red_v[d0] + red_v[384 + d0] + red_v[768 + d0] + red_v[1152 + d0];
    float s1 = red_v[d0+1] + red_v[384 + d0+1] + red_v[768 + d0+1] + red_v[1152 + d0+1];
    ushort2 o; o.x = f2h(s0); o.y = f2h(s1);
    *reinterpret_cast<ushort2*>(out_v + (size_t)n * NV3 + d0) = o;
  }
}

// -------- vec output epilogue --------
__global__ __launch_bounds__(128) void vec_epilogue_kernel(
    const float* __restrict__ tmp, const float* __restrict__ bout_v,
    const float* __restrict__ vectors, float* __restrict__ out)
{
  __shared__ float l[NV3];
  int n = blockIdx.x, t = threadIdx.x;
  #pragma unroll
  for (int i = 0; i < 3; ++i)
    l[i * 128 + t] = tmp[((size_t)n * 3 + i) * V_DIM + t];
  __syncthreads();
  #pragma unroll
  for (int c = 0; c < 3; ++c) {
    int j = t + c * 128;      // j = w*3 + i
    int w = j / 3, i = j - 3 * w;
    out[(size_t)n * NV3 + j] = l[i * 128 + w] + bout_v[w] + vectors[(size_t)n * NV3 + j];
  }
}

// -------- residual + LayerNorm (wave per row) --------
__global__ __launch_bounds__(256) void ln_kernel(
    const float* __restrict__ x0, const float* __restrict__ dx,
    const float* __restrict__ g, const float* __restrict__ b,
    float* __restrict__ out)
{
  int r = blockIdx.x * 4 + (threadIdx.x >> 6);
  int lane = threadIdx.x & 63;
  if (r >= N_NODES) return;
  float x[8];
  float s = 0.f;
  #pragma unroll
  for (int j = 0; j < 8; ++j) {
    int d = lane + j * 64;
    x[j] = x0[(size_t)r * S_DIM + d] + dx[(size_t)r * S_DIM + d];
    s += x[j];
  }
  s = wave_sum(s);
  float mu = s * (1.f / 512.f);
  float vs = 0.f;
  #pragma unroll
  for (int j = 0; j < 8; ++j) { float t = x[j] - mu; vs += t * t; }
  vs = wave_sum(vs);
  float inv = rsqrtf(vs * (1.f / 512.f) + 1e-5f);
  #pragma unroll
  for (int j = 0; j < 8; ++j) {
    int d = lane + j * 64;
    out[(size_t)r * S_DIM + d] = (x[j] - mu) * inv * g[d] + b[d];
  }
}

extern "C" void kernel_launch(void* const* d_in, const int* in_sizes, int n_in,
                              void* d_out, int out_size, void* d_ws, size_t ws_size,
                              hipStream_t stream)
{
  (void)in_sizes; (void)n_in; (void)out_size; (void)ws_size;
  const float* scalars  = (const float*)d_in[0];
  const float* vectors  = (const float*)d_in[1];
  const float* edge_vec = (const float*)d_in[2];
  const float* Wq_s = (const float*)d_in[3];
  const float* bq_s = (const float*)d_in[4];
  const float* Wk_s = (const float*)d_in[5];
  const float* bk_s = (const float*)d_in[6];
  const float* Wv_s = (const float*)d_in[7];
  const float* bv_s = (const float*)d_in[8];
  const float* Wq_v = (const float*)d_in[9];
  const float* Wk_v = (const float*)d_in[10];
  const float* Wv_v = (const float*)d_in[11];
  const float* Wout_s = (const float*)d_in[12];
  const float* bout_s = (const float*)d_in[13];
  const float* Wout_v = (const float*)d_in[14];
  const float* bout_v = (const float*)d_in[15];
  const float* W_edge = (const float*)d_in[16];
  const float* b_edge = (const float*)d_in[17];
  const float* ln_g = (const float*)d_in[18];
  const float* ln_b = (const float*)d_in[19];
  const int* ei = (const int*)d_in[20];

  float* out = (float*)d_out;
  const size_t NS  = (size_t)N_NODES * S_DIM;     // 5,120,000
  const size_t NVs = (size_t)N_NODES * NV3;       // 3,840,000
  const size_t EH  = (size_t)E_EDGES * H_HEADS;   // 1,280,000
  const size_t WSZ = (size_t)S_DIM * S_DIM;
  const size_t WVZ = (size_t)V_DIM * V_DIM;
  const int MV = N_NODES * 3;

  char* base = (char*)d_ws;
  auto carve = [&](size_t bytes) -> char* {
    char* p = base;
    base += (bytes + 255) & ~(size_t)255;
    return p;
  };
  unsigned short* Af16 = (unsigned short*)carve(NS * 2);    // 10.24MB
  unsigned short* VT0  = (unsigned short*)carve(NVs * 2);   // 7.68MB
  float* tmpv = (float*)Af16;   // alias (15.36MB into Af16+VT0, both dead by then)
  unsigned short* qkv_s = (unsigned short*)carve((size_t)N_NODES * QKV3 * 2);   // 30.72MB
  unsigned short* qkv_v = (unsigned short*)carve((size_t)MV * VQKV3 * 2);       // 23.04MB
  unsigned short* outs_pre = (unsigned short*)carve(NS * 2);
  unsigned short* outv_pre = (unsigned short*)carve(NVs * 2);
  float* dx       = (float*)carve(NS * 4);
  float* logitsS  = (float*)carve(EH * 4);
  float* edge_att = (float*)carve(EH * 4);
  int*   colsS    = (int*)carve(E_EDGES * 4);
  unsigned short* WqkvT  = (unsigned short*)carve(3 * WSZ * 2);
  unsigned short* WoT    = (unsigned short*)carve(WSZ * 2);
  unsigned short* WqkvvT = (unsigned short*)carve(3 * WVZ * 2);
  unsigned short* WovT   = (unsigned short*)carve(WVZ * 2);
  float* bias_cat = (float*)carve(QKV3 * 4);
  int* counts = (int*)carve(N_NODES * 4);
  int* offs   = (int*)carve((N_NODES + 1) * 4);
  int* cursor = (int*)carve(N_NODES * 4);
  int* eord   = (int*)carve(E_EDGES * 4);

  hipMemsetAsync(counts, 0, N_NODES * sizeof(int), stream);
  hipMemsetAsync(cursor, 0, N_NODES * sizeof(int), stream);

  // conversions / transposes
  f32_to_f16_kernel<<<(int)(NS / 4 + 255) / 256, 256, 0, stream>>>(scalars, Af16, (int)(NS / 4));
  dim3 tBlk(32, 8);
  transpose4_kernel<<<dim3(16, 16, 4), tBlk, 0, stream>>>(Wq_s, Wk_s, Wv_s, Wout_s, WqkvT, WoT, S_DIM);
  transpose4_kernel<<<dim3(4, 4, 4), tBlk, 0, stream>>>(Wq_v, Wk_v, Wv_v, Wout_v, WqkvvT, WovT, V_DIM);
  vec_transpose_kernel<<<N_NODES, 128, 0, stream>>>(vectors, VT0);
  bias_cat_kernel<<<6, 256, 0, stream>>>(bq_s, bk_s, bv_s, bias_cat);

  // fused QKV projections
  gemm_f16_kernel<<<dim3(QKV3 / 128, (N_NODES + 127) / 128), 256, 0, stream>>>(
      Af16, WqkvT, bias_cat, nullptr, qkv_s, N_NODES, S_DIM, QKV3);
  gemm_f16_kernel<<<dim3(VQKV3 / 128, (MV + 127) / 128), 256, 0, stream>>>(
      VT0, WqkvvT, nullptr, nullptr, qkv_v, MV, V_DIM, VQKV3);

  // CSR
  count_kernel<<<(E_EDGES + 255) / 256, 256, 0, stream>>>(ei, counts);
  scan_kernel<<<1, 1024, 0, stream>>>(counts, offs);
  scatter_kernel<<<(E_EDGES + 255) / 256, 256, 0, stream>>>(ei, offs, cursor, eord);

  // edge stage
  bessel_kernel<<<E_EDGES / 32, 256, 0, stream>>>(edge_vec, eord, W_edge, b_edge, edge_att);
  edge_logits_kernel<<<E_EDGES / 32, 256, 0, stream>>>(qkv_s, qkv_v, ei, eord, edge_att,
                                                       logitsS, colsS);

  // softmax + aggregate
  agg_kernel<<<N_NODES, 256, 0, stream>>>(logitsS, colsS, qkv_s, qkv_v, offs,
                                          outs_pre, outv_pre);

  // output projections + epilogues
  gemm_f16_kernel<<<dim3(S_DIM / 128, (N_NODES + 127) / 128), 256, 0, stream>>>(
      outs_pre, WoT, bout_s, dx, nullptr, N_NODES, S_DIM, S_DIM);
  gemm_f16_kernel<<<dim3(1, (MV + 127) / 128), 256, 0, stream>>>(
      outv_pre, WovT, nullptr, tmpv, nullptr, MV, V_DIM, V_DIM);
  vec_epilogue_kernel<<<N_NODES, 128, 0, stream>>>(tmpv, bout_v, vectors, out + NS);
  ln_kernel<<<2500, 256, 0, stream>>>(scalars, dx, ln_g, ln_b, out);
}

// Round 5
// 299.617 us; speedup vs baseline: 3.0278x; 1.3665x over previous
//
#include <hip/hip_runtime.h>
#include <math.h>

#define N_NODES 10000
#define E_EDGES 160000
#define S_DIM 512
#define QKV3 (3*S_DIM)   // 1536
#define V_DIM 128
#define VQKV3 (3*V_DIM)  // 384
#define H_HEADS 8
#define R_BASIS 32
#define HD_DIM 64
#define NV3 (V_DIM*3)    // 384

typedef _Float16 f16;
typedef f16 f16x2 __attribute__((ext_vector_type(2)));
typedef f16 f16x8 __attribute__((ext_vector_type(8)));
typedef float f32x4 __attribute__((ext_vector_type(4)));

static __device__ __forceinline__ float h2f(unsigned short u) {
  f16 h; __builtin_memcpy(&h, &u, 2); return (float)h;
}
static __device__ __forceinline__ unsigned short f2h(float f) {
  f16 h = (f16)f; unsigned short u; __builtin_memcpy(&u, &h, 2); return u;
}
static __device__ __forceinline__ float wave_sum(float v) {
  #pragma unroll
  for (int o = 32; o > 0; o >>= 1) v += __shfl_xor(v, o, 64);
  return v;
}
static __device__ __forceinline__ float wave_max(float v) {
  #pragma unroll
  for (int o = 32; o > 0; o >>= 1) v = fmaxf(v, __shfl_xor(v, o, 64));
  return v;
}
static __device__ __forceinline__ float dot_i4(int4 a, int4 b, float s) {
  union U { int4 v; f16x2 h[4]; } ua, ub;
  ua.v = a; ub.v = b;
  #pragma unroll
  for (int j = 0; j < 4; ++j)
    s = __builtin_amdgcn_fdot2(ua.h[j], ub.h[j], s, false);
  return s;
}
// async global->LDS, 16B per lane; dest must be lane-linear (wavebase + lane*16)
static __device__ __forceinline__ void glds16(const unsigned short* g, unsigned short* l) {
  __builtin_amdgcn_global_load_lds(
      (const __attribute__((address_space(1))) unsigned int*)g,
      (__attribute__((address_space(3))) unsigned int*)l, 16, 0, 0);
}

// ---------------- f32 -> f16 flat convert ----------------
__global__ __launch_bounds__(256) void f32_to_f16_kernel(
    const float* __restrict__ in, unsigned short* __restrict__ out, int n4)
{
  int i = blockIdx.x * 256 + threadIdx.x;
  if (i < n4) {
    float4 v = reinterpret_cast<const float4*>(in)[i];
    ushort4 o;
    o.x = f2h(v.x); o.y = f2h(v.y); o.z = f2h(v.z); o.w = f2h(v.w);
    reinterpret_cast<ushort4*>(out)[i] = o;
  }
}

// ------- 4 weight transposes in one launch: z=0..2 -> cat dst, z=3 -> Do -------
__global__ __launch_bounds__(256) void transpose4_kernel(
    const float* __restrict__ W0, const float* __restrict__ W1,
    const float* __restrict__ W2, const float* __restrict__ W3,
    unsigned short* __restrict__ Dcat, unsigned short* __restrict__ Do, int D)
{
  __shared__ float t[32][33];
  int z = blockIdx.z;
  const float* W = (z == 0) ? W0 : (z == 1) ? W1 : (z == 2) ? W2 : W3;
  unsigned short* dst = (z < 3) ? Dcat + (size_t)z * D * D : Do;
  int n0 = blockIdx.x * 32, k0 = blockIdx.y * 32;
  int x = threadIdx.x, y = threadIdx.y;   // 32 x 8
  #pragma unroll
  for (int j = 0; j < 32; j += 8)
    t[y + j][x] = W[(size_t)(k0 + y + j) * D + n0 + x];
  __syncthreads();
  #pragma unroll
  for (int j = 0; j < 32; j += 8)
    dst[(size_t)(n0 + y + j) * D + k0 + x] = f2h(t[x][y + j]);
}

// -------- bias concat [1536] --------
__global__ void bias_cat_kernel(const float* __restrict__ bq, const float* __restrict__ bk,
                                const float* __restrict__ bv, float* __restrict__ o)
{
  int c = blockIdx.x * 256 + threadIdx.x;
  if (c < QKV3)
    o[c] = (c < 512) ? bq[c] : (c < 1024) ? bk[c - 512] : bv[c - 1024];
}

// ---------------- vectors [n][128][3] f32 -> VT [(n*3+i)][128] f16 ----------------
__global__ __launch_bounds__(128) void vec_transpose_kernel(
    const float* __restrict__ vecs, unsigned short* __restrict__ VT)
{
  __shared__ float l[NV3];
  int n = blockIdx.x, t = threadIdx.x;
  #pragma unroll
  for (int j = 0; j < 3; ++j) l[t + j * 128] = vecs[(size_t)n * NV3 + t + j * 128];
  __syncthreads();
  #pragma unroll
  for (int i = 0; i < 3; ++i)
    VT[((size_t)n * 3 + i) * V_DIM + t] = f2h(l[t * 3 + i]);
}

// ---------------- f16 MFMA GEMM: C = A[M][K] @ Bt[N][K]^T + bias ----------------
// 128x128 tile, BK=32, 4 waves (2x2). global_load_lds staging, double-buffered,
// 2-phase schedule, swizzled reads (slot ^= (row>>1)&3, pre-swizzled source),
// C staged through LDS for coalesced full-line writes.
__global__ __launch_bounds__(256) void gemm_f16_kernel(
    const unsigned short* __restrict__ A, const unsigned short* __restrict__ Bt,
    const float* __restrict__ bias, float* __restrict__ Cf,
    unsigned short* __restrict__ Ch, int M, int K, int Nn)
{
  __shared__ unsigned short lds[2][2][128 * 32];   // [buf][A=0/B=1][row*32 + h]
  int tid = threadIdx.x;
  int wid = tid >> 6, lane = tid & 63;
  int wr = wid >> 1, wc = wid & 1;
  int row0 = blockIdx.y * 128, col0 = blockIdx.x * 128;

  // staging: thread owns 16B chunks idx = tid and tid+256 of each 8KB tile
  int r0 = tid >> 2, s0 = tid & 3;
  int r1 = r0 + 64;
  int sw0 = (r0 >> 1) & 3;                 // same for r1 (r1>>1 = r0>>1 + 32)
  int aoff = (s0 ^ sw0) * 8;               // pre-swizzled source k-offset (halves)
  int gra0 = row0 + r0; if (gra0 >= M) gra0 = M - 1;
  int gra1 = row0 + r1; if (gra1 >= M) gra1 = M - 1;
  const unsigned short* ag0 = A + (size_t)gra0 * K + aoff;
  const unsigned short* ag1 = A + (size_t)gra1 * K + aoff;
  const unsigned short* bg0 = Bt + (size_t)(col0 + r0) * K + aoff;
  const unsigned short* bg1 = Bt + (size_t)(col0 + r1) * K + aoff;

  f32x4 acc[4][4];
  #pragma unroll
  for (int m = 0; m < 4; ++m)
    #pragma unroll
    for (int n = 0; n < 4; ++n) acc[m][n] = (f32x4){0.f, 0.f, 0.f, 0.f};

  int lr = lane & 15, lq = lane >> 4;
  int slot = (lq ^ ((lr >> 1) & 3)) * 8;   // swizzled read slot (halves)
  int aro[4], bro[4];
  #pragma unroll
  for (int m = 0; m < 4; ++m) aro[m] = (wr * 64 + m * 16 + lr) * 32 + slot;
  #pragma unroll
  for (int n = 0; n < 4; ++n) bro[n] = (wc * 64 + n * 16 + lr) * 32 + slot;

  int nk = K >> 5;
  // prologue: stage tile 0
  glds16(ag0, &lds[0][0][tid * 8]);
  glds16(ag1, &lds[0][0][(tid + 256) * 8]);
  glds16(bg0, &lds[0][1][tid * 8]);
  glds16(bg1, &lds[0][1][(tid + 256) * 8]);
  __syncthreads();

  for (int t = 0; t < nk; ++t) {
    int cur = t & 1;
    if (t + 1 < nk) {                      // stage next tile into other buffer
      int ko = (t + 1) << 5;
      glds16(ag0 + ko, &lds[cur ^ 1][0][tid * 8]);
      glds16(ag1 + ko, &lds[cur ^ 1][0][(tid + 256) * 8]);
      glds16(bg0 + ko, &lds[cur ^ 1][1][tid * 8]);
      glds16(bg1 + ko, &lds[cur ^ 1][1][(tid + 256) * 8]);
    }
    const unsigned short* Ab = lds[cur][0];
    const unsigned short* Bb = lds[cur][1];
    f16x8 af[4], bf[4];
    #pragma unroll
    for (int m = 0; m < 4; ++m) af[m] = *reinterpret_cast<const f16x8*>(Ab + aro[m]);
    #pragma unroll
    for (int n = 0; n < 4; ++n) bf[n] = *reinterpret_cast<const f16x8*>(Bb + bro[n]);
    #pragma unroll
    for (int m = 0; m < 4; ++m)
      #pragma unroll
      for (int n = 0; n < 4; ++n)
        acc[m][n] = __builtin_amdgcn_mfma_f32_16x16x32_f16(af[m], bf[n], acc[m][n], 0, 0, 0);
    __syncthreads();
  }

  // epilogue: per 16-row slab (x2 wr groups), stage [32][128] in LDS, write full lines
  float bcol[4];
  #pragma unroll
  for (int n = 0; n < 4; ++n)
    bcol[n] = bias ? bias[col0 + wc * 64 + n * 16 + lr] : 0.f;
  int rl = tid >> 3, cc = (tid & 7) * 16;

  if (Cf) {
    float* cst = reinterpret_cast<float*>(&lds[0][0][0]);      // 16KB
    #pragma unroll
    for (int m = 0; m < 4; ++m) {
      __syncthreads();
      #pragma unroll
      for (int n = 0; n < 4; ++n)
        #pragma unroll
        for (int j = 0; j < 4; ++j)
          cst[(wr * 16 + lq * 4 + j) * 128 + wc * 64 + n * 16 + lr] = acc[m][n][j] + bcol[n];
      __syncthreads();
      int row = row0 + (rl >> 4) * 64 + m * 16 + (rl & 15);
      if (row < M) {
        float4* dst = reinterpret_cast<float4*>(Cf + (size_t)row * Nn + col0 + cc);
        const float4* src = reinterpret_cast<const float4*>(cst + rl * 128 + cc);
        dst[0] = src[0]; dst[1] = src[1]; dst[2] = src[2]; dst[3] = src[3];
      }
    }
  } else {
    unsigned short* csth = &lds[0][0][0];                      // 8KB
    #pragma unroll
    for (int m = 0; m < 4; ++m) {
      __syncthreads();
      #pragma unroll
      for (int n = 0; n < 4; ++n)
        #pragma unroll
        for (int j = 0; j < 4; ++j)
          csth[(wr * 16 + lq * 4 + j) * 128 + wc * 64 + n * 16 + lr] = f2h(acc[m][n][j] + bcol[n]);
      __syncthreads();
      int row = row0 + (rl >> 4) * 64 + m * 16 + (rl & 15);
      if (row < M) {
        int4* dst = reinterpret_cast<int4*>(Ch + (size_t)row * Nn + col0 + cc);
        const int4* src = reinterpret_cast<const int4*>(csth + rl * 128 + cc);
        dst[0] = src[0]; dst[1] = src[1];
      }
    }
  }
}

// -------- CSR build --------
__global__ void count_kernel(const int* __restrict__ ei, int* __restrict__ counts) {
  int e = blockIdx.x * 256 + threadIdx.x;
  if (e < E_EDGES) atomicAdd(&counts[ei[e]], 1);
}

__global__ __launch_bounds__(1024) void scan_kernel(const int* __restrict__ counts,
                                                    int* __restrict__ offs) {
  __shared__ int wsum[16];
  __shared__ int carry_s;
  int tid = threadIdx.x;
  int lane = tid & 63, w = tid >> 6;
  if (tid == 0) carry_s = 0;
  __syncthreads();
  for (int base = 0; base < N_NODES; base += 1024) {
    int i = base + tid;
    int v = (i < N_NODES) ? counts[i] : 0;
    int x = v;
    #pragma unroll
    for (int o = 1; o < 64; o <<= 1) {
      int t = __shfl_up(x, o, 64);
      if (lane >= o) x += t;
    }
    if (lane == 63) wsum[w] = x;
    __syncthreads();
    if (w == 0 && lane < 16) {
      int t = wsum[lane];
      #pragma unroll
      for (int o = 1; o < 16; o <<= 1) {
        int u = __shfl_up(t, o, 64);
        if (lane >= o) t += u;
      }
      wsum[lane] = t;
    }
    __syncthreads();
    int incl = x + ((w > 0) ? wsum[w - 1] : 0);
    int c = carry_s;
    __syncthreads();
    if (i < N_NODES) offs[i] = c + incl - v;
    if (tid == 1023) carry_s = c + incl;
    __syncthreads();
  }
  if (tid == 0) offs[N_NODES] = carry_s;
}

__global__ void scatter_kernel(const int* __restrict__ ei, const int* __restrict__ offs,
                               int* __restrict__ cursor, int* __restrict__ eord) {
  int e = blockIdx.x * 256 + threadIdx.x;
  if (e < E_EDGES) {
    int r = ei[e];
    int p = offs[r] + atomicAdd(&cursor[r], 1);
    eord[p] = e;
  }
}

// -------- bessel basis + edge MLP -> edge_att[pos][8] (8 lanes/edge) --------
__global__ __launch_bounds__(256) void bessel_kernel(
    const float* __restrict__ edge_vec, const int* __restrict__ eord,
    const float* __restrict__ W_edge, const float* __restrict__ b_edge,
    float* __restrict__ edge_att)
{
  __shared__ float Wl[R_BASIS * H_HEADS];
  int tid = threadIdx.x;
  Wl[tid] = W_edge[tid];
  __syncthreads();
  int lane = tid & 63, wv = tid >> 6;
  int g = lane >> 3, h = lane & 7;
  int pos = blockIdx.x * 32 + wv * 8 + g;
  int e = eord[pos];
  float ex = edge_vec[(size_t)e * 3 + 0];
  float ey = edge_vec[(size_t)e * 3 + 1];
  float ez = edge_vec[(size_t)e * 3 + 2];
  float d = sqrtf(ex * ex + ey * ey + ez * ez);
  float th = d * 0.31415926535897932f;  // pi*d/10
  float s1 = __sinf(th), c1 = __cosf(th);
  float s2 = 2.f * s1 * c1,        c2 = fmaf(c1, c1, -s1 * s1);
  float s3 = fmaf(s2, c1, c2 * s1), c3 = fmaf(c2, c1, -s2 * s1);
  float s4 = 2.f * s2 * c2,        c4 = fmaf(c2, c2, -s2 * s2);
  float sr[4] = {s1, s2, s3, s4};
  float cr[4] = {c1, c2, c3, c4};
  float acc = 0.f;
  #pragma unroll
  for (int t = 0; t < 8; ++t) {
    #pragma unroll
    for (int j = 0; j < 4; ++j) {
      acc = fmaf(sr[j], Wl[(t * 4 + j) * H_HEADS + h], acc);
      float sn = fmaf(sr[j], c4, cr[j] * s4);
      cr[j] = fmaf(cr[j], c4, -sr[j] * s4);
      sr[j] = sn;
    }
  }
  float cut = (d < 10.f) ? 0.5f * (c1 + 1.f) : 0.f;
  float scale = cut / fmaxf(d, 1e-8f);
  edge_att[(size_t)pos * H_HEADS + h] = fmaf(acc, scale, b_edge[h]);
}

// -------- per-edge logits: 8 lanes/edge, batched register gathers --------
__global__ __launch_bounds__(256, 4) void edge_logits_kernel(
    const unsigned short* __restrict__ qkv_s, const unsigned short* __restrict__ qkv_v,
    const int* __restrict__ ei, const int* __restrict__ eord,
    const float* __restrict__ edge_att,
    float* __restrict__ logits, int* __restrict__ cols)
{
  int lane = threadIdx.x & 63;
  int wv = threadIdx.x >> 6;
  int g = lane >> 3, h = lane & 7;
  int pos = blockIdx.x * 32 + wv * 8 + g;
  int e = eord[pos];
  int row = ei[e], col = ei[E_EDGES + e];

  const unsigned short* qp = qkv_s + (size_t)row * QKV3 + h * HD_DIM;
  const unsigned short* kp = qkv_s + (size_t)col * QKV3 + 512 + h * HD_DIM;
  int4 qa[8], ka[8];
  #pragma unroll
  for (int r = 0; r < 8; ++r) qa[r] = *reinterpret_cast<const int4*>(qp + r * 8);
  #pragma unroll
  for (int r = 0; r < 8; ++r) ka[r] = *reinterpret_cast<const int4*>(kp + r * 8);

  int4 qv[6], kv[6];
  #pragma unroll
  for (int r = 0; r < 6; ++r) {
    int f = h * 48 + r * 8;
    int i = f >> 7, w = f & 127;
    qv[r] = *reinterpret_cast<const int4*>(qkv_v + ((size_t)row * 3 + i) * VQKV3 + w);
    kv[r] = *reinterpret_cast<const int4*>(qkv_v + ((size_t)col * 3 + i) * VQKV3 + 128 + w);
  }

  float qk = 0.f;
  #pragma unroll
  for (int r = 0; r < 8; ++r) qk = dot_i4(qa[r], ka[r], qk);

  float pv = 0.f;
  #pragma unroll
  for (int r = 0; r < 6; ++r) pv = dot_i4(qv[r], kv[r], pv);
  pv += __shfl_xor(pv, 1, 64);
  pv += __shfl_xor(pv, 2, 64);
  pv += __shfl_xor(pv, 4, 64);
  pv *= 0.57735026918962576f;  // 1/sqrt(3)

  float eah = edge_att[(size_t)pos * H_HEADS + h];
  logits[(size_t)pos * H_HEADS + h] = (qk + pv + eah) * 0.125f;
  if (h == 0) cols[pos] = col;
}

// -------- per-node softmax + aggregation (4-wave edge-parallel) --------
#define MAXDEG 512
__global__ __launch_bounds__(256) void agg_kernel(
    const float* __restrict__ logits, const int* __restrict__ cols,
    const unsigned short* __restrict__ qkv_s, const unsigned short* __restrict__ qkv_v,
    const int* __restrict__ offs,
    unsigned short* __restrict__ out_s, unsigned short* __restrict__ out_v)
{
  __shared__ float attn_lds[MAXDEG * H_HEADS];
  __shared__ float av_lds[MAXDEG];
  __shared__ int col_lds[MAXDEG];
  __shared__ float m_sh[H_HEADS], inv_sh[H_HEADS];

  int n = blockIdx.x;
  int beg = offs[n];
  int deg = offs[n + 1] - beg;
  int tid = threadIdx.x;
  bool fits = (deg <= MAXDEG);

  if (tid < 64) {
    int lane = tid;
    float lm[H_HEADS];
    #pragma unroll
    for (int h = 0; h < H_HEADS; ++h) lm[h] = -INFINITY;
    for (int i = lane; i < deg; i += 64) {
      const float4* lp = reinterpret_cast<const float4*>(logits + (size_t)(beg + i) * 8);
      float4 a = lp[0], b = lp[1];
      if (fits) col_lds[i] = cols[beg + i];
      lm[0] = fmaxf(lm[0], a.x); lm[1] = fmaxf(lm[1], a.y);
      lm[2] = fmaxf(lm[2], a.z); lm[3] = fmaxf(lm[3], a.w);
      lm[4] = fmaxf(lm[4], b.x); lm[5] = fmaxf(lm[5], b.y);
      lm[6] = fmaxf(lm[6], b.z); lm[7] = fmaxf(lm[7], b.w);
    }
    #pragma unroll
    for (int h = 0; h < H_HEADS; ++h) lm[h] = wave_max(lm[h]);

    float ls[H_HEADS];
    #pragma unroll
    for (int h = 0; h < H_HEADS; ++h) ls[h] = 0.f;
    for (int i = lane; i < deg; i += 64) {
      const float4* lp = reinterpret_cast<const float4*>(logits + (size_t)(beg + i) * 8);
      float4 a = lp[0], b = lp[1];
      float w[8];
      w[0] = expf(a.x - lm[0]); w[1] = expf(a.y - lm[1]);
      w[2] = expf(a.z - lm[2]); w[3] = expf(a.w - lm[3]);
      w[4] = expf(b.x - lm[4]); w[5] = expf(b.y - lm[5]);
      w[6] = expf(b.z - lm[6]); w[7] = expf(b.w - lm[7]);
      #pragma unroll
      for (int h = 0; h < H_HEADS; ++h) {
        ls[h] += w[h];
        if (fits) attn_lds[i * 8 + h] = w[h];
      }
    }
    #pragma unroll
    for (int h = 0; h < H_HEADS; ++h) ls[h] = wave_sum(ls[h]);

    float inv[H_HEADS];
    #pragma unroll
    for (int h = 0; h < H_HEADS; ++h) inv[h] = 1.f / (ls[h] + 1e-9f);
    if (lane == 0) {
      #pragma unroll
      for (int h = 0; h < H_HEADS; ++h) { m_sh[h] = lm[h]; inv_sh[h] = inv[h]; }
    }
    if (fits) {
      for (int i = lane; i < deg; i += 64) {
        float a = 0.f;
        #pragma unroll
        for (int h = 0; h < H_HEADS; ++h) a += attn_lds[i * 8 + h] * inv[h];
        av_lds[i] = 0.125f * a;
      }
    }
  }
  __syncthreads();

  int lane = tid & 63, wv = tid >> 6;
  int h = lane >> 3;
  int fv = lane * 8;
  int vi = fv >> 7, vw = fv & 127;
  float ih = inv_sh[h], mh = m_sh[h];
  float accs[8] = {0,0,0,0,0,0,0,0};
  float accv[8] = {0,0,0,0,0,0,0,0};

  auto body = [&](int i) {
    int colv;
    float wgt, av;
    if (fits) {
      colv = col_lds[i];
      wgt = attn_lds[i * 8 + h] * ih;
      av = av_lds[i];
    } else {
      colv = cols[beg + i];
      const float* lp = logits + (size_t)(beg + i) * 8;
      wgt = expf(lp[h] - mh) * ih;
      float a = 0.f;
      #pragma unroll
      for (int hh = 0; hh < H_HEADS; ++hh)
        a += expf(lp[hh] - m_sh[hh]) * inv_sh[hh];
      av = 0.125f * a;
    }
    int4 vs = *reinterpret_cast<const int4*>(qkv_s + (size_t)colv * QKV3 + 1024 + lane * 8);
    union U { int4 v; unsigned short u[8]; } uv; uv.v = vs;
    #pragma unroll
    for (int j = 0; j < 8; ++j) accs[j] = fmaf(wgt, h2f(uv.u[j]), accs[j]);
    if (lane < 48) {
      int4 vvl = *reinterpret_cast<const int4*>(qkv_v + ((size_t)colv * 3 + vi) * VQKV3 + 256 + vw);
      union U2 { int4 v; unsigned short u[8]; } uv2; uv2.v = vvl;
      #pragma unroll
      for (int j = 0; j < 8; ++j) accv[j] = fmaf(av, h2f(uv2.u[j]), accv[j]);
    }
  };

  int i = wv;
  for (; i + 4 < deg; i += 8) { body(i); body(i + 4); }
  if (i < deg) body(i);
  __syncthreads();

  float* red_s = attn_lds;            // [4][512]
  float* red_v = attn_lds + 2048;     // [4][384]
  #pragma unroll
  for (int j = 0; j < 8; j += 4)
    *reinterpret_cast<float4*>(&red_s[wv * 512 + lane * 8 + j]) =
      make_float4(accs[j], accs[j+1], accs[j+2], accs[j+3]);
  if (lane < 48) {
    #pragma unroll
    for (int j = 0; j < 8; j += 4)
      *reinterpret_cast<float4*>(&red_v[wv * 384 + lane * 8 + j]) =
        make_float4(accv[j], accv[j+1], accv[j+2], accv[j+3]);
  }
  __syncthreads();

  {
    int d0 = 2 * tid;
    float s0 = red_s[d0] + red_s[512 + d0] + red_s[1024 + d0] + red_s[1536 + d0];
    float s1 = red_s[d0+1] + red_s[512 + d0+1] + red_s[1024 + d0+1] + red_s[1536 + d0+1];
    ushort2 o; o.x = f2h(s0); o.y = f2h(s1);
    *reinterpret_cast<ushort2*>(out_s + (size_t)n * S_DIM + d0) = o;
  }
  if (tid < 192) {
    int d0 = 2 * tid;
    float s0 = red_v[d0] + red_v[384 + d0] + red_v[768 + d0] + red_v[1152 + d0];
    float s1 = red_v[d0+1] + red_v[384 + d0+1] + red_v[768 + d0+1] + red_v[1152 + d0+1];
    ushort2 o; o.x = f2h(s0); o.y = f2h(s1);
    *reinterpret_cast<ushort2*>(out_v + (size_t)n * NV3 + d0) = o;
  }
}

// -------- vec output epilogue --------
__global__ __launch_bounds__(128) void vec_epilogue_kernel(
    const float* __restrict__ tmp, const float* __restrict__ bout_v,
    const float* __restrict__ vectors, float* __restrict__ out)
{
  __shared__ float l[NV3];
  int n = blockIdx.x, t = threadIdx.x;
  #pragma unroll
  for (int i = 0; i < 3; ++i)
    l[i * 128 + t] = tmp[((size_t)n * 3 + i) * V_DIM + t];
  __syncthreads();
  #pragma unroll
  for (int c = 0; c < 3; ++c) {
    int j = t + c * 128;      // j = w*3 + i
    int w = j / 3, i = j - 3 * w;
    out[(size_t)n * NV3 + j] = l[i * 128 + w] + bout_v[w] + vectors[(size_t)n * NV3 + j];
  }
}

// -------- residual + LayerNorm (wave per row) --------
__global__ __launch_bounds__(256) void ln_kernel(
    const float* __restrict__ x0, const float* __restrict__ dx,
    const float* __restrict__ g, const float* __restrict__ b,
    float* __restrict__ out)
{
  int r = blockIdx.x * 4 + (threadIdx.x >> 6);
  int lane = threadIdx.x & 63;
  if (r >= N_NODES) return;
  float x[8];
  float s = 0.f;
  #pragma unroll
  for (int j = 0; j < 8; ++j) {
    int d = lane + j * 64;
    x[j] = x0[(size_t)r * S_DIM + d] + dx[(size_t)r * S_DIM + d];
    s += x[j];
  }
  s = wave_sum(s);
  float mu = s * (1.f / 512.f);
  float vs = 0.f;
  #pragma unroll
  for (int j = 0; j < 8; ++j) { float t = x[j] - mu; vs += t * t; }
  vs = wave_sum(vs);
  float inv = rsqrtf(vs * (1.f / 512.f) + 1e-5f);
  #pragma unroll
  for (int j = 0; j < 8; ++j) {
    int d = lane + j * 64;
    out[(size_t)r * S_DIM + d] = (x[j] - mu) * inv * g[d] + b[d];
  }
}

extern "C" void kernel_launch(void* const* d_in, const int* in_sizes, int n_in,
                              void* d_out, int out_size, void* d_ws, size_t ws_size,
                              hipStream_t stream)
{
  (void)in_sizes; (void)n_in; (void)out_size; (void)ws_size;
  const float* scalars  = (const float*)d_in[0];
  const float* vectors  = (const float*)d_in[1];
  const float* edge_vec = (const float*)d_in[2];
  const float* Wq_s = (const float*)d_in[3];
  const float* bq_s = (const float*)d_in[4];
  const float* Wk_s = (const float*)d_in[5];
  const float* bk_s = (const float*)d_in[6];
  const float* Wv_s = (const float*)d_in[7];
  const float* bv_s = (const float*)d_in[8];
  const float* Wq_v = (const float*)d_in[9];
  const float* Wk_v = (const float*)d_in[10];
  const float* Wv_v = (const float*)d_in[11];
  const float* Wout_s = (const float*)d_in[12];
  const float* bout_s = (const float*)d_in[13];
  const float* Wout_v = (const float*)d_in[14];
  const float* bout_v = (const float*)d_in[15];
  const float* W_edge = (const float*)d_in[16];
  const float* b_edge = (const float*)d_in[17];
  const float* ln_g = (const float*)d_in[18];
  const float* ln_b = (const float*)d_in[19];
  const int* ei = (const int*)d_in[20];

  float* out = (float*)d_out;
  const size_t NS  = (size_t)N_NODES * S_DIM;     // 5,120,000
  const size_t NVs = (size_t)N_NODES * NV3;       // 3,840,000
  const size_t EH  = (size_t)E_EDGES * H_HEADS;   // 1,280,000
  const size_t WSZ = (size_t)S_DIM * S_DIM;
  const size_t WVZ = (size_t)V_DIM * V_DIM;
  const int MV = N_NODES * 3;

  char* base = (char*)d_ws;
  auto carve = [&](size_t bytes) -> char* {
    char* p = base;
    base += (bytes + 255) & ~(size_t)255;
    return p;
  };
  unsigned short* Af16 = (unsigned short*)carve(NS * 2);    // 10.24MB
  unsigned short* VT0  = (unsigned short*)carve(NVs * 2);   // 7.68MB
  float* tmpv = (float*)Af16;   // alias (15.36MB into Af16+VT0, both dead by then)
  unsigned short* qkv_s = (unsigned short*)carve((size_t)N_NODES * QKV3 * 2);   // 30.72MB
  unsigned short* qkv_v = (unsigned short*)carve((size_t)MV * VQKV3 * 2);       // 23.04MB
  unsigned short* outs_pre = (unsigned short*)carve(NS * 2);
  unsigned short* outv_pre = (unsigned short*)carve(NVs * 2);
  float* dx       = (float*)carve(NS * 4);
  float* logitsS  = (float*)carve(EH * 4);
  float* edge_att = (float*)carve(EH * 4);
  int*   colsS    = (int*)carve(E_EDGES * 4);
  unsigned short* WqkvT  = (unsigned short*)carve(3 * WSZ * 2);
  unsigned short* WoT    = (unsigned short*)carve(WSZ * 2);
  unsigned short* WqkvvT = (unsigned short*)carve(3 * WVZ * 2);
  unsigned short* WovT   = (unsigned short*)carve(WVZ * 2);
  float* bias_cat = (float*)carve(QKV3 * 4);
  int* counts = (int*)carve(N_NODES * 4);
  int* offs   = (int*)carve((N_NODES + 1) * 4);
  int* cursor = (int*)carve(N_NODES * 4);
  int* eord   = (int*)carve(E_EDGES * 4);

  hipMemsetAsync(counts, 0, N_NODES * sizeof(int), stream);
  hipMemsetAsync(cursor, 0, N_NODES * sizeof(int), stream);

  // conversions / transposes
  f32_to_f16_kernel<<<(int)(NS / 4 + 255) / 256, 256, 0, stream>>>(scalars, Af16, (int)(NS / 4));
  dim3 tBlk(32, 8);
  transpose4_kernel<<<dim3(16, 16, 4), tBlk, 0, stream>>>(Wq_s, Wk_s, Wv_s, Wout_s, WqkvT, WoT, S_DIM);
  transpose4_kernel<<<dim3(4, 4, 4), tBlk, 0, stream>>>(Wq_v, Wk_v, Wv_v, Wout_v, WqkvvT, WovT, V_DIM);
  vec_transpose_kernel<<<N_NODES, 128, 0, stream>>>(vectors, VT0);
  bias_cat_kernel<<<6, 256, 0, stream>>>(bq_s, bk_s, bv_s, bias_cat);

  // fused QKV projections
  gemm_f16_kernel<<<dim3(QKV3 / 128, (N_NODES + 127) / 128), 256, 0, stream>>>(
      Af16, WqkvT, bias_cat, nullptr, qkv_s, N_NODES, S_DIM, QKV3);
  gemm_f16_kernel<<<dim3(VQKV3 / 128, (MV + 127) / 128), 256, 0, stream>>>(
      VT0, WqkvvT, nullptr, nullptr, qkv_v, MV, V_DIM, VQKV3);

  // CSR
  count_kernel<<<(E_EDGES + 255) / 256, 256, 0, stream>>>(ei, counts);
  scan_kernel<<<1, 1024, 0, stream>>>(counts, offs);
  scatter_kernel<<<(E_EDGES + 255) / 256, 256, 0, stream>>>(ei, offs, cursor, eord);

  // edge stage
  bessel_kernel<<<E_EDGES / 32, 256, 0, stream>>>(edge_vec, eord, W_edge, b_edge, edge_att);
  edge_logits_kernel<<<E_EDGES / 32, 256, 0, stream>>>(qkv_s, qkv_v, ei, eord, edge_att,
                                                       logitsS, colsS);

  // softmax + aggregate
  agg_kernel<<<N_NODES, 256, 0, stream>>>(logitsS, colsS, qkv_s, qkv_v, offs,
                                          outs_pre, outv_pre);

  // output projections + epilogues
  gemm_f16_kernel<<<dim3(S_DIM / 128, (N_NODES + 127) / 128), 256, 0, stream>>>(
      outs_pre, WoT, bout_s, dx, nullptr, N_NODES, S_DIM, S_DIM);
  gemm_f16_kernel<<<dim3(1, (MV + 127) / 128), 256, 0, stream>>>(
      outv_pre, WovT, nullptr, tmpv, nullptr, MV, V_DIM, V_DIM);
  vec_epilogue_kernel<<<N_NODES, 128, 0, stream>>>(tmpv, bout_v, vectors, out + NS);
  ln_kernel<<<2500, 256, 0, stream>>>(scalars, dx, ln_g, ln_b, out);
}

// Round 7
// 276.742 us; speedup vs baseline: 3.2781x; 1.0827x over previous
//
#include <hip/hip_runtime.h>
#include <math.h>

#define N_NODES 10000
#define E_EDGES 160000
#define S_DIM 512
#define QKV3 (3*S_DIM)   // 1536
#define V_DIM 128
#define VQKV3 (3*V_DIM)  // 384
#define H_HEADS 8
#define R_BASIS 32
#define HD_DIM 64
#define NV3 (V_DIM*3)    // 384
#define KV8P 896         // fp8 V row: 512 scalar + 384 vector

typedef _Float16 f16;
typedef f16 f16x2 __attribute__((ext_vector_type(2)));
typedef f16 f16x8 __attribute__((ext_vector_type(8)));
typedef float f32x4 __attribute__((ext_vector_type(4)));
typedef float fl2 __attribute__((ext_vector_type(2)));

static __device__ __forceinline__ float h2f(unsigned short u) {
  f16 h; __builtin_memcpy(&h, &u, 2); return (float)h;
}
static __device__ __forceinline__ unsigned short f2h(float f) {
  f16 h = (f16)f; unsigned short u; __builtin_memcpy(&u, &h, 2); return u;
}
static __device__ __forceinline__ float wave_sum(float v) {
  #pragma unroll
  for (int o = 32; o > 0; o >>= 1) v += __shfl_xor(v, o, 64);
  return v;
}
static __device__ __forceinline__ float wave_max(float v) {
  #pragma unroll
  for (int o = 32; o > 0; o >>= 1) v = fmaxf(v, __shfl_xor(v, o, 64));
  return v;
}
static __device__ __forceinline__ float dot_i4(int4 a, int4 b, float s) {
  union U { int4 v; f16x2 h[4]; } ua, ub;
  ua.v = a; ub.v = b;
  #pragma unroll
  for (int j = 0; j < 4; ++j)
    s = __builtin_amdgcn_fdot2(ua.h[j], ub.h[j], s, false);
  return s;
}
// async global->LDS, 16B per lane; dest must be lane-linear (wavebase + lane*16)
static __device__ __forceinline__ void glds16(const unsigned short* g, unsigned short* l) {
  __builtin_amdgcn_global_load_lds(
      (const __attribute__((address_space(1))) unsigned int*)g,
      (__attribute__((address_space(3))) unsigned int*)l, 16, 0, 0);
}

// ------- fused prep: f32->f16 scalars | edge count | bias concat -------
__global__ __launch_bounds__(256) void prep_kernel(
    const float* __restrict__ scalars, unsigned short* __restrict__ Af16,
    const int* __restrict__ ei, int* __restrict__ counts,
    const float* __restrict__ bq, const float* __restrict__ bk,
    const float* __restrict__ bv, float* __restrict__ bias_cat)
{
  int b = blockIdx.x, t = threadIdx.x;
  if (b < 5000) {                       // 5000*256 = 1,280,000 float4 chunks
    int i = b * 256 + t;
    float4 v = reinterpret_cast<const float4*>(scalars)[i];
    ushort4 o;
    o.x = f2h(v.x); o.y = f2h(v.y); o.z = f2h(v.z); o.w = f2h(v.w);
    reinterpret_cast<ushort4*>(Af16)[i] = o;
  } else if (b < 5625) {                // 625*256 >= 160,000 edges
    int e = (b - 5000) * 256 + t;
    if (e < E_EDGES) atomicAdd(&counts[ei[e]], 1);
  } else {                              // 6 blocks: bias concat [1536]
    int c = (b - 5625) * 256 + t;
    if (c < QKV3)
      bias_cat[c] = (c < 512) ? bq[c] : (c < 1024) ? bk[c - 512] : bv[c - 1024];
  }
}

// ------- 4 weight transposes in one launch: z=0..2 -> cat dst, z=3 -> Do -------
__global__ __launch_bounds__(256) void transpose4_kernel(
    const float* __restrict__ W0, const float* __restrict__ W1,
    const float* __restrict__ W2, const float* __restrict__ W3,
    unsigned short* __restrict__ Dcat, unsigned short* __restrict__ Do, int D)
{
  __shared__ float t[32][33];
  int z = blockIdx.z;
  const float* W = (z == 0) ? W0 : (z == 1) ? W1 : (z == 2) ? W2 : W3;
  unsigned short* dst = (z < 3) ? Dcat + (size_t)z * D * D : Do;
  int n0 = blockIdx.x * 32, k0 = blockIdx.y * 32;
  int x = threadIdx.x, y = threadIdx.y;   // 32 x 8
  #pragma unroll
  for (int j = 0; j < 32; j += 8)
    t[y + j][x] = W[(size_t)(k0 + y + j) * D + n0 + x];
  __syncthreads();
  #pragma unroll
  for (int j = 0; j < 32; j += 8)
    dst[(size_t)(n0 + y + j) * D + k0 + x] = f2h(t[x][y + j]);
}

// ---------------- vectors [n][128][3] f32 -> VT [(n*3+i)][128] f16 ----------------
__global__ __launch_bounds__(128) void vec_transpose_kernel(
    const float* __restrict__ vecs, unsigned short* __restrict__ VT)
{
  __shared__ float l[NV3];
  int n = blockIdx.x, t = threadIdx.x;
  #pragma unroll
  for (int j = 0; j < 3; ++j) l[t + j * 128] = vecs[(size_t)n * NV3 + t + j * 128];
  __syncthreads();
  #pragma unroll
  for (int i = 0; i < 3; ++i)
    VT[((size_t)n * 3 + i) * V_DIM + t] = f2h(l[t * 3 + i]);
}

// ---------------- f16 MFMA GEMM (verified fast, round 5) ----------------
__global__ __launch_bounds__(256) void gemm_f16_kernel(
    const unsigned short* __restrict__ A, const unsigned short* __restrict__ Bt,
    const float* __restrict__ bias, float* __restrict__ Cf,
    unsigned short* __restrict__ Ch, int M, int K, int Nn)
{
  __shared__ unsigned short lds[2][2][128 * 32];
  int tid = threadIdx.x;
  int wid = tid >> 6, lane = tid & 63;
  int wr = wid >> 1, wc = wid & 1;
  int row0 = blockIdx.y * 128, col0 = blockIdx.x * 128;

  int r0 = tid >> 2, s0 = tid & 3;
  int r1 = r0 + 64;
  int sw0 = (r0 >> 1) & 3;
  int aoff = (s0 ^ sw0) * 8;
  int gra0 = row0 + r0; if (gra0 >= M) gra0 = M - 1;
  int gra1 = row0 + r1; if (gra1 >= M) gra1 = M - 1;
  const unsigned short* ag0 = A + (size_t)gra0 * K + aoff;
  const unsigned short* ag1 = A + (size_t)gra1 * K + aoff;
  const unsigned short* bg0 = Bt + (size_t)(col0 + r0) * K + aoff;
  const unsigned short* bg1 = Bt + (size_t)(col0 + r1) * K + aoff;

  f32x4 acc[4][4];
  #pragma unroll
  for (int m = 0; m < 4; ++m)
    #pragma unroll
    for (int n = 0; n < 4; ++n) acc[m][n] = (f32x4){0.f, 0.f, 0.f, 0.f};

  int lr = lane & 15, lq = lane >> 4;
  int slot = (lq ^ ((lr >> 1) & 3)) * 8;
  int aro[4], bro[4];
  #pragma unroll
  for (int m = 0; m < 4; ++m) aro[m] = (wr * 64 + m * 16 + lr) * 32 + slot;
  #pragma unroll
  for (int n = 0; n < 4; ++n) bro[n] = (wc * 64 + n * 16 + lr) * 32 + slot;

  int nk = K >> 5;
  glds16(ag0, &lds[0][0][tid * 8]);
  glds16(ag1, &lds[0][0][(tid + 256) * 8]);
  glds16(bg0, &lds[0][1][tid * 8]);
  glds16(bg1, &lds[0][1][(tid + 256) * 8]);
  __syncthreads();

  for (int t = 0; t < nk; ++t) {
    int cur = t & 1;
    if (t + 1 < nk) {
      int ko = (t + 1) << 5;
      glds16(ag0 + ko, &lds[cur ^ 1][0][tid * 8]);
      glds16(ag1 + ko, &lds[cur ^ 1][0][(tid + 256) * 8]);
      glds16(bg0 + ko, &lds[cur ^ 1][1][tid * 8]);
      glds16(bg1 + ko, &lds[cur ^ 1][1][(tid + 256) * 8]);
    }
    const unsigned short* Ab = lds[cur][0];
    const unsigned short* Bb = lds[cur][1];
    f16x8 af[4], bf[4];
    #pragma unroll
    for (int m = 0; m < 4; ++m) af[m] = *reinterpret_cast<const f16x8*>(Ab + aro[m]);
    #pragma unroll
    for (int n = 0; n < 4; ++n) bf[n] = *reinterpret_cast<const f16x8*>(Bb + bro[n]);
    #pragma unroll
    for (int m = 0; m < 4; ++m)
      #pragma unroll
      for (int n = 0; n < 4; ++n)
        acc[m][n] = __builtin_amdgcn_mfma_f32_16x16x32_f16(af[m], bf[n], acc[m][n], 0, 0, 0);
    __syncthreads();
  }

  float bcol[4];
  #pragma unroll
  for (int n = 0; n < 4; ++n)
    bcol[n] = bias ? bias[col0 + wc * 64 + n * 16 + lr] : 0.f;
  int rl = tid >> 3, cc = (tid & 7) * 16;

  if (Cf) {
    float* cst = reinterpret_cast<float*>(&lds[0][0][0]);
    #pragma unroll
    for (int m = 0; m < 4; ++m) {
      __syncthreads();
      #pragma unroll
      for (int n = 0; n < 4; ++n)
        #pragma unroll
        for (int j = 0; j < 4; ++j)
          cst[(wr * 16 + lq * 4 + j) * 128 + wc * 64 + n * 16 + lr] = acc[m][n][j] + bcol[n];
      __syncthreads();
      int row = row0 + (rl >> 4) * 64 + m * 16 + (rl & 15);
      if (row < M) {
        float4* dst = reinterpret_cast<float4*>(Cf + (size_t)row * Nn + col0 + cc);
        const float4* src = reinterpret_cast<const float4*>(cst + rl * 128 + cc);
        dst[0] = src[0]; dst[1] = src[1]; dst[2] = src[2]; dst[3] = src[3];
      }
    }
  } else {
    unsigned short* csth = &lds[0][0][0];
    #pragma unroll
    for (int m = 0; m < 4; ++m) {
      __syncthreads();
      #pragma unroll
      for (int n = 0; n < 4; ++n)
        #pragma unroll
        for (int j = 0; j < 4; ++j)
          csth[(wr * 16 + lq * 4 + j) * 128 + wc * 64 + n * 16 + lr] = f2h(acc[m][n][j] + bcol[n]);
      __syncthreads();
      int row = row0 + (rl >> 4) * 64 + m * 16 + (rl & 15);
      if (row < M) {
        int4* dst = reinterpret_cast<int4*>(Ch + (size_t)row * Nn + col0 + cc);
        const int4* src = reinterpret_cast<const int4*>(csth + rl * 128 + cc);
        dst[0] = src[0]; dst[1] = src[1];
      }
    }
  }
}

// -------- pack V into compact fp8 rows: v8 [n][896] (2 nodes/block) --------
__global__ __launch_bounds__(256) void pack_v8_kernel(
    const unsigned short* __restrict__ qkv_s, const unsigned short* __restrict__ qkv_v,
    unsigned char* __restrict__ v8)
{
  int t = threadIdx.x;
  int j = t & 127;
  if (j >= 112) return;
  int n = blockIdx.x * 2 + (t >> 7);
  int c = j * 8;
  const unsigned short* src;
  if (c < 512) {
    src = qkv_s + (size_t)n * QKV3 + 1024 + c;                 // v_s
  } else {
    int cc = c - 512, i = cc >> 7, w = cc & 127;
    src = qkv_v + ((size_t)n * 3 + i) * VQKV3 + 256 + w;       // v_v
  }
  int4 sv = *reinterpret_cast<const int4*>(src);
  union { int4 v; unsigned short u[8]; } us; us.v = sv;
  float f[8];
  #pragma unroll
  for (int q = 0; q < 8; ++q) f[q] = h2f(us.u[q]);
  unsigned int d0 = (unsigned)__builtin_amdgcn_cvt_pk_fp8_f32(f[0], f[1], 0, false);
  d0 = (unsigned)__builtin_amdgcn_cvt_pk_fp8_f32(f[2], f[3], (int)d0, true);
  unsigned int d1 = (unsigned)__builtin_amdgcn_cvt_pk_fp8_f32(f[4], f[5], 0, false);
  d1 = (unsigned)__builtin_amdgcn_cvt_pk_fp8_f32(f[6], f[7], (int)d1, true);
  uint2 o; o.x = d0; o.y = d1;
  *reinterpret_cast<uint2*>(v8 + (size_t)n * KV8P + c) = o;
}

// -------- CSR scan + scatter --------
__global__ __launch_bounds__(1024) void scan_kernel(const int* __restrict__ counts,
                                                    int* __restrict__ offs) {
  __shared__ int wsum[16];
  __shared__ int carry_s;
  int tid = threadIdx.x;
  int lane = tid & 63, w = tid >> 6;
  if (tid == 0) carry_s = 0;
  __syncthreads();
  for (int base = 0; base < N_NODES; base += 1024) {
    int i = base + tid;
    int v = (i < N_NODES) ? counts[i] : 0;
    int x = v;
    #pragma unroll
    for (int o = 1; o < 64; o <<= 1) {
      int t = __shfl_up(x, o, 64);
      if (lane >= o) x += t;
    }
    if (lane == 63) wsum[w] = x;
    __syncthreads();
    if (w == 0 && lane < 16) {
      int t = wsum[lane];
      #pragma unroll
      for (int o = 1; o < 16; o <<= 1) {
        int u = __shfl_up(t, o, 64);
        if (lane >= o) t += u;
      }
      wsum[lane] = t;
    }
    __syncthreads();
    int incl = x + ((w > 0) ? wsum[w - 1] : 0);
    int c = carry_s;
    __syncthreads();
    if (i < N_NODES) offs[i] = c + incl - v;
    if (tid == 1023) carry_s = c + incl;
    __syncthreads();
  }
  if (tid == 0) offs[N_NODES] = carry_s;
}

__global__ void scatter_kernel(const int* __restrict__ ei, const int* __restrict__ offs,
                               int* __restrict__ cursor, int* __restrict__ eord) {
  int e = blockIdx.x * 256 + threadIdx.x;
  if (e < E_EDGES) {
    int r = ei[e];
    int p = offs[r] + atomicAdd(&cursor[r], 1);
    eord[p] = e;
  }
}

// -------- per-edge logits: 8 lanes/edge, f16 gathers, fused bessel --------
__global__ __launch_bounds__(256, 4) void edge_logits_kernel(
    const unsigned short* __restrict__ qkv_s, const unsigned short* __restrict__ qkv_v,
    const float* __restrict__ edge_vec, const int* __restrict__ ei,
    const int* __restrict__ eord,
    const float* __restrict__ W_edge, const float* __restrict__ b_edge,
    float* __restrict__ logits, int* __restrict__ cols)
{
  __shared__ float Wl[R_BASIS * H_HEADS];
  Wl[threadIdx.x] = W_edge[threadIdx.x];
  __syncthreads();

  int lane = threadIdx.x & 63;
  int wv = threadIdx.x >> 6;
  int g = lane >> 3, h = lane & 7;
  int pos = blockIdx.x * 32 + wv * 8 + g;
  int e = eord[pos];
  int row = ei[e], col = ei[E_EDGES + e];

  // issue all gathers first (latency batching)
  const unsigned short* qp = qkv_s + (size_t)row * QKV3 + h * HD_DIM;
  const unsigned short* kp = qkv_s + (size_t)col * QKV3 + 512 + h * HD_DIM;
  int4 qa[8], ka[8];
  #pragma unroll
  for (int r = 0; r < 8; ++r) qa[r] = *reinterpret_cast<const int4*>(qp + r * 8);
  #pragma unroll
  for (int r = 0; r < 8; ++r) ka[r] = *reinterpret_cast<const int4*>(kp + r * 8);

  int4 qv[6], kv[6];
  #pragma unroll
  for (int r = 0; r < 6; ++r) {
    int f = h * 48 + r * 8;
    int i = f >> 7, w = f & 127;
    qv[r] = *reinterpret_cast<const int4*>(qkv_v + ((size_t)row * 3 + i) * VQKV3 + w);
    kv[r] = *reinterpret_cast<const int4*>(qkv_v + ((size_t)col * 3 + i) * VQKV3 + 128 + w);
  }

  float ex = edge_vec[(size_t)e * 3 + 0];
  float ey = edge_vec[(size_t)e * 3 + 1];
  float ez = edge_vec[(size_t)e * 3 + 2];

  float qk = 0.f;
  #pragma unroll
  for (int r = 0; r < 8; ++r) qk = dot_i4(qa[r], ka[r], qk);

  float pv = 0.f;
  #pragma unroll
  for (int r = 0; r < 6; ++r) pv = dot_i4(qv[r], kv[r], pv);
  pv += __shfl_xor(pv, 1, 64);
  pv += __shfl_xor(pv, 2, 64);
  pv += __shfl_xor(pv, 4, 64);
  pv *= 0.57735026918962576f;  // 1/sqrt(3)

  // bessel + edge MLP (4-way-ILP sin recurrence), lane = head column
  float d = sqrtf(ex * ex + ey * ey + ez * ez);
  float th = d * 0.31415926535897932f;  // pi*d/10
  float s1 = __sinf(th), c1 = __cosf(th);
  float s2 = 2.f * s1 * c1,         c2 = fmaf(c1, c1, -s1 * s1);
  float s3 = fmaf(s2, c1, c2 * s1), c3 = fmaf(c2, c1, -s2 * s1);
  float s4 = 2.f * s2 * c2,         c4 = fmaf(c2, c2, -s2 * s2);
  float sr[4] = {s1, s2, s3, s4};
  float cr[4] = {c1, c2, c3, c4};
  float acc = 0.f;
  #pragma unroll
  for (int t = 0; t < 8; ++t) {
    #pragma unroll
    for (int j = 0; j < 4; ++j) {
      acc = fmaf(sr[j], Wl[(t * 4 + j) * H_HEADS + h], acc);
      float sn = fmaf(sr[j], c4, cr[j] * s4);
      cr[j] = fmaf(cr[j], c4, -sr[j] * s4);
      sr[j] = sn;
    }
  }
  float cut = (d < 10.f) ? 0.5f * (c1 + 1.f) : 0.f;
  float eah = fmaf(acc, cut / fmaxf(d, 1e-8f), b_edge[h]);

  logits[(size_t)pos * H_HEADS + h] = (qk + pv + eah) * 0.125f;
  if (h == 0) cols[pos] = col;
}

// -------- per-node softmax + aggregation (4-wave edge-parallel, fp8 V) --------
#define MAXDEG 512
__global__ __launch_bounds__(256) void agg_kernel(
    const float* __restrict__ logits, const int* __restrict__ cols,
    const unsigned char* __restrict__ v8, const int* __restrict__ offs,
    unsigned short* __restrict__ out_s, unsigned short* __restrict__ out_v)
{
  __shared__ float attn_lds[MAXDEG * H_HEADS];
  __shared__ float av_lds[MAXDEG];
  __shared__ int col_lds[MAXDEG];
  __shared__ float m_sh[H_HEADS], inv_sh[H_HEADS];

  int n = blockIdx.x;
  int beg = offs[n];
  int deg = offs[n + 1] - beg;
  int tid = threadIdx.x;
  bool fits = (deg <= MAXDEG);

  if (tid < 64) {
    int lane = tid;
    float lm[H_HEADS];
    #pragma unroll
    for (int h = 0; h < H_HEADS; ++h) lm[h] = -INFINITY;
    for (int i = lane; i < deg; i += 64) {
      const float4* lp = reinterpret_cast<const float4*>(logits + (size_t)(beg + i) * 8);
      float4 a = lp[0], b = lp[1];
      if (fits) col_lds[i] = cols[beg + i];
      lm[0] = fmaxf(lm[0], a.x); lm[1] = fmaxf(lm[1], a.y);
      lm[2] = fmaxf(lm[2], a.z); lm[3] = fmaxf(lm[3], a.w);
      lm[4] = fmaxf(lm[4], b.x); lm[5] = fmaxf(lm[5], b.y);
      lm[6] = fmaxf(lm[6], b.z); lm[7] = fmaxf(lm[7], b.w);
    }
    #pragma unroll
    for (int h = 0; h < H_HEADS; ++h) lm[h] = wave_max(lm[h]);

    float ls[H_HEADS];
    #pragma unroll
    for (int h = 0; h < H_HEADS; ++h) ls[h] = 0.f;
    for (int i = lane; i < deg; i += 64) {
      const float4* lp = reinterpret_cast<const float4*>(logits + (size_t)(beg + i) * 8);
      float4 a = lp[0], b = lp[1];
      float w[8];
      w[0] = expf(a.x - lm[0]); w[1] = expf(a.y - lm[1]);
      w[2] = expf(a.z - lm[2]); w[3] = expf(a.w - lm[3]);
      w[4] = expf(b.x - lm[4]); w[5] = expf(b.y - lm[5]);
      w[6] = expf(b.z - lm[6]); w[7] = expf(b.w - lm[7]);
      #pragma unroll
      for (int h = 0; h < H_HEADS; ++h) {
        ls[h] += w[h];
        if (fits) attn_lds[i * 8 + h] = w[h];
      }
    }
    #pragma unroll
    for (int h = 0; h < H_HEADS; ++h) ls[h] = wave_sum(ls[h]);

    float inv[H_HEADS];
    #pragma unroll
    for (int h = 0; h < H_HEADS; ++h) inv[h] = 1.f / (ls[h] + 1e-9f);
    if (lane == 0) {
      #pragma unroll
      for (int h = 0; h < H_HEADS; ++h) { m_sh[h] = lm[h]; inv_sh[h] = inv[h]; }
    }
    if (fits) {
      for (int i = lane; i < deg; i += 64) {
        float a = 0.f;
        #pragma unroll
        for (int h = 0; h < H_HEADS; ++h) a += attn_lds[i * 8 + h] * inv[h];
        av_lds[i] = 0.125f * a;
      }
    }
  }
  __syncthreads();

  int lane = tid & 63, wv = tid >> 6;
  int h = lane >> 3;
  float ih = inv_sh[h], mh = m_sh[h];
  float accs[8] = {0,0,0,0,0,0,0,0};
  float accv[8] = {0,0,0,0,0,0,0,0};

  auto body = [&](int i) {
    int colv;
    float wgt, av;
    if (fits) {
      colv = col_lds[i];
      wgt = attn_lds[i * 8 + h] * ih;
      av = av_lds[i];
    } else {
      colv = cols[beg + i];
      const float* lp = logits + (size_t)(beg + i) * 8;
      wgt = expf(lp[h] - mh) * ih;
      float a = 0.f;
      #pragma unroll
      for (int hh = 0; hh < H_HEADS; ++hh)
        a += expf(lp[hh] - m_sh[hh]) * inv_sh[hh];
      av = 0.125f * a;
    }
    uint2 vs = *reinterpret_cast<const uint2*>(v8 + (size_t)colv * KV8P + lane * 8);
    fl2 b0 = __builtin_amdgcn_cvt_pk_f32_fp8(vs.x, false);
    fl2 b1 = __builtin_amdgcn_cvt_pk_f32_fp8(vs.x, true);
    fl2 b2 = __builtin_amdgcn_cvt_pk_f32_fp8(vs.y, false);
    fl2 b3 = __builtin_amdgcn_cvt_pk_f32_fp8(vs.y, true);
    accs[0] = fmaf(wgt, b0.x, accs[0]); accs[1] = fmaf(wgt, b0.y, accs[1]);
    accs[2] = fmaf(wgt, b1.x, accs[2]); accs[3] = fmaf(wgt, b1.y, accs[3]);
    accs[4] = fmaf(wgt, b2.x, accs[4]); accs[5] = fmaf(wgt, b2.y, accs[5]);
    accs[6] = fmaf(wgt, b3.x, accs[6]); accs[7] = fmaf(wgt, b3.y, accs[7]);
    if (lane < 48) {
      uint2 vv = *reinterpret_cast<const uint2*>(v8 + (size_t)colv * KV8P + 512 + lane * 8);
      fl2 c0 = __builtin_amdgcn_cvt_pk_f32_fp8(vv.x, false);
      fl2 c1 = __builtin_amdgcn_cvt_pk_f32_fp8(vv.x, true);
      fl2 c2 = __builtin_amdgcn_cvt_pk_f32_fp8(vv.y, false);
      fl2 c3 = __builtin_amdgcn_cvt_pk_f32_fp8(vv.y, true);
      accv[0] = fmaf(av, c0.x, accv[0]); accv[1] = fmaf(av, c0.y, accv[1]);
      accv[2] = fmaf(av, c1.x, accv[2]); accv[3] = fmaf(av, c1.y, accv[3]);
      accv[4] = fmaf(av, c2.x, accv[4]); accv[5] = fmaf(av, c2.y, accv[5]);
      accv[6] = fmaf(av, c3.x, accv[6]); accv[7] = fmaf(av, c3.y, accv[7]);
    }
  };

  int i = wv;
  for (; i + 4 < deg; i += 8) { body(i); body(i + 4); }
  if (i < deg) body(i);
  __syncthreads();

  float* red_s = attn_lds;            // [4][512]
  float* red_v = attn_lds + 2048;     // [4][384]
  #pragma unroll
  for (int j = 0; j < 8; j += 4)
    *reinterpret_cast<float4*>(&red_s[wv * 512 + lane * 8 + j]) =
      make_float4(accs[j], accs[j+1], accs[j+2], accs[j+3]);
  if (lane < 48) {
    #pragma unroll
    for (int j = 0; j < 8; j += 4)
      *reinterpret_cast<float4*>(&red_v[wv * 384 + lane * 8 + j]) =
        make_float4(accv[j], accv[j+1], accv[j+2], accv[j+3]);
  }
  __syncthreads();

  {
    int d0 = 2 * tid;
    float s0 = red_s[d0] + red_s[512 + d0] + red_s[1024 + d0] + red_s[1536 + d0];
    float s1 = red_s[d0+1] + red_s[512 + d0+1] + red_s[1024 + d0+1] + red_s[1536 + d0+1];
    ushort2 o; o.x = f2h(s0); o.y = f2h(s1);
    *reinterpret_cast<ushort2*>(out_s + (size_t)n * S_DIM + d0) = o;
  }
  if (tid < 192) {
    int d0 = 2 * tid;
    float s0 = red_v[d0] + red_v[384 + d0] + red_v[768 + d0] + red_v[1152 + d0];
    float s1 = red_v[d0+1] + red_v[384 + d0+1] + red_v[768 + d0+1] + red_v[1152 + d0+1];
    ushort2 o; o.x = f2h(s0); o.y = f2h(s1);
    *reinterpret_cast<ushort2*>(out_v + (size_t)n * NV3 + d0) = o;
  }
}

// -------- vec output epilogue --------
__global__ __launch_bounds__(128) void vec_epilogue_kernel(
    const float* __restrict__ tmp, const float* __restrict__ bout_v,
    const float* __restrict__ vectors, float* __restrict__ out)
{
  __shared__ float l[NV3];
  int n = blockIdx.x, t = threadIdx.x;
  #pragma unroll
  for (int i = 0; i < 3; ++i)
    l[i * 128 + t] = tmp[((size_t)n * 3 + i) * V_DIM + t];
  __syncthreads();
  #pragma unroll
  for (int c = 0; c < 3; ++c) {
    int j = t + c * 128;      // j = w*3 + i
    int w = j / 3, i = j - 3 * w;
    out[(size_t)n * NV3 + j] = l[i * 128 + w] + bout_v[w] + vectors[(size_t)n * NV3 + j];
  }
}

// -------- residual + LayerNorm (wave per row) --------
__global__ __launch_bounds__(256) void ln_kernel(
    const float* __restrict__ x0, const float* __restrict__ dx,
    const float* __restrict__ g, const float* __restrict__ b,
    float* __restrict__ out)
{
  int r = blockIdx.x * 4 + (threadIdx.x >> 6);
  int lane = threadIdx.x & 63;
  if (r >= N_NODES) return;
  float x[8];
  float s = 0.f;
  #pragma unroll
  for (int j = 0; j < 8; ++j) {
    int d = lane + j * 64;
    x[j] = x0[(size_t)r * S_DIM + d] + dx[(size_t)r * S_DIM + d];
    s += x[j];
  }
  s = wave_sum(s);
  float mu = s * (1.f / 512.f);
  float vs = 0.f;
  #pragma unroll
  for (int j = 0; j < 8; ++j) { float t = x[j] - mu; vs += t * t; }
  vs = wave_sum(vs);
  float inv = rsqrtf(vs * (1.f / 512.f) + 1e-5f);
  #pragma unroll
  for (int j = 0; j < 8; ++j) {
    int d = lane + j * 64;
    out[(size_t)r * S_DIM + d] = (x[j] - mu) * inv * g[d] + b[d];
  }
}

extern "C" void kernel_launch(void* const* d_in, const int* in_sizes, int n_in,
                              void* d_out, int out_size, void* d_ws, size_t ws_size,
                              hipStream_t stream)
{
  (void)in_sizes; (void)n_in; (void)out_size; (void)ws_size;
  const float* scalars  = (const float*)d_in[0];
  const float* vectors  = (const float*)d_in[1];
  const float* edge_vec = (const float*)d_in[2];
  const float* Wq_s = (const float*)d_in[3];
  const float* bq_s = (const float*)d_in[4];
  const float* Wk_s = (const float*)d_in[5];
  const float* bk_s = (const float*)d_in[6];
  const float* Wv_s = (const float*)d_in[7];
  const float* bv_s = (const float*)d_in[8];
  const float* Wq_v = (const float*)d_in[9];
  const float* Wk_v = (const float*)d_in[10];
  const float* Wv_v = (const float*)d_in[11];
  const float* Wout_s = (const float*)d_in[12];
  const float* bout_s = (const float*)d_in[13];
  const float* Wout_v = (const float*)d_in[14];
  const float* bout_v = (const float*)d_in[15];
  const float* W_edge = (const float*)d_in[16];
  const float* b_edge = (const float*)d_in[17];
  const float* ln_g = (const float*)d_in[18];
  const float* ln_b = (const float*)d_in[19];
  const int* ei = (const int*)d_in[20];

  float* out = (float*)d_out;
  const size_t NS  = (size_t)N_NODES * S_DIM;     // 5,120,000
  const size_t NVs = (size_t)N_NODES * NV3;       // 3,840,000
  const size_t EH  = (size_t)E_EDGES * H_HEADS;   // 1,280,000
  const size_t WSZ = (size_t)S_DIM * S_DIM;
  const size_t WVZ = (size_t)V_DIM * V_DIM;
  const int MV = N_NODES * 3;

  char* base = (char*)d_ws;
  auto carve = [&](size_t bytes) -> char* {
    char* p = base;
    base += (bytes + 255) & ~(size_t)255;
    return p;
  };
  unsigned short* Af16 = (unsigned short*)carve(NS * 2);    // 10.24MB
  unsigned short* VT0  = (unsigned short*)carve(NVs * 2);   // 7.68MB
  float* tmpv = (float*)Af16;   // alias (15.36MB; Af16+VT0 dead by then)
  unsigned short* qkv_s = (unsigned short*)carve((size_t)N_NODES * QKV3 * 2);   // 30.72MB
  unsigned short* qkv_v = (unsigned short*)carve((size_t)MV * VQKV3 * 2);       // 23.04MB
  unsigned short* outs_pre = (unsigned short*)carve(NS * 2);
  unsigned short* outv_pre = (unsigned short*)carve(NVs * 2);
  float* dx       = (float*)carve(NS * 4);        // 20.48MB
  // v8 aliases dx: lifetimes disjoint (v8 used pack->agg; dx written by Wout gemm after agg)
  unsigned char* v8 = (unsigned char*)dx;                       // 8.96MB
  float* logitsS  = (float*)carve(EH * 4);
  int*   colsS    = (int*)carve(E_EDGES * 4);
  unsigned short* WqkvT  = (unsigned short*)carve(3 * WSZ * 2);
  unsigned short* WoT    = (unsigned short*)carve(WSZ * 2);
  unsigned short* WqkvvT = (unsigned short*)carve(3 * WVZ * 2);
  unsigned short* WovT   = (unsigned short*)carve(WVZ * 2);
  float* bias_cat = (float*)carve(QKV3 * 4);
  int* counts = (int*)carve(N_NODES * 4);
  int* offs   = (int*)carve((N_NODES + 1) * 4);
  int* cursor = (int*)carve(N_NODES * 4);
  int* eord   = (int*)carve(E_EDGES * 4);

  hipMemsetAsync(counts, 0, N_NODES * sizeof(int), stream);
  hipMemsetAsync(cursor, 0, N_NODES * sizeof(int), stream);

  // fused prep: f32->f16 scalars | edge count | bias concat
  prep_kernel<<<5631, 256, 0, stream>>>(scalars, Af16, ei, counts,
                                        bq_s, bk_s, bv_s, bias_cat);
  dim3 tBlk(32, 8);
  transpose4_kernel<<<dim3(16, 16, 4), tBlk, 0, stream>>>(Wq_s, Wk_s, Wv_s, Wout_s, WqkvT, WoT, S_DIM);
  transpose4_kernel<<<dim3(4, 4, 4), tBlk, 0, stream>>>(Wq_v, Wk_v, Wv_v, Wout_v, WqkvvT, WovT, V_DIM);
  vec_transpose_kernel<<<N_NODES, 128, 0, stream>>>(vectors, VT0);

  // fused QKV projections
  gemm_f16_kernel<<<dim3(QKV3 / 128, (N_NODES + 127) / 128), 256, 0, stream>>>(
      Af16, WqkvT, bias_cat, nullptr, qkv_s, N_NODES, S_DIM, QKV3);
  gemm_f16_kernel<<<dim3(VQKV3 / 128, (MV + 127) / 128), 256, 0, stream>>>(
      VT0, WqkvvT, nullptr, nullptr, qkv_v, MV, V_DIM, VQKV3);

  // compact fp8 V rows
  pack_v8_kernel<<<N_NODES / 2, 256, 0, stream>>>(qkv_s, qkv_v, v8);

  // CSR
  scan_kernel<<<1, 1024, 0, stream>>>(counts, offs);
  scatter_kernel<<<(E_EDGES + 255) / 256, 256, 0, stream>>>(ei, offs, cursor, eord);

  // edge logits (f16 K gather + fused bessel)
  edge_logits_kernel<<<E_EDGES / 32, 256, 0, stream>>>(qkv_s, qkv_v, edge_vec,
                                                       ei, eord, W_edge, b_edge,
                                                       logitsS, colsS);

  // softmax + aggregate (fp8 V gather)
  agg_kernel<<<N_NODES, 256, 0, stream>>>(logitsS, colsS, v8, offs,
                                          outs_pre, outv_pre);

  // output projections + epilogues
  gemm_f16_kernel<<<dim3(S_DIM / 128, (N_NODES + 127) / 128), 256, 0, stream>>>(
      outs_pre, WoT, bout_s, dx, nullptr, N_NODES, S_DIM, S_DIM);
  gemm_f16_kernel<<<dim3(1, (MV + 127) / 128), 256, 0, stream>>>(
      outv_pre, WovT, nullptr, tmpv, nullptr, MV, V_DIM, V_DIM);
  vec_epilogue_kernel<<<N_NODES, 128, 0, stream>>>(tmpv, bout_v, vectors, out + NS);
  ln_kernel<<<2500, 256, 0, stream>>>(scalars, dx, ln_g, ln_b, out);
}

// Round 8
// 247.301 us; speedup vs baseline: 3.6684x; 1.1190x over previous
//
#include <hip/hip_runtime.h>
#include <math.h>

#define N_NODES 10000
#define E_EDGES 160000
#define S_DIM 512
#define QKV3 (3*S_DIM)   // 1536
#define V_DIM 128
#define VQKV3 (3*V_DIM)  // 384
#define H_HEADS 8
#define R_BASIS 32
#define HD_DIM 64
#define NV3 (V_DIM*3)    // 384
#define KV8P 896         // int8 row: 512 scalar + 384 vector

typedef _Float16 f16;
typedef f16 f16x2 __attribute__((ext_vector_type(2)));
typedef f16 f16x8 __attribute__((ext_vector_type(8)));
typedef float f32x4 __attribute__((ext_vector_type(4)));

static __device__ __forceinline__ float h2f(unsigned short u) {
  f16 h; __builtin_memcpy(&h, &u, 2); return (float)h;
}
static __device__ __forceinline__ unsigned short f2h(float f) {
  f16 h = (f16)f; unsigned short u; __builtin_memcpy(&u, &h, 2); return u;
}
static __device__ __forceinline__ float wave_sum(float v) {
  #pragma unroll
  for (int o = 32; o > 0; o >>= 1) v += __shfl_xor(v, o, 64);
  return v;
}
static __device__ __forceinline__ float wave_max(float v) {
  #pragma unroll
  for (int o = 32; o > 0; o >>= 1) v = fmaxf(v, __shfl_xor(v, o, 64));
  return v;
}

#if defined(__has_builtin)
#if __has_builtin(__builtin_amdgcn_sdot4)
#define SDOT4(a, b, c) __builtin_amdgcn_sdot4((int)(a), (int)(b), (c), false)
#endif
#endif
#ifndef SDOT4
static __device__ __forceinline__ int sdot4_sw(unsigned int a, unsigned int b, int c) {
  #pragma unroll
  for (int j = 0; j < 4; ++j)
    c += (int)(char)((a >> (8 * j)) & 0xff) * (int)(char)((b >> (8 * j)) & 0xff);
  return c;
}
#define SDOT4(a, b, c) sdot4_sw((a), (b), (c))
#endif

static __device__ __forceinline__ void fma_i8x4(unsigned int w, float wt, float* acc) {
  acc[0] = fmaf(wt, (float)(int)(char)(w & 0xff), acc[0]);
  acc[1] = fmaf(wt, (float)(int)(char)((w >> 8) & 0xff), acc[1]);
  acc[2] = fmaf(wt, (float)(int)(char)((w >> 16) & 0xff), acc[2]);
  acc[3] = fmaf(wt, (float)(int)(char)((w >> 24) & 0xff), acc[3]);
}

// async global->LDS, 16B per lane; dest must be lane-linear (wavebase + lane*16)
static __device__ __forceinline__ void glds16(const unsigned short* g, unsigned short* l) {
  __builtin_amdgcn_global_load_lds(
      (const __attribute__((address_space(1))) unsigned int*)g,
      (__attribute__((address_space(3))) unsigned int*)l, 16, 0, 0);
}

// ------- fused prep: f32->f16 scalars | edge count | bias concat -------
__global__ __launch_bounds__(256) void prep_kernel(
    const float* __restrict__ scalars, unsigned short* __restrict__ Af16,
    const int* __restrict__ ei, int* __restrict__ counts,
    const float* __restrict__ bq, const float* __restrict__ bk,
    const float* __restrict__ bv, float* __restrict__ bias_cat)
{
  int b = blockIdx.x, t = threadIdx.x;
  if (b < 5000) {
    int i = b * 256 + t;
    float4 v = reinterpret_cast<const float4*>(scalars)[i];
    ushort4 o;
    o.x = f2h(v.x); o.y = f2h(v.y); o.z = f2h(v.z); o.w = f2h(v.w);
    reinterpret_cast<ushort4*>(Af16)[i] = o;
  } else if (b < 5625) {
    int e = (b - 5000) * 256 + t;
    if (e < E_EDGES) atomicAdd(&counts[ei[e]], 1);
  } else {
    int c = (b - 5625) * 256 + t;
    if (c < QKV3)
      bias_cat[c] = (c < 512) ? bq[c] : (c < 1024) ? bk[c - 512] : bv[c - 1024];
  }
}

// ------- 4 weight transposes in one launch: z=0..2 -> cat dst, z=3 -> Do -------
__global__ __launch_bounds__(256) void transpose4_kernel(
    const float* __restrict__ W0, const float* __restrict__ W1,
    const float* __restrict__ W2, const float* __restrict__ W3,
    unsigned short* __restrict__ Dcat, unsigned short* __restrict__ Do, int D)
{
  __shared__ float t[32][33];
  int z = blockIdx.z;
  const float* W = (z == 0) ? W0 : (z == 1) ? W1 : (z == 2) ? W2 : W3;
  unsigned short* dst = (z < 3) ? Dcat + (size_t)z * D * D : Do;
  int n0 = blockIdx.x * 32, k0 = blockIdx.y * 32;
  int x = threadIdx.x, y = threadIdx.y;   // 32 x 8
  #pragma unroll
  for (int j = 0; j < 32; j += 8)
    t[y + j][x] = W[(size_t)(k0 + y + j) * D + n0 + x];
  __syncthreads();
  #pragma unroll
  for (int j = 0; j < 32; j += 8)
    dst[(size_t)(n0 + y + j) * D + k0 + x] = f2h(t[x][y + j]);
}

// ---------------- vectors [n][128][3] f32 -> VT [(n*3+i)][128] f16 ----------------
__global__ __launch_bounds__(128) void vec_transpose_kernel(
    const float* __restrict__ vecs, unsigned short* __restrict__ VT)
{
  __shared__ float l[NV3];
  int n = blockIdx.x, t = threadIdx.x;
  #pragma unroll
  for (int j = 0; j < 3; ++j) l[t + j * 128] = vecs[(size_t)n * NV3 + t + j * 128];
  __syncthreads();
  #pragma unroll
  for (int i = 0; i < 3; ++i)
    VT[((size_t)n * 3 + i) * V_DIM + t] = f2h(l[t * 3 + i]);
}

// ---------------- f16 MFMA GEMM (verified fast, round 5) ----------------
__global__ __launch_bounds__(256) void gemm_f16_kernel(
    const unsigned short* __restrict__ A, const unsigned short* __restrict__ Bt,
    const float* __restrict__ bias, float* __restrict__ Cf,
    unsigned short* __restrict__ Ch, int M, int K, int Nn)
{
  __shared__ unsigned short lds[2][2][128 * 32];
  int tid = threadIdx.x;
  int wid = tid >> 6, lane = tid & 63;
  int wr = wid >> 1, wc = wid & 1;
  int row0 = blockIdx.y * 128, col0 = blockIdx.x * 128;

  int r0 = tid >> 2, s0 = tid & 3;
  int r1 = r0 + 64;
  int sw0 = (r0 >> 1) & 3;
  int aoff = (s0 ^ sw0) * 8;
  int gra0 = row0 + r0; if (gra0 >= M) gra0 = M - 1;
  int gra1 = row0 + r1; if (gra1 >= M) gra1 = M - 1;
  const unsigned short* ag0 = A + (size_t)gra0 * K + aoff;
  const unsigned short* ag1 = A + (size_t)gra1 * K + aoff;
  const unsigned short* bg0 = Bt + (size_t)(col0 + r0) * K + aoff;
  const unsigned short* bg1 = Bt + (size_t)(col0 + r1) * K + aoff;

  f32x4 acc[4][4];
  #pragma unroll
  for (int m = 0; m < 4; ++m)
    #pragma unroll
    for (int n = 0; n < 4; ++n) acc[m][n] = (f32x4){0.f, 0.f, 0.f, 0.f};

  int lr = lane & 15, lq = lane >> 4;
  int slot = (lq ^ ((lr >> 1) & 3)) * 8;
  int aro[4], bro[4];
  #pragma unroll
  for (int m = 0; m < 4; ++m) aro[m] = (wr * 64 + m * 16 + lr) * 32 + slot;
  #pragma unroll
  for (int n = 0; n < 4; ++n) bro[n] = (wc * 64 + n * 16 + lr) * 32 + slot;

  int nk = K >> 5;
  glds16(ag0, &lds[0][0][tid * 8]);
  glds16(ag1, &lds[0][0][(tid + 256) * 8]);
  glds16(bg0, &lds[0][1][tid * 8]);
  glds16(bg1, &lds[0][1][(tid + 256) * 8]);
  __syncthreads();

  for (int t = 0; t < nk; ++t) {
    int cur = t & 1;
    if (t + 1 < nk) {
      int ko = (t + 1) << 5;
      glds16(ag0 + ko, &lds[cur ^ 1][0][tid * 8]);
      glds16(ag1 + ko, &lds[cur ^ 1][0][(tid + 256) * 8]);
      glds16(bg0 + ko, &lds[cur ^ 1][1][tid * 8]);
      glds16(bg1 + ko, &lds[cur ^ 1][1][(tid + 256) * 8]);
    }
    const unsigned short* Ab = lds[cur][0];
    const unsigned short* Bb = lds[cur][1];
    f16x8 af[4], bf[4];
    #pragma unroll
    for (int m = 0; m < 4; ++m) af[m] = *reinterpret_cast<const f16x8*>(Ab + aro[m]);
    #pragma unroll
    for (int n = 0; n < 4; ++n) bf[n] = *reinterpret_cast<const f16x8*>(Bb + bro[n]);
    #pragma unroll
    for (int m = 0; m < 4; ++m)
      #pragma unroll
      for (int n = 0; n < 4; ++n)
        acc[m][n] = __builtin_amdgcn_mfma_f32_16x16x32_f16(af[m], bf[n], acc[m][n], 0, 0, 0);
    __syncthreads();
  }

  float bcol[4];
  #pragma unroll
  for (int n = 0; n < 4; ++n)
    bcol[n] = bias ? bias[col0 + wc * 64 + n * 16 + lr] : 0.f;
  int rl = tid >> 3, cc = (tid & 7) * 16;

  if (Cf) {
    float* cst = reinterpret_cast<float*>(&lds[0][0][0]);
    #pragma unroll
    for (int m = 0; m < 4; ++m) {
      __syncthreads();
      #pragma unroll
      for (int n = 0; n < 4; ++n)
        #pragma unroll
        for (int j = 0; j < 4; ++j)
          cst[(wr * 16 + lq * 4 + j) * 128 + wc * 64 + n * 16 + lr] = acc[m][n][j] + bcol[n];
      __syncthreads();
      int row = row0 + (rl >> 4) * 64 + m * 16 + (rl & 15);
      if (row < M) {
        float4* dst = reinterpret_cast<float4*>(Cf + (size_t)row * Nn + col0 + cc);
        const float4* src = reinterpret_cast<const float4*>(cst + rl * 128 + cc);
        dst[0] = src[0]; dst[1] = src[1]; dst[2] = src[2]; dst[3] = src[3];
      }
    }
  } else {
    unsigned short* csth = &lds[0][0][0];
    #pragma unroll
    for (int m = 0; m < 4; ++m) {
      __syncthreads();
      #pragma unroll
      for (int n = 0; n < 4; ++n)
        #pragma unroll
        for (int j = 0; j < 4; ++j)
          csth[(wr * 16 + lq * 4 + j) * 128 + wc * 64 + n * 16 + lr] = f2h(acc[m][n][j] + bcol[n]);
      __syncthreads();
      int row = row0 + (rl >> 4) * 64 + m * 16 + (rl & 15);
      if (row < M) {
        int4* dst = reinterpret_cast<int4*>(Ch + (size_t)row * Nn + col0 + cc);
        const int4* src = reinterpret_cast<const int4*>(csth + rl * 128 + cc);
        dst[0] = src[0]; dst[1] = src[1];
      }
    }
  }
}

// -------- pack Q,K,V into int8 rows [n][896] with per-node scales --------
// scales[3*n + {0,1,2}] = {sq, sk, sv} (dequant multipliers, amax/127)
__global__ __launch_bounds__(256) void pack_i8_kernel(
    const unsigned short* __restrict__ qkv_s, const unsigned short* __restrict__ qkv_v,
    char* __restrict__ q8, char* __restrict__ k8, char* __restrict__ v8,
    float* __restrict__ scales)
{
  __shared__ float am[336];
  __shared__ float inv_sh[3];
  int n = blockIdx.x, t = threadIdx.x;
  float va[2][8];

  auto loadChunk = [&](int chunk, float* v) {
    int r = chunk / 112, j = chunk - r * 112;
    int c = j * 8;
    const unsigned short* src;
    if (c < 512) {
      src = qkv_s + (size_t)n * QKV3 + r * 512 + c;
    } else {
      int cc = c - 512, i = cc >> 7, w = cc & 127;
      src = qkv_v + ((size_t)n * 3 + i) * VQKV3 + r * 128 + w;
    }
    int4 sv = *reinterpret_cast<const int4*>(src);
    union { int4 x; unsigned short u[8]; } us; us.x = sv;
    float m = 0.f;
    #pragma unroll
    for (int q = 0; q < 8; ++q) { v[q] = h2f(us.u[q]); m = fmaxf(m, fabsf(v[q])); }
    am[chunk] = m;
  };

  loadChunk(t, va[0]);
  if (t < 80) loadChunk(256 + t, va[1]);
  __syncthreads();

  int lane = t & 63, wid = t >> 6;
  if (wid < 3) {
    int basec = wid * 112;
    float m = am[basec + lane];
    if (lane < 48) m = fmaxf(m, am[basec + 64 + lane]);
    m = wave_max(m);
    if (lane == 0) {
      m = fmaxf(m, 1e-8f);
      scales[3 * n + wid] = m * (1.f / 127.f);
      inv_sh[wid] = 127.f / m;
    }
  }
  __syncthreads();

  auto quantStore = [&](int chunk, const float* v) {
    int r = chunk / 112, j = chunk - r * 112;
    float inv = inv_sh[r];
    unsigned int b0 = 0, b1 = 0;
    #pragma unroll
    for (int q = 0; q < 4; ++q) {
      int x = __float2int_rn(v[q] * inv);
      b0 |= ((unsigned)(x & 0xff)) << (8 * q);
    }
    #pragma unroll
    for (int q = 0; q < 4; ++q) {
      int x = __float2int_rn(v[4 + q] * inv);
      b1 |= ((unsigned)(x & 0xff)) << (8 * q);
    }
    char* dst = (r == 0 ? q8 : r == 1 ? k8 : v8) + (size_t)n * KV8P + j * 8;
    uint2 o; o.x = b0; o.y = b1;
    *reinterpret_cast<uint2*>(dst) = o;
  };

  quantStore(t, va[0]);
  if (t < 80) quantStore(256 + t, va[1]);
}

// -------- CSR scan + scatter --------
__global__ __launch_bounds__(1024) void scan_kernel(const int* __restrict__ counts,
                                                    int* __restrict__ offs) {
  __shared__ int wsum[16];
  __shared__ int carry_s;
  int tid = threadIdx.x;
  int lane = tid & 63, w = tid >> 6;
  if (tid == 0) carry_s = 0;
  __syncthreads();
  for (int base = 0; base < N_NODES; base += 1024) {
    int i = base + tid;
    int v = (i < N_NODES) ? counts[i] : 0;
    int x = v;
    #pragma unroll
    for (int o = 1; o < 64; o <<= 1) {
      int t = __shfl_up(x, o, 64);
      if (lane >= o) x += t;
    }
    if (lane == 63) wsum[w] = x;
    __syncthreads();
    if (w == 0 && lane < 16) {
      int t = wsum[lane];
      #pragma unroll
      for (int o = 1; o < 16; o <<= 1) {
        int u = __shfl_up(t, o, 64);
        if (lane >= o) t += u;
      }
      wsum[lane] = t;
    }
    __syncthreads();
    int incl = x + ((w > 0) ? wsum[w - 1] : 0);
    int c = carry_s;
    __syncthreads();
    if (i < N_NODES) offs[i] = c + incl - v;
    if (tid == 1023) carry_s = c + incl;
    __syncthreads();
  }
  if (tid == 0) offs[N_NODES] = carry_s;
}

__global__ void scatter_kernel(const int* __restrict__ ei, const int* __restrict__ offs,
                               int* __restrict__ cursor, int* __restrict__ eord) {
  int e = blockIdx.x * 256 + threadIdx.x;
  if (e < E_EDGES) {
    int r = ei[e];
    int p = offs[r] + atomicAdd(&cursor[r], 1);
    eord[p] = e;
  }
}

// -------- per-edge logits: 8 lanes/edge, int8 sdot4 gathers, fused bessel --------
__global__ __launch_bounds__(256, 4) void edge_logits_kernel(
    const char* __restrict__ q8, const char* __restrict__ k8,
    const float* __restrict__ scales,
    const float* __restrict__ edge_vec, const int* __restrict__ ei,
    const int* __restrict__ eord,
    const float* __restrict__ W_edge, const float* __restrict__ b_edge,
    float* __restrict__ logits, int* __restrict__ cols)
{
  __shared__ float Wl[R_BASIS * H_HEADS];
  Wl[threadIdx.x] = W_edge[threadIdx.x];
  __syncthreads();

  int lane = threadIdx.x & 63;
  int wv = threadIdx.x >> 6;
  int g = lane >> 3, h = lane & 7;
  int pos = blockIdx.x * 32 + wv * 8 + g;
  int e = eord[pos];
  int row = ei[e], col = ei[E_EDGES + e];

  // issue all gathers first (latency batching)
  const char* qp = q8 + (size_t)row * KV8P + h * HD_DIM;
  const char* kp = k8 + (size_t)col * KV8P + h * HD_DIM;
  uint4 qa[4], ka[4];
  #pragma unroll
  for (int r = 0; r < 4; ++r) qa[r] = *reinterpret_cast<const uint4*>(qp + r * 16);
  #pragma unroll
  for (int r = 0; r < 4; ++r) ka[r] = *reinterpret_cast<const uint4*>(kp + r * 16);

  const char* qvp = q8 + (size_t)row * KV8P + 512 + h * 48;
  const char* kvp = k8 + (size_t)col * KV8P + 512 + h * 48;
  uint4 qv[3], kv[3];
  #pragma unroll
  for (int r = 0; r < 3; ++r) qv[r] = *reinterpret_cast<const uint4*>(qvp + r * 16);
  #pragma unroll
  for (int r = 0; r < 3; ++r) kv[r] = *reinterpret_cast<const uint4*>(kvp + r * 16);

  float sq = scales[3 * row + 0];
  float sk = scales[3 * col + 1];
  float ex = edge_vec[(size_t)e * 3 + 0];
  float ey = edge_vec[(size_t)e * 3 + 1];
  float ez = edge_vec[(size_t)e * 3 + 2];

  // scalar attention (head h): 64-elem int8 dot
  int dsum = 0;
  #pragma unroll
  for (int r = 0; r < 4; ++r) {
    dsum = SDOT4(qa[r].x, ka[r].x, dsum);
    dsum = SDOT4(qa[r].y, ka[r].y, dsum);
    dsum = SDOT4(qa[r].z, ka[r].z, dsum);
    dsum = SDOT4(qa[r].w, ka[r].w, dsum);
  }
  // vector attention: 48 elems per lane, int-sum over the edge's 8 lanes
  int dvec = 0;
  #pragma unroll
  for (int r = 0; r < 3; ++r) {
    dvec = SDOT4(qv[r].x, kv[r].x, dvec);
    dvec = SDOT4(qv[r].y, kv[r].y, dvec);
    dvec = SDOT4(qv[r].z, kv[r].z, dvec);
    dvec = SDOT4(qv[r].w, kv[r].w, dvec);
  }
  dvec += __shfl_xor(dvec, 1, 64);
  dvec += __shfl_xor(dvec, 2, 64);
  dvec += __shfl_xor(dvec, 4, 64);

  float att = sq * sk * ((float)dsum + 0.57735026918962576f * (float)dvec);

  // bessel + edge MLP (4-way-ILP sin recurrence), lane = head column
  float d = sqrtf(ex * ex + ey * ey + ez * ez);
  float th = d * 0.31415926535897932f;  // pi*d/10
  float s1 = __sinf(th), c1 = __cosf(th);
  float s2 = 2.f * s1 * c1,         c2 = fmaf(c1, c1, -s1 * s1);
  float s3 = fmaf(s2, c1, c2 * s1), c3 = fmaf(c2, c1, -s2 * s1);
  float s4 = 2.f * s2 * c2,         c4 = fmaf(c2, c2, -s2 * s2);
  float sr[4] = {s1, s2, s3, s4};
  float cr[4] = {c1, c2, c3, c4};
  float acc = 0.f;
  #pragma unroll
  for (int t = 0; t < 8; ++t) {
    #pragma unroll
    for (int j = 0; j < 4; ++j) {
      acc = fmaf(sr[j], Wl[(t * 4 + j) * H_HEADS + h], acc);
      float sn = fmaf(sr[j], c4, cr[j] * s4);
      cr[j] = fmaf(cr[j], c4, -sr[j] * s4);
      sr[j] = sn;
    }
  }
  float cut = (d < 10.f) ? 0.5f * (c1 + 1.f) : 0.f;
  float eah = fmaf(acc, cut / fmaxf(d, 1e-8f), b_edge[h]);

  logits[(size_t)pos * H_HEADS + h] = (att + eah) * 0.125f;
  if (h == 0) cols[pos] = col;
}

// -------- per-node softmax + aggregation (4-wave edge-parallel, int8 V) --------
#define MAXDEG 512
__global__ __launch_bounds__(256) void agg_kernel(
    const float* __restrict__ logits, const int* __restrict__ cols,
    const char* __restrict__ v8, const float* __restrict__ scales,
    const int* __restrict__ offs,
    unsigned short* __restrict__ out_s, unsigned short* __restrict__ out_v)
{
  __shared__ float attn_lds[MAXDEG * H_HEADS];
  __shared__ float av_lds[MAXDEG];
  __shared__ int col_lds[MAXDEG];
  __shared__ float m_sh[H_HEADS], inv_sh[H_HEADS];

  int n = blockIdx.x;
  int beg = offs[n];
  int deg = offs[n + 1] - beg;
  int tid = threadIdx.x;
  bool fits = (deg <= MAXDEG);

  if (tid < 64) {
    int lane = tid;
    float lm[H_HEADS];
    #pragma unroll
    for (int h = 0; h < H_HEADS; ++h) lm[h] = -INFINITY;
    for (int i = lane; i < deg; i += 64) {
      const float4* lp = reinterpret_cast<const float4*>(logits + (size_t)(beg + i) * 8);
      float4 a = lp[0], b = lp[1];
      if (fits) col_lds[i] = cols[beg + i];
      lm[0] = fmaxf(lm[0], a.x); lm[1] = fmaxf(lm[1], a.y);
      lm[2] = fmaxf(lm[2], a.z); lm[3] = fmaxf(lm[3], a.w);
      lm[4] = fmaxf(lm[4], b.x); lm[5] = fmaxf(lm[5], b.y);
      lm[6] = fmaxf(lm[6], b.z); lm[7] = fmaxf(lm[7], b.w);
    }
    #pragma unroll
    for (int h = 0; h < H_HEADS; ++h) lm[h] = wave_max(lm[h]);

    float ls[H_HEADS];
    #pragma unroll
    for (int h = 0; h < H_HEADS; ++h) ls[h] = 0.f;
    for (int i = lane; i < deg; i += 64) {
      const float4* lp = reinterpret_cast<const float4*>(logits + (size_t)(beg + i) * 8);
      float4 a = lp[0], b = lp[1];
      float w[8];
      w[0] = expf(a.x - lm[0]); w[1] = expf(a.y - lm[1]);
      w[2] = expf(a.z - lm[2]); w[3] = expf(a.w - lm[3]);
      w[4] = expf(b.x - lm[4]); w[5] = expf(b.y - lm[5]);
      w[6] = expf(b.z - lm[6]); w[7] = expf(b.w - lm[7]);
      #pragma unroll
      for (int h = 0; h < H_HEADS; ++h) {
        ls[h] += w[h];
        if (fits) attn_lds[i * 8 + h] = w[h];
      }
    }
    #pragma unroll
    for (int h = 0; h < H_HEADS; ++h) ls[h] = wave_sum(ls[h]);

    float inv[H_HEADS];
    #pragma unroll
    for (int h = 0; h < H_HEADS; ++h) inv[h] = 1.f / (ls[h] + 1e-9f);
    if (lane == 0) {
      #pragma unroll
      for (int h = 0; h < H_HEADS; ++h) { m_sh[h] = lm[h]; inv_sh[h] = inv[h]; }
    }
    if (fits) {
      for (int i = lane; i < deg; i += 64) {
        float a = 0.f;
        #pragma unroll
        for (int h = 0; h < H_HEADS; ++h) a += attn_lds[i * 8 + h] * inv[h];
        av_lds[i] = 0.125f * a;
      }
    }
  }
  __syncthreads();

  int lane = tid & 63, wv = tid >> 6;
  int h = lane >> 3;
  float ih = inv_sh[h], mh = m_sh[h];
  float accs[8] = {0,0,0,0,0,0,0,0};
  float accv[8] = {0,0,0,0,0,0,0,0};

  auto body = [&](int i) {
    int colv;
    float wgt, av;
    if (fits) {
      colv = col_lds[i];
      wgt = attn_lds[i * 8 + h] * ih;
      av = av_lds[i];
    } else {
      colv = cols[beg + i];
      const float* lp = logits + (size_t)(beg + i) * 8;
      wgt = expf(lp[h] - mh) * ih;
      float a = 0.f;
      #pragma unroll
      for (int hh = 0; hh < H_HEADS; ++hh)
        a += expf(lp[hh] - m_sh[hh]) * inv_sh[hh];
      av = 0.125f * a;
    }
    float svc = scales[3 * colv + 2];
    wgt *= svc; av *= svc;
    uint2 vs = *reinterpret_cast<const uint2*>(v8 + (size_t)colv * KV8P + lane * 8);
    fma_i8x4(vs.x, wgt, accs);
    fma_i8x4(vs.y, wgt, accs + 4);
    if (lane < 48) {
      uint2 vvl = *reinterpret_cast<const uint2*>(v8 + (size_t)colv * KV8P + 512 + lane * 8);
      fma_i8x4(vvl.x, av, accv);
      fma_i8x4(vvl.y, av, accv + 4);
    }
  };

  int i = wv;
  for (; i + 4 < deg; i += 8) { body(i); body(i + 4); }
  if (i < deg) body(i);
  __syncthreads();

  float* red_s = attn_lds;            // [4][512]
  float* red_v = attn_lds + 2048;     // [4][384]
  #pragma unroll
  for (int j = 0; j < 8; j += 4)
    *reinterpret_cast<float4*>(&red_s[wv * 512 + lane * 8 + j]) =
      make_float4(accs[j], accs[j+1], accs[j+2], accs[j+3]);
  if (lane < 48) {
    #pragma unroll
    for (int j = 0; j < 8; j += 4)
      *reinterpret_cast<float4*>(&red_v[wv * 384 + lane * 8 + j]) =
        make_float4(accv[j], accv[j+1], accv[j+2], accv[j+3]);
  }
  __syncthreads();

  {
    int d0 = 2 * tid;
    float s0 = red_s[d0] + red_s[512 + d0] + red_s[1024 + d0] + red_s[1536 + d0];
    float s1 = red_s[d0+1] + red_s[512 + d0+1] + red_s[1024 + d0+1] + red_s[1536 + d0+1];
    ushort2 o; o.x = f2h(s0); o.y = f2h(s1);
    *reinterpret_cast<ushort2*>(out_s + (size_t)n * S_DIM + d0) = o;
  }
  if (tid < 192) {
    int d0 = 2 * tid;
    float s0 = red_v[d0] + red_v[384 + d0] + red_v[768 + d0] + red_v[1152 + d0];
    float s1 = red_v[d0+1] + red_v[384 + d0+1] + red_v[768 + d0+1] + red_v[1152 + d0+1];
    ushort2 o; o.x = f2h(s0); o.y = f2h(s1);
    *reinterpret_cast<ushort2*>(out_v + (size_t)n * NV3 + d0) = o;
  }
}

// -------- vec output epilogue --------
__global__ __launch_bounds__(128) void vec_epilogue_kernel(
    const float* __restrict__ tmp, const float* __restrict__ bout_v,
    const float* __restrict__ vectors, float* __restrict__ out)
{
  __shared__ float l[NV3];
  int n = blockIdx.x, t = threadIdx.x;
  #pragma unroll
  for (int i = 0; i < 3; ++i)
    l[i * 128 + t] = tmp[((size_t)n * 3 + i) * V_DIM + t];
  __syncthreads();
  #pragma unroll
  for (int c = 0; c < 3; ++c) {
    int j = t + c * 128;      // j = w*3 + i
    int w = j / 3, i = j - 3 * w;
    out[(size_t)n * NV3 + j] = l[i * 128 + w] + bout_v[w] + vectors[(size_t)n * NV3 + j];
  }
}

// -------- residual + LayerNorm (wave per row) --------
__global__ __launch_bounds__(256) void ln_kernel(
    const float* __restrict__ x0, const float* __restrict__ dx,
    const float* __restrict__ g, const float* __restrict__ b,
    float* __restrict__ out)
{
  int r = blockIdx.x * 4 + (threadIdx.x >> 6);
  int lane = threadIdx.x & 63;
  if (r >= N_NODES) return;
  float x[8];
  float s = 0.f;
  #pragma unroll
  for (int j = 0; j < 8; ++j) {
    int d = lane + j * 64;
    x[j] = x0[(size_t)r * S_DIM + d] + dx[(size_t)r * S_DIM + d];
    s += x[j];
  }
  s = wave_sum(s);
  float mu = s * (1.f / 512.f);
  float vs = 0.f;
  #pragma unroll
  for (int j = 0; j < 8; ++j) { float t = x[j] - mu; vs += t * t; }
  vs = wave_sum(vs);
  float inv = rsqrtf(vs * (1.f / 512.f) + 1e-5f);
  #pragma unroll
  for (int j = 0; j < 8; ++j) {
    int d = lane + j * 64;
    out[(size_t)r * S_DIM + d] = (x[j] - mu) * inv * g[d] + b[d];
  }
}

extern "C" void kernel_launch(void* const* d_in, const int* in_sizes, int n_in,
                              void* d_out, int out_size, void* d_ws, size_t ws_size,
                              hipStream_t stream)
{
  (void)in_sizes; (void)n_in; (void)out_size; (void)ws_size;
  const float* scalars  = (const float*)d_in[0];
  const float* vectors  = (const float*)d_in[1];
  const float* edge_vec = (const float*)d_in[2];
  const float* Wq_s = (const float*)d_in[3];
  const float* bq_s = (const float*)d_in[4];
  const float* Wk_s = (const float*)d_in[5];
  const float* bk_s = (const float*)d_in[6];
  const float* Wv_s = (const float*)d_in[7];
  const float* bv_s = (const float*)d_in[8];
  const float* Wq_v = (const float*)d_in[9];
  const float* Wk_v = (const float*)d_in[10];
  const float* Wv_v = (const float*)d_in[11];
  const float* Wout_s = (const float*)d_in[12];
  const float* bout_s = (const float*)d_in[13];
  const float* Wout_v = (const float*)d_in[14];
  const float* bout_v = (const float*)d_in[15];
  const float* W_edge = (const float*)d_in[16];
  const float* b_edge = (const float*)d_in[17];
  const float* ln_g = (const float*)d_in[18];
  const float* ln_b = (const float*)d_in[19];
  const int* ei = (const int*)d_in[20];

  float* out = (float*)d_out;
  const size_t NS  = (size_t)N_NODES * S_DIM;     // 5,120,000
  const size_t NVs = (size_t)N_NODES * NV3;       // 3,840,000
  const size_t EH  = (size_t)E_EDGES * H_HEADS;   // 1,280,000
  const size_t WSZ = (size_t)S_DIM * S_DIM;
  const size_t WVZ = (size_t)V_DIM * V_DIM;
  const int MV = N_NODES * 3;

  char* base = (char*)d_ws;
  auto carve = [&](size_t bytes) -> char* {
    char* p = base;
    base += (bytes + 255) & ~(size_t)255;
    return p;
  };
  unsigned short* Af16 = (unsigned short*)carve(NS * 2);    // 10.24MB
  unsigned short* VT0  = (unsigned short*)carve(NVs * 2);   // 7.68MB
  float* tmpv = (float*)Af16;   // alias (15.36MB; Af16+VT0 dead by then)
  // v8 aliases Af16 too: lifetime pack->agg, before tmpv is written (wout_v gemm)
  char* v8 = (char*)Af16;                                    // 8.96MB
  unsigned short* qkv_s = (unsigned short*)carve((size_t)N_NODES * QKV3 * 2);   // 30.72MB
  unsigned short* qkv_v = (unsigned short*)carve((size_t)MV * VQKV3 * 2);       // 23.04MB
  unsigned short* outs_pre = (unsigned short*)carve(NS * 2);
  unsigned short* outv_pre = (unsigned short*)carve(NVs * 2);
  float* dx       = (float*)carve(NS * 4);        // 20.48MB
  // q8/k8 alias dx: lifetimes disjoint (pack->edge_logits; dx written by Wout gemm after agg)
  char* q8 = (char*)dx;                                      // 8.96MB
  char* k8 = q8 + (size_t)N_NODES * KV8P;                    // 8.96MB (17.92 <= 20.48)
  float* logitsS  = (float*)carve(EH * 4);
  int*   colsS    = (int*)carve(E_EDGES * 4);
  unsigned short* WqkvT  = (unsigned short*)carve(3 * WSZ * 2);
  unsigned short* WoT    = (unsigned short*)carve(WSZ * 2);
  unsigned short* WqkvvT = (unsigned short*)carve(3 * WVZ * 2);
  unsigned short* WovT   = (unsigned short*)carve(WVZ * 2);
  float* bias_cat = (float*)carve(QKV3 * 4);
  float* scales   = (float*)carve(3 * N_NODES * 4);
  int* counts = (int*)carve(N_NODES * 4);
  int* offs   = (int*)carve((N_NODES + 1) * 4);
  int* cursor = (int*)carve(N_NODES * 4);
  int* eord   = (int*)carve(E_EDGES * 4);

  hipMemsetAsync(counts, 0, N_NODES * sizeof(int), stream);
  hipMemsetAsync(cursor, 0, N_NODES * sizeof(int), stream);

  // fused prep: f32->f16 scalars | edge count | bias concat
  prep_kernel<<<5631, 256, 0, stream>>>(scalars, Af16, ei, counts,
                                        bq_s, bk_s, bv_s, bias_cat);
  dim3 tBlk(32, 8);
  transpose4_kernel<<<dim3(16, 16, 4), tBlk, 0, stream>>>(Wq_s, Wk_s, Wv_s, Wout_s, WqkvT, WoT, S_DIM);
  transpose4_kernel<<<dim3(4, 4, 4), tBlk, 0, stream>>>(Wq_v, Wk_v, Wv_v, Wout_v, WqkvvT, WovT, V_DIM);
  vec_transpose_kernel<<<N_NODES, 128, 0, stream>>>(vectors, VT0);

  // fused QKV projections
  gemm_f16_kernel<<<dim3(QKV3 / 128, (N_NODES + 127) / 128), 256, 0, stream>>>(
      Af16, WqkvT, bias_cat, nullptr, qkv_s, N_NODES, S_DIM, QKV3);
  gemm_f16_kernel<<<dim3(VQKV3 / 128, (MV + 127) / 128), 256, 0, stream>>>(
      VT0, WqkvvT, nullptr, nullptr, qkv_v, MV, V_DIM, VQKV3);

  // int8 Q/K/V rows + per-node scales (overwrites Af16 region with v8 — Af16 is dead)
  pack_i8_kernel<<<N_NODES, 256, 0, stream>>>(qkv_s, qkv_v, q8, k8, v8, scales);

  // CSR
  scan_kernel<<<1, 1024, 0, stream>>>(counts, offs);
  scatter_kernel<<<(E_EDGES + 255) / 256, 256, 0, stream>>>(ei, offs, cursor, eord);

  // edge logits (int8 sdot4 gathers + fused bessel)
  edge_logits_kernel<<<E_EDGES / 32, 256, 0, stream>>>(q8, k8, scales, edge_vec,
                                                       ei, eord, W_edge, b_edge,
                                                       logitsS, colsS);

  // softmax + aggregate (int8 V gather)
  agg_kernel<<<N_NODES, 256, 0, stream>>>(logitsS, colsS, v8, scales, offs,
                                          outs_pre, outv_pre);

  // output projections + epilogues
  gemm_f16_kernel<<<dim3(S_DIM / 128, (N_NODES + 127) / 128), 256, 0, stream>>>(
      outs_pre, WoT, bout_s, dx, nullptr, N_NODES, S_DIM, S_DIM);
  gemm_f16_kernel<<<dim3(1, (MV + 127) / 128), 256, 0, stream>>>(
      outv_pre, WovT, nullptr, tmpv, nullptr, MV, V_DIM, V_DIM);
  vec_epilogue_kernel<<<N_NODES, 128, 0, stream>>>(tmpv, bout_v, vectors, out + NS);
  ln_kernel<<<2500, 256, 0, stream>>>(scalars, dx, ln_g, ln_b, out);
}